// Round 11
// baseline (485.897 us; speedup 1.0000x reference)
//
#include <hip/hip_runtime.h>
#include <math.h>

namespace {
constexpr int NB  = 256;
constexpr int NU  = 8;
constexpr int NKT = 4;
constexpr int NH  = 128;
constexpr int NO  = 4;
constexpr int NA  = 7;
constexpr int NV  = 400;
constexpr int NE  = 53824;
constexpr int NCV = 6728;
constexpr int NDK = 64;
constexpr int NDKC= 32;

constexpr int H1 = 31, W1 = 31;
constexpr int H2 = 30, W2 = 30;
constexpr int H3 = 29, W3 = 29;
}

typedef __attribute__((ext_vector_type(8))) short bf16x8_t;
typedef __attribute__((ext_vector_type(4))) float f32x4_t;

__device__ __forceinline__ unsigned short f2bf(float f) {
    unsigned int u = __float_as_uint(f);
    u += 0x7FFFu + ((u >> 16) & 1u);   // RNE
    return (unsigned short)(u >> 16);
}
__device__ __forceinline__ float bf2f(unsigned short h) {
    return __uint_as_float((unsigned int)h << 16);
}

// ---------------- conv1 (2x2, 3->16) + relu + maxpool2 ----------------
__global__ __launch_bounds__(256)
void k_conv1(const float* __restrict__ x, const float* __restrict__ w,
             const float* __restrict__ bias, float* __restrict__ out)
{
    __shared__ float ws[16*3*2*2];
    __shared__ float bs[16];
    int tid = threadIdx.x;
    if (tid < 192) ws[tid] = w[tid];
    if (tid < 16)  bs[tid] = bias[tid];
    __syncthreads();
    long idx = (long)blockIdx.x*256 + tid;
    if (idx >= (long)NB*16*H1*W1) return;
    int pw = idx % W1; long t = idx / W1;
    int ph = t % H1; t /= H1;
    int oc = t % 16; int b = t / 16;
    float mx = 0.f;
#pragma unroll
    for (int dh = 0; dh < 2; ++dh)
#pragma unroll
    for (int dw = 0; dw < 2; ++dw) {
        int h = 2*ph + dh, ww = 2*pw + dw;
        float s = bs[oc];
#pragma unroll
        for (int kh = 0; kh < 2; ++kh)
#pragma unroll
        for (int kw = 0; kw < 2; ++kw) {
            const float* xp = x + (((long)b*64 + (h+kh))*64 + (ww+kw))*3;
#pragma unroll
            for (int ic = 0; ic < 3; ++ic)
                s += xp[ic] * ws[((oc*3+ic)*2+kh)*2+kw];
        }
        mx = fmaxf(mx, s);
    }
    out[idx] = mx;
}

// ---------------- conv 2x2 as implicit GEMM, 4x8 micro-tile ----------------
// M=OC, K=IC*4, N=spatial per batch. Micro: 4 (m) x (4+4) (n, two stride-4 blocks
// at tx*4 and NT/2+tx*4 -> 2-way LDS bank aliasing only = free).
// Per-output K-accumulation order identical to the 4x4 version (bit-exact).
template<int OC, int IC, int HIN, int WIN, int HOUT, int WOUT>
__global__ __launch_bounds__(256)
void conv2x2_gemm(const float* __restrict__ in, const float* __restrict__ w,
                  const float* __restrict__ bias, float* __restrict__ out,
                  unsigned short* __restrict__ out16)
{
    constexpr int K    = IC*4;
    constexpr int TY   = OC/4;          // 16 (OC=64) or 8 (OC=32)
    constexpr int TX   = 256/TY;        // 16 or 32
    constexpr int NT   = TX*8;          // 128 or 256
    constexpr int SPAT = HOUT*WOUT;
    constexpr int NBLK = (SPAT + NT - 1)/NT;
    constexpr int HNT  = NT/2;

    const int b  = blockIdx.x / NBLK;
    const int n0 = (blockIdx.x % NBLK) * NT;

    __shared__ __align__(16) float As[16][OC+4];
    __shared__ __align__(16) float Bs[16][NT];

    const int tid = threadIdx.x;
    const int tx = tid % TX, ty = tid / TX;
    float acc[4][8] = {};
    const float* inb = in + (long)b*IC*HIN*WIN;

    // Bs staging: each thread owns one column n (conv2) or one of two (conv3),
    // so the s->(oh,ow) div/mod happens once per column.
    constexpr int COLS = NT/256 ? NT/256 : 1;          // 1 (NT=128 -> tid%128) or 1
    const int nIdx = (NT == 256) ? tid : (tid % NT);
    int oh0 = 0, ow0 = 0; bool nOk = false;
    {
        int s = n0 + nIdx;
        if (s < SPAT) { oh0 = s / WOUT; ow0 = s % WOUT; nOk = true; }
    }

    for (int kk = 0; kk < K; kk += 16) {
#pragma unroll
        for (int i = 0; i < OC*16/256; ++i) {
            int lin = tid + i*256;
            int m = lin / 16, k = lin % 16;
            As[k][m] = w[m*K + kk + k];
        }
#pragma unroll
        for (int i = 0; i < 16*NT/256; ++i) {
            int lin = tid + i*256;
            int k = lin / NT;           // NT=256: k=i ; NT=128: k = tid/128 + 2i
            // n == nIdx by construction (lin % NT == tid % NT)
            int gk = kk + k;
            int ic = gk >> 2, tap = gk & 3;
            float v = 0.f;
            if (nOk)
                v = inb[(ic*HIN + oh0 + (tap>>1))*WIN + ow0 + (tap&1)];
            Bs[k][nIdx] = v;
        }
        __syncthreads();
#pragma unroll
        for (int k = 0; k < 16; ++k) {
            float4 a4 = *reinterpret_cast<const float4*>(&As[k][ty*4]);
            float4 b4a = *reinterpret_cast<const float4*>(&Bs[k][tx*4]);
            float4 b4b = *reinterpret_cast<const float4*>(&Bs[k][HNT + tx*4]);
            float av[4] = {a4.x,a4.y,a4.z,a4.w};
            float bw[8] = {b4a.x,b4a.y,b4a.z,b4a.w, b4b.x,b4b.y,b4b.z,b4b.w};
#pragma unroll
            for (int i = 0; i < 4; ++i)
#pragma unroll
            for (int j = 0; j < 8; ++j) acc[i][j] += av[i]*bw[j];
        }
        __syncthreads();
    }
#pragma unroll
    for (int i = 0; i < 4; ++i) {
        int gm = ty*4 + i;
        float bi = bias[gm];
#pragma unroll
        for (int j = 0; j < 8; ++j) {
            int s = n0 + (j < 4 ? tx*4 + j : HNT + tx*4 + (j-4));
            if (s < SPAT) {
                float v = fmaxf(acc[i][j] + bi, 0.f);
                out[((long)b*OC + gm)*SPAT + s] = v;
                if (out16) out16[((long)b*OC + gm)*SPAT + s] = f2bf(v);
            }
        }
    }
}

// ---------------- fp32 -> bf16 transposed convert: in [B][R][Cc] -> out [B][Cc][R] ----------------
__global__ __launch_bounds__(256)
void k_f2bt(const float* __restrict__ in, unsigned short* __restrict__ out,
            int R, int Cc, long sIn)
{
    __shared__ unsigned short t[32][33];
    const int b = blockIdx.z;
    const int r0 = blockIdx.y * 32, c0 = blockIdx.x * 32;
    const float* ip = in + (long)b * sIn;
    unsigned short* op = out + (long)b * sIn;
    const int tid = threadIdx.x;
    {
        int rr = tid >> 3, c4 = (tid & 7) * 4;
        int gr = r0 + rr;
        unsigned short h0=0,h1=0,h2=0,h3=0;
        if (gr < R) {
            if (c0 + c4 + 3 < Cc) {
                float4 f = *(const float4*)(ip + (long)gr*Cc + c0 + c4);
                h0=f2bf(f.x); h1=f2bf(f.y); h2=f2bf(f.z); h3=f2bf(f.w);
            } else {
                if (c0+c4+0 < Cc) h0 = f2bf(ip[(long)gr*Cc + c0+c4+0]);
                if (c0+c4+1 < Cc) h1 = f2bf(ip[(long)gr*Cc + c0+c4+1]);
                if (c0+c4+2 < Cc) h2 = f2bf(ip[(long)gr*Cc + c0+c4+2]);
                if (c0+c4+3 < Cc) h3 = f2bf(ip[(long)gr*Cc + c0+c4+3]);
            }
        }
        t[rr][c4+0]=h0; t[rr][c4+1]=h1; t[rr][c4+2]=h2; t[rr][c4+3]=h3;
    }
    __syncthreads();
    {
        int cc = tid >> 3, r4 = (tid & 7) * 4;
        int gc = c0 + cc;
        if (gc < Cc && r0 + r4 < R) {
            if (r0 + r4 + 3 < R) {
                *(ushort4*)(op + (long)gc*R + r0 + r4) =
                    make_ushort4(t[r4+0][cc], t[r4+1][cc], t[r4+2][cc], t[r4+3][cc]);
            } else {
#pragma unroll
                for (int j = 0; j < 4; ++j)
                    if (r0 + r4 + j < R) op[(long)gc*R + r0 + r4 + j] = t[r4+j][cc];
            }
        }
    }
}

// ---------------- bf16 MFMA GEMM staging, 16B-wide ----------------
template<int ROWS, bool F32>
__device__ __forceinline__ void stage_tile(const void* __restrict__ Av, long lda,
                                           int m0, int kk, int kEnd, int Mlim,
                                           unsigned short* lds, int tid)
{
#pragma unroll
    for (int i = 0; i < ROWS/64; ++i) {
        int row = (tid >> 2) + i*64;
        int blk = tid & 3;
        long gm = m0 + row;
        long gk = kk + blk*8;
        ushort4 lo = make_ushort4(0,0,0,0), hi = make_ushort4(0,0,0,0);
        if (gm < Mlim && gk < kEnd) {
            if (F32) {
                const float* A = (const float*)Av + gm*lda + gk;
                float4 f0 = *(const float4*)(A);
                float4 f1 = *(const float4*)(A + 4);
                lo = make_ushort4(f2bf(f0.x),f2bf(f0.y),f2bf(f0.z),f2bf(f0.w));
                hi = make_ushort4(f2bf(f1.x),f2bf(f1.y),f2bf(f1.z),f2bf(f1.w));
            } else {
                const unsigned short* A = (const unsigned short*)Av + gm*lda + gk;
                lo = *(const ushort4*)(A);
                hi = *(const ushort4*)(A + 4);
            }
        }
        int p = (blk ^ (row & 3)) << 3;
        *(ushort4*)&lds[row*32 + p]     = lo;
        *(ushort4*)&lds[row*32 + p + 4] = hi;
    }
}

template<int BM, int BN, bool AF32>
__global__ __launch_bounds__(256)
void bgemm_splitk(const void* __restrict__ Av, long lda, long sA,
                  const unsigned short* __restrict__ BT, long ldbt, long sB,
                  float* __restrict__ Cpart,
                  int M, int N, int K, int nsplit, int kChunk)
{
    constexpr int MR = BM/32, NR = BN/32;
    const int z = blockIdx.z;
    const int batch = z / nsplit, split = z - batch*nsplit;
    const int kStart = split * kChunk;
    const int kEnd = (kStart + kChunk < K) ? (kStart + kChunk) : K;
    const int m0 = blockIdx.y * BM;
    const int n0 = blockIdx.x * BN;

    __shared__ __align__(16) unsigned short As[BM*32];
    __shared__ __align__(16) unsigned short Bs[BN*32];

    const int tid = threadIdx.x;
    const int wave = tid >> 6, lane = tid & 63;
    const int wr = wave >> 1, wc = wave & 1;
    const int lr = lane & 15, lk = lane >> 4;
    const int rbase = wr*(BM/2), cbase = wc*(BN/2);

    const void* Ab = AF32 ? (const void*)((const float*)Av + (long)batch*sA)
                          : (const void*)((const unsigned short*)Av + (long)batch*sA);
    const unsigned short* Bb = BT + (long)batch*sB;

    f32x4_t acc[MR][NR];
#pragma unroll
    for (int i = 0; i < MR; ++i)
#pragma unroll
    for (int j = 0; j < NR; ++j)
        acc[i][j] = (f32x4_t){0.f,0.f,0.f,0.f};

    for (int kk = kStart; kk < kEnd; kk += 32) {
        stage_tile<BM,AF32>(Ab, lda, m0, kk, kEnd, M, As, tid);
        stage_tile<BN,false>((const void*)Bb, ldbt, n0, kk, kEnd, N, Bs, tid);
        __syncthreads();
        bf16x8_t af[MR], bfv[NR];
#pragma unroll
        for (int i = 0; i < MR; ++i) {
            int row = rbase + i*16 + lr;
            af[i] = *(const bf16x8_t*)&As[row*32 + ((lk ^ (row & 3)) << 3)];
        }
#pragma unroll
        for (int j = 0; j < NR; ++j) {
            int col = cbase + j*16 + lr;
            bfv[j] = *(const bf16x8_t*)&Bs[col*32 + ((lk ^ (col & 3)) << 3)];
        }
#pragma unroll
        for (int i = 0; i < MR; ++i)
#pragma unroll
        for (int j = 0; j < NR; ++j)
            acc[i][j] = __builtin_amdgcn_mfma_f32_16x16x32_bf16(af[i], bfv[j], acc[i][j], 0, 0, 0);
        __syncthreads();
    }

    const long cb2 = (long)z * M * N;
#pragma unroll
    for (int i = 0; i < MR; ++i) {
#pragma unroll
        for (int r = 0; r < 4; ++r) {
            int gm = m0 + rbase + i*16 + lk*4 + r;
            if (gm >= M) continue;
#pragma unroll
            for (int j = 0; j < NR; ++j) {
                int gn = n0 + cbase + j*16 + lr;
                if (gn < N) Cpart[cb2 + (long)gm*N + gn] = acc[i][j][r];
            }
        }
    }
}

// direct bf16 GEMM (full K), bf16 output, 128x128 tile
template<bool AF32>
__global__ __launch_bounds__(256)
void bgemm_direct(const void* __restrict__ Av, long lda, long sA,
                  const unsigned short* __restrict__ BT, long ldbt, long sB,
                  unsigned short* __restrict__ Cout, long ldc, long sC,
                  int M, int N, int K)
{
    const int batch = blockIdx.z;
    const int m0 = blockIdx.y * 128;
    const int n0 = blockIdx.x * 128;

    __shared__ __align__(16) unsigned short As[128*32];
    __shared__ __align__(16) unsigned short Bs[128*32];

    const int tid = threadIdx.x;
    const int wave = tid >> 6, lane = tid & 63;
    const int wr = wave >> 1, wc = wave & 1;
    const int lr = lane & 15, lk = lane >> 4;

    const void* Ab = AF32 ? (const void*)((const float*)Av + (long)batch*sA)
                          : (const void*)((const unsigned short*)Av + (long)batch*sA);
    const unsigned short* Bb = BT + (long)batch*sB;

    f32x4_t acc[4][4];
#pragma unroll
    for (int i = 0; i < 4; ++i)
#pragma unroll
    for (int j = 0; j < 4; ++j)
        acc[i][j] = (f32x4_t){0.f,0.f,0.f,0.f};

    for (int kk = 0; kk < K; kk += 32) {
        stage_tile<128,AF32>(Ab, lda, m0, kk, K, M, As, tid);
        stage_tile<128,false>((const void*)Bb, ldbt, n0, kk, K, N, Bs, tid);
        __syncthreads();
        bf16x8_t af[4], bfv[4];
#pragma unroll
        for (int i = 0; i < 4; ++i) {
            int row = wr*64 + i*16 + lr;
            af[i]  = *(const bf16x8_t*)&As[row*32 + ((lk ^ (row & 3)) << 3)];
            int col = wc*64 + i*16 + lr;
            bfv[i] = *(const bf16x8_t*)&Bs[col*32 + ((lk ^ (col & 3)) << 3)];
        }
#pragma unroll
        for (int i = 0; i < 4; ++i)
#pragma unroll
        for (int j = 0; j < 4; ++j)
            acc[i][j] = __builtin_amdgcn_mfma_f32_16x16x32_bf16(af[i], bfv[j], acc[i][j], 0, 0, 0);
        __syncthreads();
    }

    unsigned short* C = Cout + (long)batch * sC;
#pragma unroll
    for (int i = 0; i < 4; ++i) {
#pragma unroll
        for (int r = 0; r < 4; ++r) {
            int gm = m0 + wr*64 + i*16 + lk*4 + r;
            if (gm >= M) continue;
#pragma unroll
            for (int j = 0; j < 4; ++j) {
                int gn = n0 + wc*64 + j*16 + lr;
                if (gn < N) C[(long)gm*ldc + gn] = f2bf(acc[i][j][r]);
            }
        }
    }
}

// direct bf16-input GEMM, fp32 output, 64x64 tile, batched over grid.z (pre path)
template<bool AF32>
__global__ __launch_bounds__(256)
void bgemm_f32(const void* __restrict__ Av, long lda, long sA,
               const unsigned short* __restrict__ BT, long ldbt, long sB,
               float* __restrict__ Cout, long ldc, long sC,
               int M, int N, int K)
{
    const int batch = blockIdx.z;
    const int m0 = blockIdx.y * 64;
    const int n0 = blockIdx.x * 64;

    __shared__ __align__(16) unsigned short As[64*32];
    __shared__ __align__(16) unsigned short Bs[64*32];

    const int tid = threadIdx.x;
    const int wave = tid >> 6, lane = tid & 63;
    const int wr = wave >> 1, wc = wave & 1;
    const int lr = lane & 15, lk = lane >> 4;
    const int rbase = wr*32, cbase = wc*32;

    const void* Ab = AF32 ? (const void*)((const float*)Av + (long)batch*sA)
                          : (const void*)((const unsigned short*)Av + (long)batch*sA);
    const unsigned short* Bb = BT + (long)batch*sB;

    f32x4_t acc[2][2];
#pragma unroll
    for (int i = 0; i < 2; ++i)
#pragma unroll
    for (int j = 0; j < 2; ++j)
        acc[i][j] = (f32x4_t){0.f,0.f,0.f,0.f};

    for (int kk = 0; kk < K; kk += 32) {
        stage_tile<64,AF32>(Ab, lda, m0, kk, K, M, As, tid);
        stage_tile<64,false>((const void*)Bb, ldbt, n0, kk, K, N, Bs, tid);
        __syncthreads();
        bf16x8_t af[2], bfv[2];
#pragma unroll
        for (int i = 0; i < 2; ++i) {
            int row = rbase + i*16 + lr;
            af[i] = *(const bf16x8_t*)&As[row*32 + ((lk ^ (row & 3)) << 3)];
            int col = cbase + i*16 + lr;
            bfv[i] = *(const bf16x8_t*)&Bs[col*32 + ((lk ^ (col & 3)) << 3)];
        }
#pragma unroll
        for (int i = 0; i < 2; ++i)
#pragma unroll
        for (int j = 0; j < 2; ++j)
            acc[i][j] = __builtin_amdgcn_mfma_f32_16x16x32_bf16(af[i], bfv[j], acc[i][j], 0, 0, 0);
        __syncthreads();
    }

    float* C = Cout + (long)batch * sC;
#pragma unroll
    for (int i = 0; i < 2; ++i) {
#pragma unroll
        for (int r = 0; r < 4; ++r) {
            int gm = m0 + rbase + i*16 + lk*4 + r;
            if (gm >= M) continue;
#pragma unroll
            for (int j = 0; j < 2; ++j) {
                int gn = n0 + cbase + j*16 + lr;
                if (gn < N) C[(long)gm*ldc + gn] = acc[i][j][r];
            }
        }
    }
}

// ---------------- k0: fp32 split-K GEMM, BM=256 (all M), BN=64 (all N) ----------------
__global__ __launch_bounds__(256)
void k0_gemm(const float* __restrict__ A, const float* __restrict__ B,
             float* __restrict__ Cpart, int K, int kChunk)
{
    const int z = blockIdx.x;
    const int kStart = z * kChunk;
    const int kEnd = (kStart + kChunk < K) ? (kStart + kChunk) : K;
    __shared__ __align__(16) float As[16][260];
    __shared__ __align__(16) float Bs[16][64];
    const int tid = threadIdx.x;
    const int tx = tid & 15, ty = tid >> 4;
    float acc[16][4] = {};
    for (int kk = kStart; kk < kEnd; kk += 16) {
#pragma unroll
        for (int i = 0; i < 4; ++i) {
            int row = (tid >> 2) + i*64;
            int k4 = (tid & 3) * 4;
            long gk = kk + k4;
            float4 f = {0,0,0,0};
            if (gk + 3 < (long)kEnd) f = *(const float4*)(A + (long)row*K + gk);
            else {
                if (gk+0 < kEnd) f.x = A[(long)row*K+gk+0];
                if (gk+1 < kEnd) f.y = A[(long)row*K+gk+1];
                if (gk+2 < kEnd) f.z = A[(long)row*K+gk+2];
                if (gk+3 < kEnd) f.w = A[(long)row*K+gk+3];
            }
            As[k4+0][row]=f.x; As[k4+1][row]=f.y; As[k4+2][row]=f.z; As[k4+3][row]=f.w;
        }
        {
            int k = tid >> 4, n = (tid & 15) * 4;
            long gk = kk + k;
            float4 f = {0,0,0,0};
            if (gk < kEnd) f = *(const float4*)(B + gk*64 + n);
            *(float4*)&Bs[k][n] = f;
        }
        __syncthreads();
#pragma unroll
        for (int k = 0; k < 16; ++k) {
            float4 b4 = *reinterpret_cast<const float4*>(&Bs[k][tx*4]);
            float bw[4] = {b4.x,b4.y,b4.z,b4.w};
#pragma unroll
            for (int i4 = 0; i4 < 4; ++i4) {
                float4 a4 = *reinterpret_cast<const float4*>(&As[k][ty*16 + i4*4]);
                float av[4] = {a4.x,a4.y,a4.z,a4.w};
#pragma unroll
                for (int r = 0; r < 4; ++r)
#pragma unroll
                for (int j = 0; j < 4; ++j) acc[i4*4+r][j] += av[r]*bw[j];
            }
        }
        __syncthreads();
    }
    float* cp = Cpart + (long)z*256*64;
#pragma unroll
    for (int i = 0; i < 16; ++i) {
        int gm = ty*16 + i;
#pragma unroll
        for (int j = 0; j < 4; ++j)
            cp[(long)gm*64 + tx*4 + j] = acc[i][j];
    }
}

__global__ __launch_bounds__(256)
void k_reduce_splitk(const float* __restrict__ Cpart, float* __restrict__ out,
                     long ldcOut, long sOut,
                     const float* __restrict__ bias, long sBias,
                     int nbatch, int M, int N, int nsplit)
{
    long idx = (long)blockIdx.x*256 + threadIdx.x;
    long total = (long)nbatch*M*N;
    if (idx >= total) return;
    int n = idx % N; long t = idx / N;
    int m = t % M; int bi = t / M;
    const float* p = Cpart + ((long)bi*nsplit)*((long)M*N) + (long)m*N + n;
    float s = bias ? bias[(long)bi*sBias + n] : 0.f;
#pragma unroll 8
    for (int si = 0; si < nsplit; ++si) s += p[(long)si*M*N];
    out[(long)bi*sOut + (long)m*ldcOut + n] = s;
}

// ---------------- q ----------------
__global__ __launch_bounds__(256)
void k_q(const float* __restrict__ opt, const float* __restrict__ hx,
         const float* __restrict__ Wq, float* __restrict__ q)
{
    int idx = blockIdx.x*256 + threadIdx.x;
    if (idx >= NB*NU*NDK) return;
    int k = idx & 63; int t = idx >> 6;
    int u = t & 7; int b = t >> 3;
    const float* hxr = hx + (long)(b*NU+u)*NH;
    float acc = 0.f;
    for (int o = 0; o < NO; ++o) {
        const float* w = Wq + ((long)(o*NU+u)*NH)*NDK + k;
        float s = 0.f;
        for (int h = 0; h < NH; ++h) s += hxr[h] * w[(long)h*NDK];
        acc += opt[b*NO+o] * s;
    }
    q[idx] = acc;
}

// ---------------- scores + softmax(2) + attn_in + real ----------------
__global__ __launch_bounds__(64)
void k_attn(const float* __restrict__ q, const float* __restrict__ k0,
            const float* __restrict__ bk, const float* __restrict__ v0,
            const float* __restrict__ bv, float* __restrict__ attn,
            float* __restrict__ real)
{
    int bu = blockIdx.x;
    int lane = threadIdx.x;
    int b = bu >> 3;
    float qv = q[(long)bu*NDK + lane];
    float s0 = qv * k0[(long)b*NDK + lane];
    float s1 = qv * bk[lane];
    for (int off = 32; off; off >>= 1) {
        s0 += __shfl_xor(s0, off);
        s1 += __shfl_xor(s1, off);
    }
    s0 *= 0.125f; s1 *= 0.125f;
    float mx = fmaxf(s0, s1);
    float e0 = expf(s0-mx), e1 = expf(s1-mx);
    float inv = 1.f/(e0+e1);
    float p0 = e0*inv, p1 = e1*inv;
    if (lane == 0) real[bu] = p0;
    for (int v = lane; v < NV; v += 64)
        attn[(long)bu*NV + v] = p0*v0[(long)b*NV + v] + p1*bv[v];
}

// ---------------- top-k mask ----------------
__global__ void k_topk(const float* __restrict__ real, float* __restrict__ mask)
{
    int b = blockIdx.x*blockDim.x + threadIdx.x;
    if (b >= NB) return;
    float v[NU]; bool sel[NU];
#pragma unroll
    for (int i = 0; i < NU; ++i) { v[i] = real[b*NU+i]; sel[i] = false; }
    for (int t = 0; t < NKT; ++t) {
        int best = 0; float bvv = -1e30f;
#pragma unroll
        for (int i = 0; i < NU; ++i)
            if (!sel[i] && v[i] > bvv) { bvv = v[i]; best = i; }
        sel[best] = true;
    }
#pragma unroll
    for (int i = 0; i < NU; ++i) mask[b*NU+i] = sel[i] ? 1.f : 0.f;
}

// ---------------- LSTM gates (pre = pre_i + pre_h + blstm) ----------------
__global__ __launch_bounds__(256)
void k_gates(const float* __restrict__ pre_i, const float* __restrict__ pre_h,
             const float* __restrict__ blstm, const float* __restrict__ cx,
             float* __restrict__ cn, float* __restrict__ hn)
{
    int idx = blockIdx.x*256 + threadIdx.x;
    if (idx >= NB*NU*NH) return;
    int h = idx & 127; int bu = idx >> 7;
    int u = bu & 7;
    const float* pi = pre_i + (long)bu*512;
    const float* ph = pre_h + (long)bu*512;
    const float* bl = blstm + (long)u*512;
    float ig = pi[h]     + ph[h]     + bl[h];
    float fg = pi[128+h] + ph[128+h] + bl[128+h];
    float gg = pi[256+h] + ph[256+h] + bl[256+h];
    float og = pi[384+h] + ph[384+h] + bl[384+h];
    float si = 1.f/(1.f+expf(-ig));
    float sf = 1.f/(1.f+expf(-fg));
    float so = 1.f/(1.f+expf(-og));
    float c = sf*cx[idx] + si*tanhf(gg);
    cn[idx] = c;
    hn[idx] = so*tanhf(c);
}

// ---------------- qc,kc ----------------
__global__ __launch_bounds__(256)
void k_qckc(const float* __restrict__ hn, const float* __restrict__ Wqc,
            const float* __restrict__ Wkc, float* __restrict__ qc,
            float* __restrict__ kc)
{
    int idx = blockIdx.x*256 + threadIdx.x;
    if (idx >= NB*NU*64) return;
    int j = idx & 63; int t = idx >> 6;
    int u = t & 7; int b = t >> 3;
    int k = j & 31;
    const float* W = (j < 32 ? Wqc : Wkc) + ((long)u*NH)*NDKC + k;
    const float* h = hn + (long)(b*NU+u)*NH;
    float s = 0.f;
    for (int hh = 0; hh < NH; ++hh) s += h[hh]*W[(long)hh*NDKC];
    (j < 32 ? qc : kc)[(b*NU+u)*NDKC + k] = s;
}

// ---------------- comm probs ----------------
__global__ __launch_bounds__(64)
void k_cp(const float* __restrict__ qc, const float* __restrict__ kc,
          const float* __restrict__ mask, float* __restrict__ cp)
{
    int b = blockIdx.x;
    int lane = threadIdx.x;
    int u = lane >> 3, n = lane & 7;
    const float* qr = qc + (long)(b*NU+u)*NDKC;
    const float* kr = kc + (long)(b*NU+n)*NDKC;
    float d = 0.f;
    for (int k = 0; k < NDKC; ++k) d += qr[k]*kr[k];
    d *= 0.17677669529663687f;
    float mx = d;
    for (int off = 4; off; off >>= 1) mx = fmaxf(mx, __shfl_xor(mx, off, 8));
    float e = expf(d-mx);
    float sm = e;
    for (int off = 4; off; off >>= 1) sm += __shfl_xor(sm, off, 8);
    cp[b*64 + lane] = (e/sm) * mask[b*NU+u];
}

// ---------------- ctx (bf16 in/out) ----------------
__global__ __launch_bounds__(256)
void k_ctx(const unsigned short* __restrict__ vc, const float* __restrict__ cp,
           unsigned short* __restrict__ ctx)
{
    int b = blockIdx.y;
    int v = blockIdx.x*256 + threadIdx.x;
    __shared__ float cps[64];
    if (threadIdx.x < 64) cps[threadIdx.x] = cp[b*64 + threadIdx.x];
    __syncthreads();
    if (v >= NCV) return;
    float vv[NU];
#pragma unroll
    for (int n = 0; n < NU; ++n) vv[n] = bf2f(vc[((long)(b*NU+n))*NCV + v]);
#pragma unroll
    for (int u = 0; u < NU; ++u) {
        float s = 0.f;
#pragma unroll
        for (int n = 0; n < NU; ++n) s += cps[u*8+n]*vv[n];
        ctx[((long)(b*NU+u))*NCV + v] = f2bf(s);
    }
}

// ---------------- fused tail: blend + hy-sum + logits-softmax ----------------
__global__ __launch_bounds__(128)
void k_tail(const float* __restrict__ hn, const float* __restrict__ cn,
            const float* __restrict__ hcw, const float* __restrict__ hx,
            const float* __restrict__ cx, const float* __restrict__ mask,
            const float* __restrict__ piw, const float* __restrict__ pib,
            float* __restrict__ hy, float* __restrict__ cy,
            float* __restrict__ out)
{
    const int b = blockIdx.x;
    const int h = threadIdx.x;
    __shared__ float hs[128];
    __shared__ float lg[28];
    float s = 0.f;
#pragma unroll
    for (int u = 0; u < NU; ++u) {
        int idx = (b*NU+u)*NH + h;
        float m = mask[b*NU+u];
        float hyv = m*(hn[idx]+hcw[idx]) + (1.f-m)*hx[idx];
        float cyv = m*cn[idx] + (1.f-m)*cx[idx];
        hy[idx] = hyv; cy[idx] = cyv;
        s += hyv;
    }
    hs[h] = s;
    __syncthreads();
    if (h < 28) {
        int o = h / 7, a = h - o*7;
        float acc = pib[o*NA+a];
        for (int k = 0; k < NH; ++k) acc += hs[k] * piw[((long)o*NH+k)*NA + a];
        lg[h] = acc;
    }
    __syncthreads();
    if (h < NO) {
        float mx = lg[h*NA];
#pragma unroll
        for (int a = 1; a < NA; ++a) mx = fmaxf(mx, lg[h*NA+a]);
        float e[NA]; float sm = 0.f;
#pragma unroll
        for (int a = 0; a < NA; ++a) { e[a] = expf(lg[h*NA+a]-mx); sm += e[a]; }
        float inv = 1.f/sm;
#pragma unroll
        for (int a = 0; a < NA; ++a) out[(long)b*NO*NA + h*NA + a] = e[a]*inv;
    }
}

extern "C" void kernel_launch(void* const* d_in, const int* in_sizes, int n_in,
                              void* d_out, int out_size, void* d_ws, size_t ws_size,
                              hipStream_t stream) {
    const float* x    = (const float*)d_in[0];
    const float* hx   = (const float*)d_in[1];
    const float* cx   = (const float*)d_in[2];
    const float* opt  = (const float*)d_in[3];
    const float* c1w  = (const float*)d_in[4];
    const float* c1b  = (const float*)d_in[5];
    const float* c2w  = (const float*)d_in[6];
    const float* c2b  = (const float*)d_in[7];
    const float* c3w  = (const float*)d_in[8];
    const float* c3b  = (const float*)d_in[9];
    const float* Wk   = (const float*)d_in[10];
    const float* bk   = (const float*)d_in[11];
    const float* Wv   = (const float*)d_in[12];
    const float* bv   = (const float*)d_in[13];
    const float* Wq   = (const float*)d_in[14];
    const float* Wi   = (const float*)d_in[15];
    const float* Wh   = (const float*)d_in[16];
    const float* blstm= (const float*)d_in[17];
    const float* Wqc  = (const float*)d_in[18];
    const float* Wkc  = (const float*)d_in[19];
    const float* Wvc  = (const float*)d_in[20];
    const float* Wout = (const float*)d_in[21];
    const float* piw  = (const float*)d_in[22];
    const float* pib  = (const float*)d_in[23];

    float* out = (float*)d_out;
    float* hy  = out + (long)NB*NO*NA;
    float* cy  = hy + (long)NB*NU*NH;

    float* ws = (float*)d_ws;
    long o = 0;
    float* b_k0  = ws + o; o += 16384;
    float* b_v0  = ws + o; o += 102400;
    float* b_q   = ws + o; o += 131072;
    float* b_at  = ws + o; o += 819200;
    float* b_re  = ws + o; o += 2048;
    float* b_mk  = ws + o; o += 2048;
    float* b_pre = ws + o; o += 1048576;
    float* b_cn  = ws + o; o += 262144;
    float* b_hn  = ws + o; o += 262144;
    float* b_qc  = ws + o; o += 65536;
    float* b_kc  = ws + o; o += 65536;
    float* b_cp  = ws + o; o += 16384;
    float* b_hc  = ws + o; o += 262144;
    float* b_hs  = ws + o; o += 32768;
    // o == 3088384 (fixed region)
    //
    // Region spans (floats), all < NEED = 33,419,264 (133.7 MB, PROVEN):
    //  P1OFF  3,088,384: S1 p1 [3,936,256 -> 7,024,640]
    //                    S2 k0 partials [5,242,880 -> 8,331,264]  (p1/c2 dead)
    //                    S3-S5 WvT [10,764,800 -> 13,853,184]     (after k0 reduce)
    //                    S8+ WvcT [-> 6,533,120], WoutT [-> 9,977,856],
    //                        partW [-> 14,172,160]  (all < EMBOFF)
    //  C2OFF  7,024,640: S1 c2 [7,372,800 -> 14,397,440]  (dead after conv3)
    //  EMBOFF 14,397,440: S1-S2 emb32 [13,778,944 -> 28,176,384] (dead after k0)
    //                     S5 v0 partials [8,908,800 -> 23,306,240]
    //                     S9+ vc16 [-> 21,286,912], ctx16 [-> 28,176,384]
    //  TOFF   28,176,384: S1-S5 emb16 [3,444,736 -> 31,621,120]  (from conv3 epilogue)
    //                     S7 WiT [-> 28,995,584], WhT [-> 29,257,728],
    //                        pre_h [-> 30,306,304]  (emb16 dead after v0)
    constexpr long P1OFF  = 3088384;
    constexpr long C2OFF  = 7024640;
    constexpr long EMBOFF = 14397440;
    constexpr long TOFF   = 28176384;
    constexpr long NEED   = TOFF + 5242880;   // 33,419,264 floats (proven)
    if (ws_size < (size_t)NEED * sizeof(float)) return;

    float* p1    = ws + P1OFF;
    float* c2    = ws + C2OFF;
    float* emb   = ws + EMBOFF;
    float* partK = ws + P1OFF;                                   // k0 partials (S2, p1/c2 dead)
    float* partV = ws + EMBOFF;                                  // v0 partials (S5, emb32 dead)
    unsigned short* emb16 = (unsigned short*)(ws + TOFF);        // S1-S5 (conv3 epilogue)
    unsigned short* WvT   = (unsigned short*)(ws + P1OFF);       // S3-S5 (after k0 reduce)
    unsigned short* WiT   = (unsigned short*)(ws + TOFF);        // S7 (emb16 dead)
    unsigned short* WhT   = (unsigned short*)(ws + TOFF + 819200);
    float* pre_h          = ws + TOFF + 819200 + 262144;
    unsigned short* WvcT  = (unsigned short*)(ws + P1OFF);       // S8 (WvT dead)
    unsigned short* WoutT = (unsigned short*)(ws + P1OFF + 3444736);
    float* partW          = ws + P1OFF + 2*3444736;
    unsigned short* vc16  = (unsigned short*)(ws + EMBOFF);      // S9 (v0 partials dead)
    unsigned short* ctx16 = (unsigned short*)(ws + EMBOFF + 6889472);

    // S1) conv stack (conv3 emits emb32 + emb16 in one pass; bit-identical RNE)
    k_conv1<<<(NB*16*H1*W1 + 255)/256, 256, 0, stream>>>(x, c1w, c1b, p1);
    conv2x2_gemm<32,16,H1,W1,H2,W2><<<NB*((H2*W2+255)/256), 256, 0, stream>>>(p1, c2w, c2b, c2, nullptr);
    conv2x2_gemm<64,32,H2,W2,H3,W3><<<NB*((H3*W3+127)/128), 256, 0, stream>>>(c2, c3w, c3b, emb, emb16);

    // S2) k0 = emb@Wk + bk  (fp32 — precision-critical for top-k; partials in dead p1/c2)
    k0_gemm<<<320, 256, 0, stream>>>(emb, Wk, partK, NE, 176);
    k_reduce_splitk<<<(NB*NDK + 255)/256, 256, 0, stream>>>(
        partK, b_k0, NDK, 0, bk, 0, 1, NB, NDK, 320);

    // S3) Wv -> bf16 transposed [400][53824]  (k0 partials dead)
    k_f2bt<<<dim3(13, 1682, 1), 256, 0, stream>>>(Wv, WvT, NE, NV, 0);

    // S5) v0 = emb16@Wv + bv  (bf16 MFMA, 128x128, S=87; partials at EMBOFF, emb32 dead)
    bgemm_splitk<128,128,false><<<dim3(4,2,87), 256, 0, stream>>>(
        emb16, NE, 0, WvT, NE, 0, partV, NB, NV, NE, 87, 624);
    k_reduce_splitk<<<(NB*NV + 255)/256, 256, 0, stream>>>(
        partV, b_v0, NV, 0, bv, 0, 1, NB, NV, 87);

    // S6) q / attention / top-k
    k_q<<<(NB*NU*NDK + 255)/256, 256, 0, stream>>>(opt, hx, Wq, b_q);
    k_attn<<<NB*NU, 64, 0, stream>>>(b_q, b_k0, bk, b_v0, bv, b_at, b_re);
    k_topk<<<1, 256, 0, stream>>>(b_re, b_mk);

    // S7) LSTM pre in bf16 MFMA (fp32 accum/out) — proven round 10, absmax unchanged
    k_f2bt<<<dim3(16, 13, 8), 256, 0, stream>>>(Wi, WiT, NV, 512, (long)NV*512);
    k_f2bt<<<dim3(16, 4, 8), 256, 0, stream>>>(Wh, WhT, NH, 512, (long)NH*512);
    bgemm_f32<true><<<dim3(8, 4, NU), 256, 0, stream>>>(
        b_at, (long)NU*NV, NV, WiT, NV, (long)512*NV,
        b_pre, (long)NU*512, 512, NB, 512, NV);
    bgemm_f32<true><<<dim3(8, 4, NU), 256, 0, stream>>>(
        hx, (long)NU*NH, NH, WhT, NH, (long)512*NH,
        pre_h, (long)NU*512, 512, NB, 512, NH);
    k_gates<<<(NB*NU*NH + 255)/256, 256, 0, stream>>>(b_pre, pre_h, blstm, cx, b_cn, b_hn);

    // S8) convert Wvc/Wout (WvT dead after v0)
    k_f2bt<<<dim3(211, 4, 8), 256, 0, stream>>>(Wvc, WvcT, NH, NCV, (long)NH*NCV);
    k_f2bt<<<dim3(4, 211, 8), 256, 0, stream>>>(Wout, WoutT, NCV, NH, (long)NCV*NH);

    // S9) vc = h_new@Wvc (bf16 MFMA direct, bf16 out)  (v0 partials dead)
    bgemm_direct<true><<<dim3((NCV+127)/128, 2, NU), 256, 0, stream>>>(
        b_hn, (long)NU*NH, NH, WvcT, NH, (long)NCV*NH,
        vc16, (long)NU*NCV, NCV, NB, NCV, NH);

    // S10) comm probs + ctx
    k_qckc<<<(NB*NU*64 + 255)/256, 256, 0, stream>>>(b_hn, Wqc, Wkc, b_qc, b_kc);
    k_cp<<<NB, 64, 0, stream>>>(b_qc, b_kc, b_mk, b_cp);
    k_ctx<<<dim3((NCV+255)/256, NB), 256, 0, stream>>>(vc16, b_cp, ctx16);

    // S11) hcomm_w = ctx@Wout (bf16 MFMA split-K 16)
    bgemm_splitk<64,64,false><<<dim3(2,4,NU*16), 256, 0, stream>>>(
        ctx16, (long)NU*NCV, NCV, WoutT, NCV, (long)NCV*NH,
        partW, NB, NH, NCV, 16, 448);
    k_reduce_splitk<<<(NU*NB*NH + 255)/256, 256, 0, stream>>>(
        partW, b_hc, (long)NU*NH, NH, nullptr, 0, NU, NB, NH, 16);

    // S12) fused blend + hy-sum + logits
    k_tail<<<NB, 128, 0, stream>>>(b_hn, b_cn, b_hc, hx, cx, b_mk, piw, pib, hy, cy, out);
}

// Round 12
// 465.548 us; speedup vs baseline: 1.0437x; 1.0437x over previous
//
#include <hip/hip_runtime.h>
#include <math.h>

namespace {
constexpr int NB  = 256;
constexpr int NU  = 8;
constexpr int NKT = 4;
constexpr int NH  = 128;
constexpr int NO  = 4;
constexpr int NA  = 7;
constexpr int NV  = 400;
constexpr int NE  = 53824;
constexpr int NCV = 6728;
constexpr int NDK = 64;
constexpr int NDKC= 32;

constexpr int H1 = 31, W1 = 31;
constexpr int H2 = 30, W2 = 30;
constexpr int H3 = 29, W3 = 29;
}

typedef __attribute__((ext_vector_type(8))) short bf16x8_t;
typedef __attribute__((ext_vector_type(4))) float f32x4_t;

__device__ __forceinline__ unsigned short f2bf(float f) {
    unsigned int u = __float_as_uint(f);
    u += 0x7FFFu + ((u >> 16) & 1u);   // RNE
    return (unsigned short)(u >> 16);
}
__device__ __forceinline__ float bf2f(unsigned short h) {
    return __uint_as_float((unsigned int)h << 16);
}

// ---------------- conv1 (2x2, 3->16) + relu + maxpool2 ----------------
__global__ __launch_bounds__(256)
void k_conv1(const float* __restrict__ x, const float* __restrict__ w,
             const float* __restrict__ bias, float* __restrict__ out)
{
    __shared__ float ws[16*3*2*2];
    __shared__ float bs[16];
    int tid = threadIdx.x;
    if (tid < 192) ws[tid] = w[tid];
    if (tid < 16)  bs[tid] = bias[tid];
    __syncthreads();
    long idx = (long)blockIdx.x*256 + tid;
    if (idx >= (long)NB*16*H1*W1) return;
    int pw = idx % W1; long t = idx / W1;
    int ph = t % H1; t /= H1;
    int oc = t % 16; int b = t / 16;
    float mx = 0.f;
#pragma unroll
    for (int dh = 0; dh < 2; ++dh)
#pragma unroll
    for (int dw = 0; dw < 2; ++dw) {
        int h = 2*ph + dh, ww = 2*pw + dw;
        float s = bs[oc];
#pragma unroll
        for (int kh = 0; kh < 2; ++kh)
#pragma unroll
        for (int kw = 0; kw < 2; ++kw) {
            const float* xp = x + (((long)b*64 + (h+kh))*64 + (ww+kw))*3;
#pragma unroll
            for (int ic = 0; ic < 3; ++ic)
                s += xp[ic] * ws[((oc*3+ic)*2+kh)*2+kw];
        }
        mx = fmaxf(mx, s);
    }
    out[idx] = mx;
}

// ---------------- conv 2x2 as implicit GEMM, 4x4 micro (round-10 structure) ----------------
// Per-thread Bs column n = tid & (NT-1) is loop-invariant -> oh/ow div/mod hoisted
// out of the K loop (bit-identical addresses and accumulation order vs round 10).
template<int OC, int IC, int HIN, int WIN, int HOUT, int WOUT>
__global__ __launch_bounds__(256)
void conv2x2_gemm(const float* __restrict__ in, const float* __restrict__ w,
                  const float* __restrict__ bias, float* __restrict__ out)
{
    constexpr int K    = IC*4;
    constexpr int TY   = OC/4;          // 16 (OC=64) or 8 (OC=32)
    constexpr int TX   = 256/TY;        // 16 or 32
    constexpr int NT   = TX*4;          // 64 or 128
    constexpr int SPAT = HOUT*WOUT;
    constexpr int NBLK = (SPAT + NT - 1)/NT;

    const int b  = blockIdx.x / NBLK;
    const int n0 = (blockIdx.x % NBLK) * NT;

    __shared__ __align__(16) float As[16][OC+4];
    __shared__ __align__(16) float Bs[16][NT];

    const int tid = threadIdx.x;
    const int tx = tid % TX, ty = tid / TX;
    float acc[4][4] = {};
    const float* inb = in + (long)b*IC*HIN*WIN;

    // hoisted: this thread always stages column nIdx of Bs
    const int nIdx = tid & (NT-1);
    int ohw = 0; bool nOk = false;
    {
        int s = n0 + nIdx;
        if (s < SPAT) { ohw = (s / WOUT) * WIN + (s % WOUT); nOk = true; }
    }

    for (int kk = 0; kk < K; kk += 16) {
#pragma unroll
        for (int i = 0; i < OC*16/256; ++i) {
            int lin = tid + i*256;
            int m = lin / 16, k = lin % 16;
            As[k][m] = w[m*K + kk + k];
        }
#pragma unroll
        for (int i = 0; i < 16*NT/256; ++i) {
            int lin = tid + i*256;
            int k = lin / NT;               // n == nIdx (lin % NT == tid % NT)
            int gk = kk + k;
            int ic = gk >> 2, tap = gk & 3;
            float v = 0.f;
            if (nOk)
                v = inb[ic*HIN*WIN + ohw + (tap>>1)*WIN + (tap&1)];
            Bs[k][nIdx] = v;
        }
        __syncthreads();
#pragma unroll
        for (int k = 0; k < 16; ++k) {
            float4 a4 = *reinterpret_cast<const float4*>(&As[k][ty*4]);
            float4 b4 = *reinterpret_cast<const float4*>(&Bs[k][tx*4]);
            float av[4] = {a4.x,a4.y,a4.z,a4.w};
            float bw[4] = {b4.x,b4.y,b4.z,b4.w};
#pragma unroll
            for (int i = 0; i < 4; ++i)
#pragma unroll
            for (int j = 0; j < 4; ++j) acc[i][j] += av[i]*bw[j];
        }
        __syncthreads();
    }
#pragma unroll
    for (int i = 0; i < 4; ++i) {
        int gm = ty*4 + i;
        float bi = bias[gm];
#pragma unroll
        for (int j = 0; j < 4; ++j) {
            int s = n0 + tx*4 + j;
            if (s < SPAT)
                out[((long)b*OC + gm)*SPAT + s] = fmaxf(acc[i][j] + bi, 0.f);
        }
    }
}

// ---------------- fp32 -> bf16 elementwise convert (n multiple of 8) ----------------
__global__ __launch_bounds__(256)
void k_cvt(const float* __restrict__ in, unsigned short* __restrict__ out, long n)
{
    long i = ((long)blockIdx.x*256 + threadIdx.x) * 8;
    if (i >= n) return;
    float4 a = *(const float4*)(in + i);
    float4 b = *(const float4*)(in + i + 4);
    uint4 u;
    u.x = (unsigned)f2bf(a.x) | ((unsigned)f2bf(a.y) << 16);
    u.y = (unsigned)f2bf(a.z) | ((unsigned)f2bf(a.w) << 16);
    u.z = (unsigned)f2bf(b.x) | ((unsigned)f2bf(b.y) << 16);
    u.w = (unsigned)f2bf(b.z) | ((unsigned)f2bf(b.w) << 16);
    *(uint4*)(out + i) = u;
}

// ---------------- fp32 -> bf16 transposed convert: in [B][R][Cc] -> out [B][Cc][R] ----------------
__global__ __launch_bounds__(256)
void k_f2bt(const float* __restrict__ in, unsigned short* __restrict__ out,
            int R, int Cc, long sIn)
{
    __shared__ unsigned short t[32][33];
    const int b = blockIdx.z;
    const int r0 = blockIdx.y * 32, c0 = blockIdx.x * 32;
    const float* ip = in + (long)b * sIn;
    unsigned short* op = out + (long)b * sIn;
    const int tid = threadIdx.x;
    {
        int rr = tid >> 3, c4 = (tid & 7) * 4;
        int gr = r0 + rr;
        unsigned short h0=0,h1=0,h2=0,h3=0;
        if (gr < R) {
            if (c0 + c4 + 3 < Cc) {
                float4 f = *(const float4*)(ip + (long)gr*Cc + c0 + c4);
                h0=f2bf(f.x); h1=f2bf(f.y); h2=f2bf(f.z); h3=f2bf(f.w);
            } else {
                if (c0+c4+0 < Cc) h0 = f2bf(ip[(long)gr*Cc + c0+c4+0]);
                if (c0+c4+1 < Cc) h1 = f2bf(ip[(long)gr*Cc + c0+c4+1]);
                if (c0+c4+2 < Cc) h2 = f2bf(ip[(long)gr*Cc + c0+c4+2]);
                if (c0+c4+3 < Cc) h3 = f2bf(ip[(long)gr*Cc + c0+c4+3]);
            }
        }
        t[rr][c4+0]=h0; t[rr][c4+1]=h1; t[rr][c4+2]=h2; t[rr][c4+3]=h3;
    }
    __syncthreads();
    {
        int cc = tid >> 3, r4 = (tid & 7) * 4;
        int gc = c0 + cc;
        if (gc < Cc && r0 + r4 < R) {
            if (r0 + r4 + 3 < R) {
                *(ushort4*)(op + (long)gc*R + r0 + r4) =
                    make_ushort4(t[r4+0][cc], t[r4+1][cc], t[r4+2][cc], t[r4+3][cc]);
            } else {
#pragma unroll
                for (int j = 0; j < 4; ++j)
                    if (r0 + r4 + j < R) op[(long)gc*R + r0 + r4 + j] = t[r4+j][cc];
            }
        }
    }
}

// ---------------- bf16 MFMA GEMM staging, 16B-wide ----------------
template<int ROWS, bool F32>
__device__ __forceinline__ void stage_tile(const void* __restrict__ Av, long lda,
                                           int m0, int kk, int kEnd, int Mlim,
                                           unsigned short* lds, int tid)
{
#pragma unroll
    for (int i = 0; i < ROWS/64; ++i) {
        int row = (tid >> 2) + i*64;
        int blk = tid & 3;
        long gm = m0 + row;
        long gk = kk + blk*8;
        ushort4 lo = make_ushort4(0,0,0,0), hi = make_ushort4(0,0,0,0);
        if (gm < Mlim && gk < kEnd) {
            if (F32) {
                const float* A = (const float*)Av + gm*lda + gk;
                float4 f0 = *(const float4*)(A);
                float4 f1 = *(const float4*)(A + 4);
                lo = make_ushort4(f2bf(f0.x),f2bf(f0.y),f2bf(f0.z),f2bf(f0.w));
                hi = make_ushort4(f2bf(f1.x),f2bf(f1.y),f2bf(f1.z),f2bf(f1.w));
            } else {
                const unsigned short* A = (const unsigned short*)Av + gm*lda + gk;
                lo = *(const ushort4*)(A);
                hi = *(const ushort4*)(A + 4);
            }
        }
        int p = (blk ^ (row & 3)) << 3;
        *(ushort4*)&lds[row*32 + p]     = lo;
        *(ushort4*)&lds[row*32 + p + 4] = hi;
    }
}

template<int BM, int BN, bool AF32>
__global__ __launch_bounds__(256)
void bgemm_splitk(const void* __restrict__ Av, long lda, long sA,
                  const unsigned short* __restrict__ BT, long ldbt, long sB,
                  float* __restrict__ Cpart,
                  int M, int N, int K, int nsplit, int kChunk)
{
    constexpr int MR = BM/32, NR = BN/32;
    const int z = blockIdx.z;
    const int batch = z / nsplit, split = z - batch*nsplit;
    const int kStart = split * kChunk;
    const int kEnd = (kStart + kChunk < K) ? (kStart + kChunk) : K;
    const int m0 = blockIdx.y * BM;
    const int n0 = blockIdx.x * BN;

    __shared__ __align__(16) unsigned short As[BM*32];
    __shared__ __align__(16) unsigned short Bs[BN*32];

    const int tid = threadIdx.x;
    const int wave = tid >> 6, lane = tid & 63;
    const int wr = wave >> 1, wc = wave & 1;
    const int lr = lane & 15, lk = lane >> 4;
    const int rbase = wr*(BM/2), cbase = wc*(BN/2);

    const void* Ab = AF32 ? (const void*)((const float*)Av + (long)batch*sA)
                          : (const void*)((const unsigned short*)Av + (long)batch*sA);
    const unsigned short* Bb = BT + (long)batch*sB;

    f32x4_t acc[MR][NR];
#pragma unroll
    for (int i = 0; i < MR; ++i)
#pragma unroll
    for (int j = 0; j < NR; ++j)
        acc[i][j] = (f32x4_t){0.f,0.f,0.f,0.f};

    for (int kk = kStart; kk < kEnd; kk += 32) {
        stage_tile<BM,AF32>(Ab, lda, m0, kk, kEnd, M, As, tid);
        stage_tile<BN,false>((const void*)Bb, ldbt, n0, kk, kEnd, N, Bs, tid);
        __syncthreads();
        bf16x8_t af[MR], bfv[NR];
#pragma unroll
        for (int i = 0; i < MR; ++i) {
            int row = rbase + i*16 + lr;
            af[i] = *(const bf16x8_t*)&As[row*32 + ((lk ^ (row & 3)) << 3)];
        }
#pragma unroll
        for (int j = 0; j < NR; ++j) {
            int col = cbase + j*16 + lr;
            bfv[j] = *(const bf16x8_t*)&Bs[col*32 + ((lk ^ (col & 3)) << 3)];
        }
#pragma unroll
        for (int i = 0; i < MR; ++i)
#pragma unroll
        for (int j = 0; j < NR; ++j)
            acc[i][j] = __builtin_amdgcn_mfma_f32_16x16x32_bf16(af[i], bfv[j], acc[i][j], 0, 0, 0);
        __syncthreads();
    }

    const long cb2 = (long)z * M * N;
#pragma unroll
    for (int i = 0; i < MR; ++i) {
#pragma unroll
        for (int r = 0; r < 4; ++r) {
            int gm = m0 + rbase + i*16 + lk*4 + r;
            if (gm >= M) continue;
#pragma unroll
            for (int j = 0; j < NR; ++j) {
                int gn = n0 + cbase + j*16 + lr;
                if (gn < N) Cpart[cb2 + (long)gm*N + gn] = acc[i][j][r];
            }
        }
    }
}

// direct bf16 GEMM (full K), bf16 output, 128x128 tile
template<bool AF32>
__global__ __launch_bounds__(256)
void bgemm_direct(const void* __restrict__ Av, long lda, long sA,
                  const unsigned short* __restrict__ BT, long ldbt, long sB,
                  unsigned short* __restrict__ Cout, long ldc, long sC,
                  int M, int N, int K)
{
    const int batch = blockIdx.z;
    const int m0 = blockIdx.y * 128;
    const int n0 = blockIdx.x * 128;

    __shared__ __align__(16) unsigned short As[128*32];
    __shared__ __align__(16) unsigned short Bs[128*32];

    const int tid = threadIdx.x;
    const int wave = tid >> 6, lane = tid & 63;
    const int wr = wave >> 1, wc = wave & 1;
    const int lr = lane & 15, lk = lane >> 4;

    const void* Ab = AF32 ? (const void*)((const float*)Av + (long)batch*sA)
                          : (const void*)((const unsigned short*)Av + (long)batch*sA);
    const unsigned short* Bb = BT + (long)batch*sB;

    f32x4_t acc[4][4];
#pragma unroll
    for (int i = 0; i < 4; ++i)
#pragma unroll
    for (int j = 0; j < 4; ++j)
        acc[i][j] = (f32x4_t){0.f,0.f,0.f,0.f};

    for (int kk = 0; kk < K; kk += 32) {
        stage_tile<128,AF32>(Ab, lda, m0, kk, K, M, As, tid);
        stage_tile<128,false>((const void*)Bb, ldbt, n0, kk, K, N, Bs, tid);
        __syncthreads();
        bf16x8_t af[4], bfv[4];
#pragma unroll
        for (int i = 0; i < 4; ++i) {
            int row = wr*64 + i*16 + lr;
            af[i]  = *(const bf16x8_t*)&As[row*32 + ((lk ^ (row & 3)) << 3)];
            int col = wc*64 + i*16 + lr;
            bfv[i] = *(const bf16x8_t*)&Bs[col*32 + ((lk ^ (col & 3)) << 3)];
        }
#pragma unroll
        for (int i = 0; i < 4; ++i)
#pragma unroll
        for (int j = 0; j < 4; ++j)
            acc[i][j] = __builtin_amdgcn_mfma_f32_16x16x32_bf16(af[i], bfv[j], acc[i][j], 0, 0, 0);
        __syncthreads();
    }

    unsigned short* C = Cout + (long)batch * sC;
#pragma unroll
    for (int i = 0; i < 4; ++i) {
#pragma unroll
        for (int r = 0; r < 4; ++r) {
            int gm = m0 + wr*64 + i*16 + lk*4 + r;
            if (gm >= M) continue;
#pragma unroll
            for (int j = 0; j < 4; ++j) {
                int gn = n0 + wc*64 + j*16 + lr;
                if (gn < N) C[(long)gm*ldc + gn] = f2bf(acc[i][j][r]);
            }
        }
    }
}

// direct bf16-input GEMM, fp32 output, 64x64 tile, batched over grid.z (pre path)
template<bool AF32>
__global__ __launch_bounds__(256)
void bgemm_f32(const void* __restrict__ Av, long lda, long sA,
               const unsigned short* __restrict__ BT, long ldbt, long sB,
               float* __restrict__ Cout, long ldc, long sC,
               int M, int N, int K)
{
    const int batch = blockIdx.z;
    const int m0 = blockIdx.y * 64;
    const int n0 = blockIdx.x * 64;

    __shared__ __align__(16) unsigned short As[64*32];
    __shared__ __align__(16) unsigned short Bs[64*32];

    const int tid = threadIdx.x;
    const int wave = tid >> 6, lane = tid & 63;
    const int wr = wave >> 1, wc = wave & 1;
    const int lr = lane & 15, lk = lane >> 4;
    const int rbase = wr*32, cbase = wc*32;

    const void* Ab = AF32 ? (const void*)((const float*)Av + (long)batch*sA)
                          : (const void*)((const unsigned short*)Av + (long)batch*sA);
    const unsigned short* Bb = BT + (long)batch*sB;

    f32x4_t acc[2][2];
#pragma unroll
    for (int i = 0; i < 2; ++i)
#pragma unroll
    for (int j = 0; j < 2; ++j)
        acc[i][j] = (f32x4_t){0.f,0.f,0.f,0.f};

    for (int kk = 0; kk < K; kk += 32) {
        stage_tile<64,AF32>(Ab, lda, m0, kk, K, M, As, tid);
        stage_tile<64,false>((const void*)Bb, ldbt, n0, kk, K, N, Bs, tid);
        __syncthreads();
        bf16x8_t af[2], bfv[2];
#pragma unroll
        for (int i = 0; i < 2; ++i) {
            int row = rbase + i*16 + lr;
            af[i] = *(const bf16x8_t*)&As[row*32 + ((lk ^ (row & 3)) << 3)];
            int col = cbase + i*16 + lr;
            bfv[i] = *(const bf16x8_t*)&Bs[col*32 + ((lk ^ (col & 3)) << 3)];
        }
#pragma unroll
        for (int i = 0; i < 2; ++i)
#pragma unroll
        for (int j = 0; j < 2; ++j)
            acc[i][j] = __builtin_amdgcn_mfma_f32_16x16x32_bf16(af[i], bfv[j], acc[i][j], 0, 0, 0);
        __syncthreads();
    }

    float* C = Cout + (long)batch * sC;
#pragma unroll
    for (int i = 0; i < 2; ++i) {
#pragma unroll
        for (int r = 0; r < 4; ++r) {
            int gm = m0 + rbase + i*16 + lk*4 + r;
            if (gm >= M) continue;
#pragma unroll
            for (int j = 0; j < 2; ++j) {
                int gn = n0 + cbase + j*16 + lr;
                if (gn < N) C[(long)gm*ldc + gn] = acc[i][j][r];
            }
        }
    }
}

// ---------------- k0: fp32 split-K GEMM, BM=256 (all M), BN=64 (all N) ----------------
__global__ __launch_bounds__(256)
void k0_gemm(const float* __restrict__ A, const float* __restrict__ B,
             float* __restrict__ Cpart, int K, int kChunk)
{
    const int z = blockIdx.x;
    const int kStart = z * kChunk;
    const int kEnd = (kStart + kChunk < K) ? (kStart + kChunk) : K;
    __shared__ __align__(16) float As[16][260];
    __shared__ __align__(16) float Bs[16][64];
    const int tid = threadIdx.x;
    const int tx = tid & 15, ty = tid >> 4;
    float acc[16][4] = {};
    for (int kk = kStart; kk < kEnd; kk += 16) {
#pragma unroll
        for (int i = 0; i < 4; ++i) {
            int row = (tid >> 2) + i*64;
            int k4 = (tid & 3) * 4;
            long gk = kk + k4;
            float4 f = {0,0,0,0};
            if (gk + 3 < (long)kEnd) f = *(const float4*)(A + (long)row*K + gk);
            else {
                if (gk+0 < kEnd) f.x = A[(long)row*K+gk+0];
                if (gk+1 < kEnd) f.y = A[(long)row*K+gk+1];
                if (gk+2 < kEnd) f.z = A[(long)row*K+gk+2];
                if (gk+3 < kEnd) f.w = A[(long)row*K+gk+3];
            }
            As[k4+0][row]=f.x; As[k4+1][row]=f.y; As[k4+2][row]=f.z; As[k4+3][row]=f.w;
        }
        {
            int k = tid >> 4, n = (tid & 15) * 4;
            long gk = kk + k;
            float4 f = {0,0,0,0};
            if (gk < kEnd) f = *(const float4*)(B + gk*64 + n);
            *(float4*)&Bs[k][n] = f;
        }
        __syncthreads();
#pragma unroll
        for (int k = 0; k < 16; ++k) {
            float4 b4 = *reinterpret_cast<const float4*>(&Bs[k][tx*4]);
            float bw[4] = {b4.x,b4.y,b4.z,b4.w};
#pragma unroll
            for (int i4 = 0; i4 < 4; ++i4) {
                float4 a4 = *reinterpret_cast<const float4*>(&As[k][ty*16 + i4*4]);
                float av[4] = {a4.x,a4.y,a4.z,a4.w};
#pragma unroll
                for (int r = 0; r < 4; ++r)
#pragma unroll
                for (int j = 0; j < 4; ++j) acc[i4*4+r][j] += av[r]*bw[j];
            }
        }
        __syncthreads();
    }
    float* cp = Cpart + (long)z*256*64;
#pragma unroll
    for (int i = 0; i < 16; ++i) {
        int gm = ty*16 + i;
#pragma unroll
        for (int j = 0; j < 4; ++j)
            cp[(long)gm*64 + tx*4 + j] = acc[i][j];
    }
}

__global__ __launch_bounds__(256)
void k_reduce_splitk(const float* __restrict__ Cpart, float* __restrict__ out,
                     long ldcOut, long sOut,
                     const float* __restrict__ bias, long sBias,
                     int nbatch, int M, int N, int nsplit)
{
    long idx = (long)blockIdx.x*256 + threadIdx.x;
    long total = (long)nbatch*M*N;
    if (idx >= total) return;
    int n = idx % N; long t = idx / N;
    int m = t % M; int bi = t / M;
    const float* p = Cpart + ((long)bi*nsplit)*((long)M*N) + (long)m*N + n;
    float s = bias ? bias[(long)bi*sBias + n] : 0.f;
#pragma unroll 8
    for (int si = 0; si < nsplit; ++si) s += p[(long)si*M*N];
    out[(long)bi*sOut + (long)m*ldcOut + n] = s;
}

// ---------------- q ----------------
__global__ __launch_bounds__(256)
void k_q(const float* __restrict__ opt, const float* __restrict__ hx,
         const float* __restrict__ Wq, float* __restrict__ q)
{
    int idx = blockIdx.x*256 + threadIdx.x;
    if (idx >= NB*NU*NDK) return;
    int k = idx & 63; int t = idx >> 6;
    int u = t & 7; int b = t >> 3;
    const float* hxr = hx + (long)(b*NU+u)*NH;
    float acc = 0.f;
    for (int o = 0; o < NO; ++o) {
        const float* w = Wq + ((long)(o*NU+u)*NH)*NDK + k;
        float s = 0.f;
        for (int h = 0; h < NH; ++h) s += hxr[h] * w[(long)h*NDK];
        acc += opt[b*NO+o] * s;
    }
    q[idx] = acc;
}

// ---------------- scores + softmax(2) + attn_in + real ----------------
__global__ __launch_bounds__(64)
void k_attn(const float* __restrict__ q, const float* __restrict__ k0,
            const float* __restrict__ bk, const float* __restrict__ v0,
            const float* __restrict__ bv, float* __restrict__ attn,
            float* __restrict__ real)
{
    int bu = blockIdx.x;
    int lane = threadIdx.x;
    int b = bu >> 3;
    float qv = q[(long)bu*NDK + lane];
    float s0 = qv * k0[(long)b*NDK + lane];
    float s1 = qv * bk[lane];
    for (int off = 32; off; off >>= 1) {
        s0 += __shfl_xor(s0, off);
        s1 += __shfl_xor(s1, off);
    }
    s0 *= 0.125f; s1 *= 0.125f;
    float mx = fmaxf(s0, s1);
    float e0 = expf(s0-mx), e1 = expf(s1-mx);
    float inv = 1.f/(e0+e1);
    float p0 = e0*inv, p1 = e1*inv;
    if (lane == 0) real[bu] = p0;
    for (int v = lane; v < NV; v += 64)
        attn[(long)bu*NV + v] = p0*v0[(long)b*NV + v] + p1*bv[v];
}

// ---------------- top-k mask ----------------
__global__ void k_topk(const float* __restrict__ real, float* __restrict__ mask)
{
    int b = blockIdx.x*blockDim.x + threadIdx.x;
    if (b >= NB) return;
    float v[NU]; bool sel[NU];
#pragma unroll
    for (int i = 0; i < NU; ++i) { v[i] = real[b*NU+i]; sel[i] = false; }
    for (int t = 0; t < NKT; ++t) {
        int best = 0; float bvv = -1e30f;
#pragma unroll
        for (int i = 0; i < NU; ++i)
            if (!sel[i] && v[i] > bvv) { bvv = v[i]; best = i; }
        sel[best] = true;
    }
#pragma unroll
    for (int i = 0; i < NU; ++i) mask[b*NU+i] = sel[i] ? 1.f : 0.f;
}

// ---------------- LSTM gates (pre = pre_i + pre_h + blstm) ----------------
__global__ __launch_bounds__(256)
void k_gates(const float* __restrict__ pre_i, const float* __restrict__ pre_h,
             const float* __restrict__ blstm, const float* __restrict__ cx,
             float* __restrict__ cn, float* __restrict__ hn)
{
    int idx = blockIdx.x*256 + threadIdx.x;
    if (idx >= NB*NU*NH) return;
    int h = idx & 127; int bu = idx >> 7;
    int u = bu & 7;
    const float* pi = pre_i + (long)bu*512;
    const float* ph = pre_h + (long)bu*512;
    const float* bl = blstm + (long)u*512;
    float ig = pi[h]     + ph[h]     + bl[h];
    float fg = pi[128+h] + ph[128+h] + bl[128+h];
    float gg = pi[256+h] + ph[256+h] + bl[256+h];
    float og = pi[384+h] + ph[384+h] + bl[384+h];
    float si = 1.f/(1.f+expf(-ig));
    float sf = 1.f/(1.f+expf(-fg));
    float so = 1.f/(1.f+expf(-og));
    float c = sf*cx[idx] + si*tanhf(gg);
    cn[idx] = c;
    hn[idx] = so*tanhf(c);
}

// ---------------- qc,kc ----------------
__global__ __launch_bounds__(256)
void k_qckc(const float* __restrict__ hn, const float* __restrict__ Wqc,
            const float* __restrict__ Wkc, float* __restrict__ qc,
            float* __restrict__ kc)
{
    int idx = blockIdx.x*256 + threadIdx.x;
    if (idx >= NB*NU*64) return;
    int j = idx & 63; int t = idx >> 6;
    int u = t & 7; int b = t >> 3;
    int k = j & 31;
    const float* W = (j < 32 ? Wqc : Wkc) + ((long)u*NH)*NDKC + k;
    const float* h = hn + (long)(b*NU+u)*NH;
    float s = 0.f;
    for (int hh = 0; hh < NH; ++hh) s += h[hh]*W[(long)hh*NDKC];
    (j < 32 ? qc : kc)[(b*NU+u)*NDKC + k] = s;
}

// ---------------- comm probs ----------------
__global__ __launch_bounds__(64)
void k_cp(const float* __restrict__ qc, const float* __restrict__ kc,
          const float* __restrict__ mask, float* __restrict__ cp)
{
    int b = blockIdx.x;
    int lane = threadIdx.x;
    int u = lane >> 3, n = lane & 7;
    const float* qr = qc + (long)(b*NU+u)*NDKC;
    const float* kr = kc + (long)(b*NU+n)*NDKC;
    float d = 0.f;
    for (int k = 0; k < NDKC; ++k) d += qr[k]*kr[k];
    d *= 0.17677669529663687f;
    float mx = d;
    for (int off = 4; off; off >>= 1) mx = fmaxf(mx, __shfl_xor(mx, off, 8));
    float e = expf(d-mx);
    float sm = e;
    for (int off = 4; off; off >>= 1) sm += __shfl_xor(sm, off, 8);
    cp[b*64 + lane] = (e/sm) * mask[b*NU+u];
}

// ---------------- ctx (bf16 in/out) ----------------
__global__ __launch_bounds__(256)
void k_ctx(const unsigned short* __restrict__ vc, const float* __restrict__ cp,
           unsigned short* __restrict__ ctx)
{
    int b = blockIdx.y;
    int v = blockIdx.x*256 + threadIdx.x;
    __shared__ float cps[64];
    if (threadIdx.x < 64) cps[threadIdx.x] = cp[b*64 + threadIdx.x];
    __syncthreads();
    if (v >= NCV) return;
    float vv[NU];
#pragma unroll
    for (int n = 0; n < NU; ++n) vv[n] = bf2f(vc[((long)(b*NU+n))*NCV + v]);
#pragma unroll
    for (int u = 0; u < NU; ++u) {
        float s = 0.f;
#pragma unroll
        for (int n = 0; n < NU; ++n) s += cps[u*8+n]*vv[n];
        ctx[((long)(b*NU+u))*NCV + v] = f2bf(s);
    }
}

// ---------------- fused tail: blend + hy-sum + logits-softmax ----------------
__global__ __launch_bounds__(128)
void k_tail(const float* __restrict__ hn, const float* __restrict__ cn,
            const float* __restrict__ hcw, const float* __restrict__ hx,
            const float* __restrict__ cx, const float* __restrict__ mask,
            const float* __restrict__ piw, const float* __restrict__ pib,
            float* __restrict__ hy, float* __restrict__ cy,
            float* __restrict__ out)
{
    const int b = blockIdx.x;
    const int h = threadIdx.x;
    __shared__ float hs[128];
    __shared__ float lg[28];
    float s = 0.f;
#pragma unroll
    for (int u = 0; u < NU; ++u) {
        int idx = (b*NU+u)*NH + h;
        float m = mask[b*NU+u];
        float hyv = m*(hn[idx]+hcw[idx]) + (1.f-m)*hx[idx];
        float cyv = m*cn[idx] + (1.f-m)*cx[idx];
        hy[idx] = hyv; cy[idx] = cyv;
        s += hyv;
    }
    hs[h] = s;
    __syncthreads();
    if (h < 28) {
        int o = h / 7, a = h - o*7;
        float acc = pib[o*NA+a];
        for (int k = 0; k < NH; ++k) acc += hs[k] * piw[((long)o*NH+k)*NA + a];
        lg[h] = acc;
    }
    __syncthreads();
    if (h < NO) {
        float mx = lg[h*NA];
#pragma unroll
        for (int a = 1; a < NA; ++a) mx = fmaxf(mx, lg[h*NA+a]);
        float e[NA]; float sm = 0.f;
#pragma unroll
        for (int a = 0; a < NA; ++a) { e[a] = expf(lg[h*NA+a]-mx); sm += e[a]; }
        float inv = 1.f/sm;
#pragma unroll
        for (int a = 0; a < NA; ++a) out[(long)b*NO*NA + h*NA + a] = e[a]*inv;
    }
}

extern "C" void kernel_launch(void* const* d_in, const int* in_sizes, int n_in,
                              void* d_out, int out_size, void* d_ws, size_t ws_size,
                              hipStream_t stream) {
    const float* x    = (const float*)d_in[0];
    const float* hx   = (const float*)d_in[1];
    const float* cx   = (const float*)d_in[2];
    const float* opt  = (const float*)d_in[3];
    const float* c1w  = (const float*)d_in[4];
    const float* c1b  = (const float*)d_in[5];
    const float* c2w  = (const float*)d_in[6];
    const float* c2b  = (const float*)d_in[7];
    const float* c3w  = (const float*)d_in[8];
    const float* c3b  = (const float*)d_in[9];
    const float* Wk   = (const float*)d_in[10];
    const float* bk   = (const float*)d_in[11];
    const float* Wv   = (const float*)d_in[12];
    const float* bv   = (const float*)d_in[13];
    const float* Wq   = (const float*)d_in[14];
    const float* Wi   = (const float*)d_in[15];
    const float* Wh   = (const float*)d_in[16];
    const float* blstm= (const float*)d_in[17];
    const float* Wqc  = (const float*)d_in[18];
    const float* Wkc  = (const float*)d_in[19];
    const float* Wvc  = (const float*)d_in[20];
    const float* Wout = (const float*)d_in[21];
    const float* piw  = (const float*)d_in[22];
    const float* pib  = (const float*)d_in[23];

    float* out = (float*)d_out;
    float* hy  = out + (long)NB*NO*NA;
    float* cy  = hy + (long)NB*NU*NH;

    float* ws = (float*)d_ws;
    long o = 0;
    float* b_k0  = ws + o; o += 16384;
    float* b_v0  = ws + o; o += 102400;
    float* b_q   = ws + o; o += 131072;
    float* b_at  = ws + o; o += 819200;
    float* b_re  = ws + o; o += 2048;
    float* b_mk  = ws + o; o += 2048;
    float* b_pre = ws + o; o += 1048576;
    float* b_cn  = ws + o; o += 262144;
    float* b_hn  = ws + o; o += 262144;
    float* b_qc  = ws + o; o += 65536;
    float* b_kc  = ws + o; o += 65536;
    float* b_cp  = ws + o; o += 16384;
    float* b_hc  = ws + o; o += 262144;
    float* b_hs  = ws + o; o += 32768;
    // o == 3088384 — layout identical to the proven 468 µs round (all spans audited):
    //  P1OFF: p1 -> WvT -> WvcT+WoutT+partW | C2OFF: c2
    //  EMBOFF: emb32 -> v0 partials -> vc16+ctx16
    //  TOFF: k0 partials -> emb16 -> WiT+WhT+pre_h
    constexpr long P1OFF  = 3088384;
    constexpr long C2OFF  = 7024640;
    constexpr long EMBOFF = 14397440;
    constexpr long TOFF   = 28176384;
    constexpr long NEED   = TOFF + 5242880;   // 33,419,264 floats (proven)
    if (ws_size < (size_t)NEED * sizeof(float)) return;

    float* p1    = ws + P1OFF;
    float* c2    = ws + C2OFF;
    float* emb   = ws + EMBOFF;
    float* partK = ws + TOFF;                                    // k0 partials (S3)
    float* partV = ws + EMBOFF;                                  // v0 partials (S5, emb32 dead)
    unsigned short* emb16 = (unsigned short*)(ws + TOFF);        // S4-S5 (k0 partials dead)
    unsigned short* WvT   = (unsigned short*)(ws + P1OFF);       // S2-S5
    unsigned short* WiT   = (unsigned short*)(ws + TOFF);        // S7 (emb16 dead)
    unsigned short* WhT   = (unsigned short*)(ws + TOFF + 819200);
    float* pre_h          = ws + TOFF + 819200 + 262144;
    unsigned short* WvcT  = (unsigned short*)(ws + P1OFF);       // S8 (WvT dead)
    unsigned short* WoutT = (unsigned short*)(ws + P1OFF + 3444736);
    float* partW          = ws + P1OFF + 2*3444736;
    unsigned short* vc16  = (unsigned short*)(ws + EMBOFF);      // S9 (v0 partials dead)
    unsigned short* ctx16 = (unsigned short*)(ws + EMBOFF + 6889472);

    // S1) conv stack (4x4 micro, hoisted div/mod — bit-identical outputs)
    k_conv1<<<(NB*16*H1*W1 + 255)/256, 256, 0, stream>>>(x, c1w, c1b, p1);
    conv2x2_gemm<32,16,H1,W1,H2,W2><<<NB*((H2*W2+127)/128), 256, 0, stream>>>(p1, c2w, c2b, c2);
    conv2x2_gemm<64,32,H2,W2,H3,W3><<<NB*((H3*W3+63)/64), 256, 0, stream>>>(c2, c3w, c3b, emb);

    // S2) Wv -> bf16 transposed [400][53824]  (p1/c2 dead)
    k_f2bt<<<dim3(13, 1682, 1), 256, 0, stream>>>(Wv, WvT, NE, NV, 0);

    // S3) k0 = emb@Wk + bk  (fp32 — precision-critical for top-k; S=320)
    k0_gemm<<<320, 256, 0, stream>>>(emb, Wk, partK, NE, 176);
    k_reduce_splitk<<<(NB*NDK + 255)/256, 256, 0, stream>>>(
        partK, b_k0, NDK, 0, bk, 0, 1, NB, NDK, 320);

    // S4) emb -> bf16 (RNE, identical rounding; k0 partials dead)
    k_cvt<<<((long)NB*NE/8 + 255)/256, 256, 0, stream>>>(emb, emb16, (long)NB*NE);

    // S5) v0 = emb16@Wv + bv  (bf16 MFMA, 128x128, S=87; partials at EMBOFF)
    bgemm_splitk<128,128,false><<<dim3(4,2,87), 256, 0, stream>>>(
        emb16, NE, 0, WvT, NE, 0, partV, NB, NV, NE, 87, 624);
    k_reduce_splitk<<<(NB*NV + 255)/256, 256, 0, stream>>>(
        partV, b_v0, NV, 0, bv, 0, 1, NB, NV, 87);

    // S6) q / attention / top-k
    k_q<<<(NB*NU*NDK + 255)/256, 256, 0, stream>>>(opt, hx, Wq, b_q);
    k_attn<<<NB*NU, 64, 0, stream>>>(b_q, b_k0, bk, b_v0, bv, b_at, b_re);
    k_topk<<<1, 256, 0, stream>>>(b_re, b_mk);

    // S7) LSTM pre in bf16 MFMA (fp32 accum/out) — proven round 10
    k_f2bt<<<dim3(16, 13, 8), 256, 0, stream>>>(Wi, WiT, NV, 512, (long)NV*512);
    k_f2bt<<<dim3(16, 4, 8), 256, 0, stream>>>(Wh, WhT, NH, 512, (long)NH*512);
    bgemm_f32<true><<<dim3(8, 4, NU), 256, 0, stream>>>(
        b_at, (long)NU*NV, NV, WiT, NV, (long)512*NV,
        b_pre, (long)NU*512, 512, NB, 512, NV);
    bgemm_f32<true><<<dim3(8, 4, NU), 256, 0, stream>>>(
        hx, (long)NU*NH, NH, WhT, NH, (long)512*NH,
        pre_h, (long)NU*512, 512, NB, 512, NH);
    k_gates<<<(NB*NU*NH + 255)/256, 256, 0, stream>>>(b_pre, pre_h, blstm, cx, b_cn, b_hn);

    // S8) convert Wvc/Wout (WvT dead after v0)
    k_f2bt<<<dim3(211, 4, 8), 256, 0, stream>>>(Wvc, WvcT, NH, NCV, (long)NH*NCV);
    k_f2bt<<<dim3(4, 211, 8), 256, 0, stream>>>(Wout, WoutT, NCV, NH, (long)NCV*NH);

    // S9) vc = h_new@Wvc (bf16 MFMA direct, bf16 out)  (v0 partials dead)
    bgemm_direct<true><<<dim3((NCV+127)/128, 2, NU), 256, 0, stream>>>(
        b_hn, (long)NU*NH, NH, WvcT, NH, (long)NCV*NH,
        vc16, (long)NU*NCV, NCV, NB, NCV, NH);

    // S10) comm probs + ctx
    k_qckc<<<(NB*NU*64 + 255)/256, 256, 0, stream>>>(b_hn, Wqc, Wkc, b_qc, b_kc);
    k_cp<<<NB, 64, 0, stream>>>(b_qc, b_kc, b_mk, b_cp);
    k_ctx<<<dim3((NCV+255)/256, NB), 256, 0, stream>>>(vc16, b_cp, ctx16);

    // S11) hcomm_w = ctx@Wout (bf16 MFMA split-K 16)
    bgemm_splitk<64,64,false><<<dim3(2,4,NU*16), 256, 0, stream>>>(
        ctx16, (long)NU*NCV, NCV, WoutT, NCV, (long)NCV*NH,
        partW, NB, NH, NCV, 16, 448);
    k_reduce_splitk<<<(NU*NB*NH + 255)/256, 256, 0, stream>>>(
        partW, b_hc, (long)NU*NH, NH, nullptr, 0, NU, NB, NH, 16);

    // S12) fused blend + hy-sum + logits
    k_tail<<<NB, 128, 0, stream>>>(b_hn, b_cn, b_hc, hx, cx, b_mk, piw, pib, hy, cy, out);
}

// Round 14
// 459.884 us; speedup vs baseline: 1.0566x; 1.0123x over previous
//
#include <hip/hip_runtime.h>
#include <math.h>

namespace {
constexpr int NB  = 256;
constexpr int NU  = 8;
constexpr int NKT = 4;
constexpr int NH  = 128;
constexpr int NO  = 4;
constexpr int NA  = 7;
constexpr int NV  = 400;
constexpr int NE  = 53824;
constexpr int NCV = 6728;
constexpr int NDK = 64;
constexpr int NDKC= 32;

constexpr int H1 = 31, W1 = 31;
constexpr int H2 = 30, W2 = 30;
constexpr int H3 = 29, W3 = 29;
}

typedef __attribute__((ext_vector_type(8))) short bf16x8_t;
typedef __attribute__((ext_vector_type(4))) float f32x4_t;

__device__ __forceinline__ unsigned short f2bf(float f) {
    unsigned int u = __float_as_uint(f);
    u += 0x7FFFu + ((u >> 16) & 1u);   // RNE
    return (unsigned short)(u >> 16);
}
__device__ __forceinline__ float bf2f(unsigned short h) {
    return __uint_as_float((unsigned int)h << 16);
}

// ---------------- conv1 (2x2, 3->16) + relu + maxpool2 ----------------
__global__ __launch_bounds__(256)
void k_conv1(const float* __restrict__ x, const float* __restrict__ w,
             const float* __restrict__ bias, float* __restrict__ out)
{
    __shared__ float ws[16*3*2*2];
    __shared__ float bs[16];
    int tid = threadIdx.x;
    if (tid < 192) ws[tid] = w[tid];
    if (tid < 16)  bs[tid] = bias[tid];
    __syncthreads();
    long idx = (long)blockIdx.x*256 + tid;
    if (idx >= (long)NB*16*H1*W1) return;
    int pw = idx % W1; long t = idx / W1;
    int ph = t % H1; t /= H1;
    int oc = t % 16; int b = t / 16;
    float mx = 0.f;
#pragma unroll
    for (int dh = 0; dh < 2; ++dh)
#pragma unroll
    for (int dw = 0; dw < 2; ++dw) {
        int h = 2*ph + dh, ww = 2*pw + dw;
        float s = bs[oc];
#pragma unroll
        for (int kh = 0; kh < 2; ++kh)
#pragma unroll
        for (int kw = 0; kw < 2; ++kw) {
            const float* xp = x + (((long)b*64 + (h+kh))*64 + (ww+kw))*3;
#pragma unroll
            for (int ic = 0; ic < 3; ++ic)
                s += xp[ic] * ws[((oc*3+ic)*2+kh)*2+kw];
        }
        mx = fmaxf(mx, s);
    }
    out[idx] = mx;
}

// ---------------- conv 2x2 as implicit GEMM, 4x4 micro, single-barrier dbuf ----------------
// Prefetch tile kk+16 global->regs during compute of tile kk, write to buf^1 after,
// ONE barrier per K-step. LDS image per tile and FMA order bit-identical to round 12.
template<int OC, int IC, int HIN, int WIN, int HOUT, int WOUT>
__global__ __launch_bounds__(256)
void conv2x2_gemm(const float* __restrict__ in, const float* __restrict__ w,
                  const float* __restrict__ bias, float* __restrict__ out)
{
    constexpr int K    = IC*4;
    constexpr int TY   = OC/4;          // 16 (OC=64) or 8 (OC=32)
    constexpr int TX   = 256/TY;        // 16 or 32
    constexpr int NT   = TX*4;          // 64 or 128
    constexpr int SPAT = HOUT*WOUT;
    constexpr int NBLK = (SPAT + NT - 1)/NT;
    constexpr int AIT  = OC*16/256;     // 4 or 2
    constexpr int BIT  = 16*NT/256;     // 4 or 8

    const int b  = blockIdx.x / NBLK;
    const int n0 = (blockIdx.x % NBLK) * NT;

    __shared__ __align__(16) float As[2][16][OC+4];
    __shared__ __align__(16) float Bs[2][16][NT];

    const int tid = threadIdx.x;
    const int tx = tid % TX, ty = tid / TX;
    float acc[4][4] = {};
    const float* inb = in + (long)b*IC*HIN*WIN;

    // hoisted per-thread Bs column
    const int nIdx = tid & (NT-1);
    int ohw = 0; bool nOk = false;
    {
        int s = n0 + nIdx;
        if (s < SPAT) { ohw = (s / WOUT) * WIN + (s % WOUT); nOk = true; }
    }

    float aR[AIT], bR[BIT];
    auto loadAB = [&](int kk) {
#pragma unroll
        for (int i = 0; i < AIT; ++i) {
            int lin = tid + i*256;
            aR[i] = w[(lin/16)*K + kk + (lin%16)];
        }
#pragma unroll
        for (int i = 0; i < BIT; ++i) {
            int k = (tid + i*256) / NT;
            int gk = kk + k;
            int ic = gk >> 2, tap = gk & 3;
            bR[i] = nOk ? inb[ic*HIN*WIN + ohw + (tap>>1)*WIN + (tap&1)] : 0.f;
        }
    };
    auto storeAB = [&](int buf) {
#pragma unroll
        for (int i = 0; i < AIT; ++i) {
            int lin = tid + i*256;
            As[buf][lin%16][lin/16] = aR[i];
        }
#pragma unroll
        for (int i = 0; i < BIT; ++i) {
            int k = (tid + i*256) / NT;
            Bs[buf][k][nIdx] = bR[i];
        }
    };

    loadAB(0);
    storeAB(0);
    __syncthreads();
    int cur = 0;
    for (int kk = 0; kk < K; kk += 16) {
        const bool more = (kk + 16 < K);
        if (more) loadAB(kk + 16);          // global prefetch, hidden under FMA
#pragma unroll
        for (int k = 0; k < 16; ++k) {
            float4 a4 = *reinterpret_cast<const float4*>(&As[cur][k][ty*4]);
            float4 b4 = *reinterpret_cast<const float4*>(&Bs[cur][k][tx*4]);
            float av[4] = {a4.x,a4.y,a4.z,a4.w};
            float bw[4] = {b4.x,b4.y,b4.z,b4.w};
#pragma unroll
            for (int i = 0; i < 4; ++i)
#pragma unroll
            for (int j = 0; j < 4; ++j) acc[i][j] += av[i]*bw[j];
        }
        if (more) {
            storeAB(cur ^ 1);
            __syncthreads();                // single barrier per K-step
            cur ^= 1;
        }
    }
#pragma unroll
    for (int i = 0; i < 4; ++i) {
        int gm = ty*4 + i;
        float bi = bias[gm];
#pragma unroll
        for (int j = 0; j < 4; ++j) {
            int s = n0 + tx*4 + j;
            if (s < SPAT)
                out[((long)b*OC + gm)*SPAT + s] = fmaxf(acc[i][j] + bi, 0.f);
        }
    }
}

// ---------------- fp32 -> bf16 elementwise convert (n multiple of 8) ----------------
__global__ __launch_bounds__(256)
void k_cvt(const float* __restrict__ in, unsigned short* __restrict__ out, long n)
{
    long i = ((long)blockIdx.x*256 + threadIdx.x) * 8;
    if (i >= n) return;
    float4 a = *(const float4*)(in + i);
    float4 b = *(const float4*)(in + i + 4);
    uint4 u;
    u.x = (unsigned)f2bf(a.x) | ((unsigned)f2bf(a.y) << 16);
    u.y = (unsigned)f2bf(a.z) | ((unsigned)f2bf(a.w) << 16);
    u.z = (unsigned)f2bf(b.x) | ((unsigned)f2bf(b.y) << 16);
    u.w = (unsigned)f2bf(b.z) | ((unsigned)f2bf(b.w) << 16);
    *(uint4*)(out + i) = u;
}

// ---------------- fp32 -> bf16 transposed convert: in [B][R][Cc] -> out [B][Cc][R] ----------------
__global__ __launch_bounds__(256)
void k_f2bt(const float* __restrict__ in, unsigned short* __restrict__ out,
            int R, int Cc, long sIn)
{
    __shared__ unsigned short t[32][33];
    const int b = blockIdx.z;
    const int r0 = blockIdx.y * 32, c0 = blockIdx.x * 32;
    const float* ip = in + (long)b * sIn;
    unsigned short* op = out + (long)b * sIn;
    const int tid = threadIdx.x;
    {
        int rr = tid >> 3, c4 = (tid & 7) * 4;
        int gr = r0 + rr;
        unsigned short h0=0,h1=0,h2=0,h3=0;
        if (gr < R) {
            if (c0 + c4 + 3 < Cc) {
                float4 f = *(const float4*)(ip + (long)gr*Cc + c0 + c4);
                h0=f2bf(f.x); h1=f2bf(f.y); h2=f2bf(f.z); h3=f2bf(f.w);
            } else {
                if (c0+c4+0 < Cc) h0 = f2bf(ip[(long)gr*Cc + c0+c4+0]);
                if (c0+c4+1 < Cc) h1 = f2bf(ip[(long)gr*Cc + c0+c4+1]);
                if (c0+c4+2 < Cc) h2 = f2bf(ip[(long)gr*Cc + c0+c4+2]);
                if (c0+c4+3 < Cc) h3 = f2bf(ip[(long)gr*Cc + c0+c4+3]);
            }
        }
        t[rr][c4+0]=h0; t[rr][c4+1]=h1; t[rr][c4+2]=h2; t[rr][c4+3]=h3;
    }
    __syncthreads();
    {
        int cc = tid >> 3, r4 = (tid & 7) * 4;
        int gc = c0 + cc;
        if (gc < Cc && r0 + r4 < R) {
            if (r0 + r4 + 3 < R) {
                *(ushort4*)(op + (long)gc*R + r0 + r4) =
                    make_ushort4(t[r4+0][cc], t[r4+1][cc], t[r4+2][cc], t[r4+3][cc]);
            } else {
#pragma unroll
                for (int j = 0; j < 4; ++j)
                    if (r0 + r4 + j < R) op[(long)gc*R + r0 + r4 + j] = t[r4+j][cc];
            }
        }
    }
}

// ---------------- bf16 MFMA GEMM staging, 16B-wide ----------------
template<int ROWS, bool F32>
__device__ __forceinline__ void stage_tile(const void* __restrict__ Av, long lda,
                                           int m0, int kk, int kEnd, int Mlim,
                                           unsigned short* lds, int tid)
{
#pragma unroll
    for (int i = 0; i < ROWS/64; ++i) {
        int row = (tid >> 2) + i*64;
        int blk = tid & 3;
        long gm = m0 + row;
        long gk = kk + blk*8;
        ushort4 lo = make_ushort4(0,0,0,0), hi = make_ushort4(0,0,0,0);
        if (gm < Mlim && gk < kEnd) {
            if (F32) {
                const float* A = (const float*)Av + gm*lda + gk;
                float4 f0 = *(const float4*)(A);
                float4 f1 = *(const float4*)(A + 4);
                lo = make_ushort4(f2bf(f0.x),f2bf(f0.y),f2bf(f0.z),f2bf(f0.w));
                hi = make_ushort4(f2bf(f1.x),f2bf(f1.y),f2bf(f1.z),f2bf(f1.w));
            } else {
                const unsigned short* A = (const unsigned short*)Av + gm*lda + gk;
                lo = *(const ushort4*)(A);
                hi = *(const ushort4*)(A + 4);
            }
        }
        int p = (blk ^ (row & 3)) << 3;
        *(ushort4*)&lds[row*32 + p]     = lo;
        *(ushort4*)&lds[row*32 + p + 4] = hi;
    }
}

template<int BM, int BN, bool AF32>
__global__ __launch_bounds__(256)
void bgemm_splitk(const void* __restrict__ Av, long lda, long sA,
                  const unsigned short* __restrict__ BT, long ldbt, long sB,
                  float* __restrict__ Cpart,
                  int M, int N, int K, int nsplit, int kChunk)
{
    constexpr int MR = BM/32, NR = BN/32;
    const int z = blockIdx.z;
    const int batch = z / nsplit, split = z - batch*nsplit;
    const int kStart = split * kChunk;
    const int kEnd = (kStart + kChunk < K) ? (kStart + kChunk) : K;
    const int m0 = blockIdx.y * BM;
    const int n0 = blockIdx.x * BN;

    __shared__ __align__(16) unsigned short As[BM*32];
    __shared__ __align__(16) unsigned short Bs[BN*32];

    const int tid = threadIdx.x;
    const int wave = tid >> 6, lane = tid & 63;
    const int wr = wave >> 1, wc = wave & 1;
    const int lr = lane & 15, lk = lane >> 4;
    const int rbase = wr*(BM/2), cbase = wc*(BN/2);

    const void* Ab = AF32 ? (const void*)((const float*)Av + (long)batch*sA)
                          : (const void*)((const unsigned short*)Av + (long)batch*sA);
    const unsigned short* Bb = BT + (long)batch*sB;

    f32x4_t acc[MR][NR];
#pragma unroll
    for (int i = 0; i < MR; ++i)
#pragma unroll
    for (int j = 0; j < NR; ++j)
        acc[i][j] = (f32x4_t){0.f,0.f,0.f,0.f};

    for (int kk = kStart; kk < kEnd; kk += 32) {
        stage_tile<BM,AF32>(Ab, lda, m0, kk, kEnd, M, As, tid);
        stage_tile<BN,false>((const void*)Bb, ldbt, n0, kk, kEnd, N, Bs, tid);
        __syncthreads();
        bf16x8_t af[MR], bfv[NR];
#pragma unroll
        for (int i = 0; i < MR; ++i) {
            int row = rbase + i*16 + lr;
            af[i] = *(const bf16x8_t*)&As[row*32 + ((lk ^ (row & 3)) << 3)];
        }
#pragma unroll
        for (int j = 0; j < NR; ++j) {
            int col = cbase + j*16 + lr;
            bfv[j] = *(const bf16x8_t*)&Bs[col*32 + ((lk ^ (col & 3)) << 3)];
        }
#pragma unroll
        for (int i = 0; i < MR; ++i)
#pragma unroll
        for (int j = 0; j < NR; ++j)
            acc[i][j] = __builtin_amdgcn_mfma_f32_16x16x32_bf16(af[i], bfv[j], acc[i][j], 0, 0, 0);
        __syncthreads();
    }

    const long cb2 = (long)z * M * N;
#pragma unroll
    for (int i = 0; i < MR; ++i) {
#pragma unroll
        for (int r = 0; r < 4; ++r) {
            int gm = m0 + rbase + i*16 + lk*4 + r;
            if (gm >= M) continue;
#pragma unroll
            for (int j = 0; j < NR; ++j) {
                int gn = n0 + cbase + j*16 + lr;
                if (gn < N) Cpart[cb2 + (long)gm*N + gn] = acc[i][j][r];
            }
        }
    }
}

// direct bf16 GEMM (full K), bf16 output, 128x128 tile
template<bool AF32>
__global__ __launch_bounds__(256)
void bgemm_direct(const void* __restrict__ Av, long lda, long sA,
                  const unsigned short* __restrict__ BT, long ldbt, long sB,
                  unsigned short* __restrict__ Cout, long ldc, long sC,
                  int M, int N, int K)
{
    const int batch = blockIdx.z;
    const int m0 = blockIdx.y * 128;
    const int n0 = blockIdx.x * 128;

    __shared__ __align__(16) unsigned short As[128*32];
    __shared__ __align__(16) unsigned short Bs[128*32];

    const int tid = threadIdx.x;
    const int wave = tid >> 6, lane = tid & 63;
    const int wr = wave >> 1, wc = wave & 1;
    const int lr = lane & 15, lk = lane >> 4;

    const void* Ab = AF32 ? (const void*)((const float*)Av + (long)batch*sA)
                          : (const void*)((const unsigned short*)Av + (long)batch*sA);
    const unsigned short* Bb = BT + (long)batch*sB;

    f32x4_t acc[4][4];
#pragma unroll
    for (int i = 0; i < 4; ++i)
#pragma unroll
    for (int j = 0; j < 4; ++j)
        acc[i][j] = (f32x4_t){0.f,0.f,0.f,0.f};

    for (int kk = 0; kk < K; kk += 32) {
        stage_tile<128,AF32>(Ab, lda, m0, kk, K, M, As, tid);
        stage_tile<128,false>((const void*)Bb, ldbt, n0, kk, K, N, Bs, tid);
        __syncthreads();
        bf16x8_t af[4], bfv[4];
#pragma unroll
        for (int i = 0; i < 4; ++i) {
            int row = wr*64 + i*16 + lr;
            af[i]  = *(const bf16x8_t*)&As[row*32 + ((lk ^ (row & 3)) << 3)];
            int col = wc*64 + i*16 + lr;
            bfv[i] = *(const bf16x8_t*)&Bs[col*32 + ((lk ^ (col & 3)) << 3)];
        }
#pragma unroll
        for (int i = 0; i < 4; ++i)
#pragma unroll
        for (int j = 0; j < 4; ++j)
            acc[i][j] = __builtin_amdgcn_mfma_f32_16x16x32_bf16(af[i], bfv[j], acc[i][j], 0, 0, 0);
        __syncthreads();
    }

    unsigned short* C = Cout + (long)batch * sC;
#pragma unroll
    for (int i = 0; i < 4; ++i) {
#pragma unroll
        for (int r = 0; r < 4; ++r) {
            int gm = m0 + wr*64 + i*16 + lk*4 + r;
            if (gm >= M) continue;
#pragma unroll
            for (int j = 0; j < 4; ++j) {
                int gn = n0 + wc*64 + j*16 + lr;
                if (gn < N) C[(long)gm*ldc + gn] = f2bf(acc[i][j][r]);
            }
        }
    }
}

// direct bf16-input GEMM, fp32 output, 64x64 tile, batched over grid.z (pre path)
template<bool AF32>
__global__ __launch_bounds__(256)
void bgemm_f32(const void* __restrict__ Av, long lda, long sA,
               const unsigned short* __restrict__ BT, long ldbt, long sB,
               float* __restrict__ Cout, long ldc, long sC,
               int M, int N, int K)
{
    const int batch = blockIdx.z;
    const int m0 = blockIdx.y * 64;
    const int n0 = blockIdx.x * 64;

    __shared__ __align__(16) unsigned short As[64*32];
    __shared__ __align__(16) unsigned short Bs[64*32];

    const int tid = threadIdx.x;
    const int wave = tid >> 6, lane = tid & 63;
    const int wr = wave >> 1, wc = wave & 1;
    const int lr = lane & 15, lk = lane >> 4;
    const int rbase = wr*32, cbase = wc*32;

    const void* Ab = AF32 ? (const void*)((const float*)Av + (long)batch*sA)
                          : (const void*)((const unsigned short*)Av + (long)batch*sA);
    const unsigned short* Bb = BT + (long)batch*sB;

    f32x4_t acc[2][2];
#pragma unroll
    for (int i = 0; i < 2; ++i)
#pragma unroll
    for (int j = 0; j < 2; ++j)
        acc[i][j] = (f32x4_t){0.f,0.f,0.f,0.f};

    for (int kk = 0; kk < K; kk += 32) {
        stage_tile<64,AF32>(Ab, lda, m0, kk, K, M, As, tid);
        stage_tile<64,false>((const void*)Bb, ldbt, n0, kk, K, N, Bs, tid);
        __syncthreads();
        bf16x8_t af[2], bfv[2];
#pragma unroll
        for (int i = 0; i < 2; ++i) {
            int row = rbase + i*16 + lr;
            af[i] = *(const bf16x8_t*)&As[row*32 + ((lk ^ (row & 3)) << 3)];
            int col = cbase + i*16 + lr;
            bfv[i] = *(const bf16x8_t*)&Bs[col*32 + ((lk ^ (col & 3)) << 3)];
        }
#pragma unroll
        for (int i = 0; i < 2; ++i)
#pragma unroll
        for (int j = 0; j < 2; ++j)
            acc[i][j] = __builtin_amdgcn_mfma_f32_16x16x32_bf16(af[i], bfv[j], acc[i][j], 0, 0, 0);
        __syncthreads();
    }

    float* C = Cout + (long)batch * sC;
#pragma unroll
    for (int i = 0; i < 2; ++i) {
#pragma unroll
        for (int r = 0; r < 4; ++r) {
            int gm = m0 + rbase + i*16 + lk*4 + r;
            if (gm >= M) continue;
#pragma unroll
            for (int j = 0; j < 2; ++j) {
                int gn = n0 + cbase + j*16 + lr;
                if (gn < N) C[(long)gm*ldc + gn] = acc[i][j][r];
            }
        }
    }
}

// ---------------- k0: fp32 split-K GEMM, BM=256 (all M), BN=64 (all N) ----------------
__global__ __launch_bounds__(256)
void k0_gemm(const float* __restrict__ A, const float* __restrict__ B,
             float* __restrict__ Cpart, int K, int kChunk)
{
    const int z = blockIdx.x;
    const int kStart = z * kChunk;
    const int kEnd = (kStart + kChunk < K) ? (kStart + kChunk) : K;
    __shared__ __align__(16) float As[16][260];
    __shared__ __align__(16) float Bs[16][64];
    const int tid = threadIdx.x;
    const int tx = tid & 15, ty = tid >> 4;
    float acc[16][4] = {};
    for (int kk = kStart; kk < kEnd; kk += 16) {
#pragma unroll
        for (int i = 0; i < 4; ++i) {
            int row = (tid >> 2) + i*64;
            int k4 = (tid & 3) * 4;
            long gk = kk + k4;
            float4 f = {0,0,0,0};
            if (gk + 3 < (long)kEnd) f = *(const float4*)(A + (long)row*K + gk);
            else {
                if (gk+0 < kEnd) f.x = A[(long)row*K+gk+0];
                if (gk+1 < kEnd) f.y = A[(long)row*K+gk+1];
                if (gk+2 < kEnd) f.z = A[(long)row*K+gk+2];
                if (gk+3 < kEnd) f.w = A[(long)row*K+gk+3];
            }
            As[k4+0][row]=f.x; As[k4+1][row]=f.y; As[k4+2][row]=f.z; As[k4+3][row]=f.w;
        }
        {
            int k = tid >> 4, n = (tid & 15) * 4;
            long gk = kk + k;
            float4 f = {0,0,0,0};
            if (gk < kEnd) f = *(const float4*)(B + gk*64 + n);
            *(float4*)&Bs[k][n] = f;
        }
        __syncthreads();
#pragma unroll
        for (int k = 0; k < 16; ++k) {
            float4 b4 = *reinterpret_cast<const float4*>(&Bs[k][tx*4]);
            float bw[4] = {b4.x,b4.y,b4.z,b4.w};
#pragma unroll
            for (int i4 = 0; i4 < 4; ++i4) {
                float4 a4 = *reinterpret_cast<const float4*>(&As[k][ty*16 + i4*4]);
                float av[4] = {a4.x,a4.y,a4.z,a4.w};
#pragma unroll
                for (int r = 0; r < 4; ++r)
#pragma unroll
                for (int j = 0; j < 4; ++j) acc[i4*4+r][j] += av[r]*bw[j];
            }
        }
        __syncthreads();
    }
    float* cp = Cpart + (long)z*256*64;
#pragma unroll
    for (int i = 0; i < 16; ++i) {
        int gm = ty*16 + i;
#pragma unroll
        for (int j = 0; j < 4; ++j)
            cp[(long)gm*64 + tx*4 + j] = acc[i][j];
    }
}

__global__ __launch_bounds__(256)
void k_reduce_splitk(const float* __restrict__ Cpart, float* __restrict__ out,
                     long ldcOut, long sOut,
                     const float* __restrict__ bias, long sBias,
                     int nbatch, int M, int N, int nsplit)
{
    long idx = (long)blockIdx.x*256 + threadIdx.x;
    long total = (long)nbatch*M*N;
    if (idx >= total) return;
    int n = idx % N; long t = idx / N;
    int m = t % M; int bi = t / M;
    const float* p = Cpart + ((long)bi*nsplit)*((long)M*N) + (long)m*N + n;
    float s = bias ? bias[(long)bi*sBias + n] : 0.f;
#pragma unroll 8
    for (int si = 0; si < nsplit; ++si) s += p[(long)si*M*N];
    out[(long)bi*sOut + (long)m*ldcOut + n] = s;
}

// ---------------- q ----------------
__global__ __launch_bounds__(256)
void k_q(const float* __restrict__ opt, const float* __restrict__ hx,
         const float* __restrict__ Wq, float* __restrict__ q)
{
    int idx = blockIdx.x*256 + threadIdx.x;
    if (idx >= NB*NU*NDK) return;
    int k = idx & 63; int t = idx >> 6;
    int u = t & 7; int b = t >> 3;
    const float* hxr = hx + (long)(b*NU+u)*NH;
    float acc = 0.f;
    for (int o = 0; o < NO; ++o) {
        const float* w = Wq + ((long)(o*NU+u)*NH)*NDK + k;
        float s = 0.f;
        for (int h = 0; h < NH; ++h) s += hxr[h] * w[(long)h*NDK];
        acc += opt[b*NO+o] * s;
    }
    q[idx] = acc;
}

// ---------------- scores + softmax(2) + attn_in + real ----------------
__global__ __launch_bounds__(64)
void k_attn(const float* __restrict__ q, const float* __restrict__ k0,
            const float* __restrict__ bk, const float* __restrict__ v0,
            const float* __restrict__ bv, float* __restrict__ attn,
            float* __restrict__ real)
{
    int bu = blockIdx.x;
    int lane = threadIdx.x;
    int b = bu >> 3;
    float qv = q[(long)bu*NDK + lane];
    float s0 = qv * k0[(long)b*NDK + lane];
    float s1 = qv * bk[lane];
    for (int off = 32; off; off >>= 1) {
        s0 += __shfl_xor(s0, off);
        s1 += __shfl_xor(s1, off);
    }
    s0 *= 0.125f; s1 *= 0.125f;
    float mx = fmaxf(s0, s1);
    float e0 = expf(s0-mx), e1 = expf(s1-mx);
    float inv = 1.f/(e0+e1);
    float p0 = e0*inv, p1 = e1*inv;
    if (lane == 0) real[bu] = p0;
    for (int v = lane; v < NV; v += 64)
        attn[(long)bu*NV + v] = p0*v0[(long)b*NV + v] + p1*bv[v];
}

// ---------------- top-k mask ----------------
__global__ void k_topk(const float* __restrict__ real, float* __restrict__ mask)
{
    int b = blockIdx.x*blockDim.x + threadIdx.x;
    if (b >= NB) return;
    float v[NU]; bool sel[NU];
#pragma unroll
    for (int i = 0; i < NU; ++i) { v[i] = real[b*NU+i]; sel[i] = false; }
    for (int t = 0; t < NKT; ++t) {
        int best = 0; float bvv = -1e30f;
#pragma unroll
        for (int i = 0; i < NU; ++i)
            if (!sel[i] && v[i] > bvv) { bvv = v[i]; best = i; }
        sel[best] = true;
    }
#pragma unroll
    for (int i = 0; i < NU; ++i) mask[b*NU+i] = sel[i] ? 1.f : 0.f;
}

// ---------------- LSTM gates (pre = pre_i + pre_h + blstm) ----------------
__global__ __launch_bounds__(256)
void k_gates(const float* __restrict__ pre_i, const float* __restrict__ pre_h,
             const float* __restrict__ blstm, const float* __restrict__ cx,
             float* __restrict__ cn, float* __restrict__ hn)
{
    int idx = blockIdx.x*256 + threadIdx.x;
    if (idx >= NB*NU*NH) return;
    int h = idx & 127; int bu = idx >> 7;
    int u = bu & 7;
    const float* pi = pre_i + (long)bu*512;
    const float* ph = pre_h + (long)bu*512;
    const float* bl = blstm + (long)u*512;
    float ig = pi[h]     + ph[h]     + bl[h];
    float fg = pi[128+h] + ph[128+h] + bl[128+h];
    float gg = pi[256+h] + ph[256+h] + bl[256+h];
    float og = pi[384+h] + ph[384+h] + bl[384+h];
    float si = 1.f/(1.f+expf(-ig));
    float sf = 1.f/(1.f+expf(-fg));
    float so = 1.f/(1.f+expf(-og));
    float c = sf*cx[idx] + si*tanhf(gg);
    cn[idx] = c;
    hn[idx] = so*tanhf(c);
}

// ---------------- qc,kc ----------------
__global__ __launch_bounds__(256)
void k_qckc(const float* __restrict__ hn, const float* __restrict__ Wqc,
            const float* __restrict__ Wkc, float* __restrict__ qc,
            float* __restrict__ kc)
{
    int idx = blockIdx.x*256 + threadIdx.x;
    if (idx >= NB*NU*64) return;
    int j = idx & 63; int t = idx >> 6;
    int u = t & 7; int b = t >> 3;
    int k = j & 31;
    const float* W = (j < 32 ? Wqc : Wkc) + ((long)u*NH)*NDKC + k;
    const float* h = hn + (long)(b*NU+u)*NH;
    float s = 0.f;
    for (int hh = 0; hh < NH; ++hh) s += h[hh]*W[(long)hh*NDKC];
    (j < 32 ? qc : kc)[(b*NU+u)*NDKC + k] = s;
}

// ---------------- comm probs ----------------
__global__ __launch_bounds__(64)
void k_cp(const float* __restrict__ qc, const float* __restrict__ kc,
          const float* __restrict__ mask, float* __restrict__ cp)
{
    int b = blockIdx.x;
    int lane = threadIdx.x;
    int u = lane >> 3, n = lane & 7;
    const float* qr = qc + (long)(b*NU+u)*NDKC;
    const float* kr = kc + (long)(b*NU+n)*NDKC;
    float d = 0.f;
    for (int k = 0; k < NDKC; ++k) d += qr[k]*kr[k];
    d *= 0.17677669529663687f;
    float mx = d;
    for (int off = 4; off; off >>= 1) mx = fmaxf(mx, __shfl_xor(mx, off, 8));
    float e = expf(d-mx);
    float sm = e;
    for (int off = 4; off; off >>= 1) sm += __shfl_xor(sm, off, 8);
    cp[b*64 + lane] = (e/sm) * mask[b*NU+u];
}

// ---------------- ctx (bf16 in/out) ----------------
__global__ __launch_bounds__(256)
void k_ctx(const unsigned short* __restrict__ vc, const float* __restrict__ cp,
           unsigned short* __restrict__ ctx)
{
    int b = blockIdx.y;
    int v = blockIdx.x*256 + threadIdx.x;
    __shared__ float cps[64];
    if (threadIdx.x < 64) cps[threadIdx.x] = cp[b*64 + threadIdx.x];
    __syncthreads();
    if (v >= NCV) return;
    float vv[NU];
#pragma unroll
    for (int n = 0; n < NU; ++n) vv[n] = bf2f(vc[((long)(b*NU+n))*NCV + v]);
#pragma unroll
    for (int u = 0; u < NU; ++u) {
        float s = 0.f;
#pragma unroll
        for (int n = 0; n < NU; ++n) s += cps[u*8+n]*vv[n];
        ctx[((long)(b*NU+u))*NCV + v] = f2bf(s);
    }
}

// ---------------- fused tail: blend + hy-sum + logits-softmax ----------------
__global__ __launch_bounds__(128)
void k_tail(const float* __restrict__ hn, const float* __restrict__ cn,
            const float* __restrict__ hcw, const float* __restrict__ hx,
            const float* __restrict__ cx, const float* __restrict__ mask,
            const float* __restrict__ piw, const float* __restrict__ pib,
            float* __restrict__ hy, float* __restrict__ cy,
            float* __restrict__ out)
{
    const int b = blockIdx.x;
    const int h = threadIdx.x;
    __shared__ float hs[128];
    __shared__ float lg[28];
    float s = 0.f;
#pragma unroll
    for (int u = 0; u < NU; ++u) {
        int idx = (b*NU+u)*NH + h;
        float m = mask[b*NU+u];
        float hyv = m*(hn[idx]+hcw[idx]) + (1.f-m)*hx[idx];
        float cyv = m*cn[idx] + (1.f-m)*cx[idx];
        hy[idx] = hyv; cy[idx] = cyv;
        s += hyv;
    }
    hs[h] = s;
    __syncthreads();
    if (h < 28) {
        int o = h / 7, a = h - o*7;
        float acc = pib[o*NA+a];
        for (int k = 0; k < NH; ++k) acc += hs[k] * piw[((long)o*NH+k)*NA + a];
        lg[h] = acc;
    }
    __syncthreads();
    if (h < NO) {
        float mx = lg[h*NA];
#pragma unroll
        for (int a = 1; a < NA; ++a) mx = fmaxf(mx, lg[h*NA+a]);
        float e[NA]; float sm = 0.f;
#pragma unroll
        for (int a = 0; a < NA; ++a) { e[a] = expf(lg[h*NA+a]-mx); sm += e[a]; }
        float inv = 1.f/sm;
#pragma unroll
        for (int a = 0; a < NA; ++a) out[(long)b*NO*NA + h*NA + a] = e[a]*inv;
    }
}

extern "C" void kernel_launch(void* const* d_in, const int* in_sizes, int n_in,
                              void* d_out, int out_size, void* d_ws, size_t ws_size,
                              hipStream_t stream) {
    const float* x    = (const float*)d_in[0];
    const float* hx   = (const float*)d_in[1];
    const float* cx   = (const float*)d_in[2];
    const float* opt  = (const float*)d_in[3];
    const float* c1w  = (const float*)d_in[4];
    const float* c1b  = (const float*)d_in[5];
    const float* c2w  = (const float*)d_in[6];
    const float* c2b  = (const float*)d_in[7];
    const float* c3w  = (const float*)d_in[8];
    const float* c3b  = (const float*)d_in[9];
    const float* Wk   = (const float*)d_in[10];
    const float* bk   = (const float*)d_in[11];
    const float* Wv   = (const float*)d_in[12];
    const float* bv   = (const float*)d_in[13];
    const float* Wq   = (const float*)d_in[14];
    const float* Wi   = (const float*)d_in[15];
    const float* Wh   = (const float*)d_in[16];
    const float* blstm= (const float*)d_in[17];
    const float* Wqc  = (const float*)d_in[18];
    const float* Wkc  = (const float*)d_in[19];
    const float* Wvc  = (const float*)d_in[20];
    const float* Wout = (const float*)d_in[21];
    const float* piw  = (const float*)d_in[22];
    const float* pib  = (const float*)d_in[23];

    float* out = (float*)d_out;
    float* hy  = out + (long)NB*NO*NA;
    float* cy  = hy + (long)NB*NU*NH;

    float* ws = (float*)d_ws;
    long o = 0;
    float* b_k0  = ws + o; o += 16384;
    float* b_v0  = ws + o; o += 102400;
    float* b_q   = ws + o; o += 131072;
    float* b_at  = ws + o; o += 819200;
    float* b_re  = ws + o; o += 2048;
    float* b_mk  = ws + o; o += 2048;
    float* b_pre = ws + o; o += 1048576;
    float* b_cn  = ws + o; o += 262144;
    float* b_hn  = ws + o; o += 262144;
    float* b_qc  = ws + o; o += 65536;
    float* b_kc  = ws + o; o += 65536;
    float* b_cp  = ws + o; o += 16384;
    float* b_hc  = ws + o; o += 262144;
    float* b_hs  = ws + o; o += 32768;
    // o == 3088384 — layout identical to the proven 465 µs round (all spans audited):
    //  P1OFF: p1 -> WvT -> WvcT+WoutT+partW | C2OFF: c2
    //  EMBOFF: emb32 -> v0 partials -> vc16+ctx16
    //  TOFF: k0 partials -> emb16 -> WiT+WhT+pre_h
    constexpr long P1OFF  = 3088384;
    constexpr long C2OFF  = 7024640;
    constexpr long EMBOFF = 14397440;
    constexpr long TOFF   = 28176384;
    constexpr long NEED   = TOFF + 5242880;   // 33,419,264 floats (proven)
    if (ws_size < (size_t)NEED * sizeof(float)) return;

    float* p1    = ws + P1OFF;
    float* c2    = ws + C2OFF;
    float* emb   = ws + EMBOFF;
    float* partK = ws + TOFF;                                    // k0 partials (S3)
    float* partV = ws + EMBOFF;                                  // v0 partials (S5, emb32 dead)
    unsigned short* emb16 = (unsigned short*)(ws + TOFF);        // S4-S5 (k0 partials dead)
    unsigned short* WvT   = (unsigned short*)(ws + P1OFF);       // S2-S5
    unsigned short* WiT   = (unsigned short*)(ws + TOFF);        // S7 (emb16 dead)
    unsigned short* WhT   = (unsigned short*)(ws + TOFF + 819200);
    float* pre_h          = ws + TOFF + 819200 + 262144;
    unsigned short* WvcT  = (unsigned short*)(ws + P1OFF);       // S8 (WvT dead)
    unsigned short* WoutT = (unsigned short*)(ws + P1OFF + 3444736);
    float* partW          = ws + P1OFF + 2*3444736;
    unsigned short* vc16  = (unsigned short*)(ws + EMBOFF);      // S9 (v0 partials dead)
    unsigned short* ctx16 = (unsigned short*)(ws + EMBOFF + 6889472);

    // S1) conv stack (dbuf staging — bit-identical outputs)
    k_conv1<<<(NB*16*H1*W1 + 255)/256, 256, 0, stream>>>(x, c1w, c1b, p1);
    conv2x2_gemm<32,16,H1,W1,H2,W2><<<NB*((H2*W2+127)/128), 256, 0, stream>>>(p1, c2w, c2b, c2);
    conv2x2_gemm<64,32,H2,W2,H3,W3><<<NB*((H3*W3+63)/64), 256, 0, stream>>>(c2, c3w, c3b, emb);

    // S2) Wv -> bf16 transposed [400][53824]  (p1/c2 dead)
    k_f2bt<<<dim3(13, 1682, 1), 256, 0, stream>>>(Wv, WvT, NE, NV, 0);

    // S3) k0 = emb@Wk + bk  (fp32 — precision-critical for top-k; S=320)
    k0_gemm<<<320, 256, 0, stream>>>(emb, Wk, partK, NE, 176);
    k_reduce_splitk<<<(NB*NDK + 255)/256, 256, 0, stream>>>(
        partK, b_k0, NDK, 0, bk, 0, 1, NB, NDK, 320);

    // S4) emb -> bf16 (RNE; k0 partials dead)
    k_cvt<<<((long)NB*NE/8 + 255)/256, 256, 0, stream>>>(emb, emb16, (long)NB*NE);

    // S5) v0 = emb16@Wv + bv  (bf16 MFMA, 128x128, S=87; partials at EMBOFF)
    bgemm_splitk<128,128,false><<<dim3(4,2,87), 256, 0, stream>>>(
        emb16, NE, 0, WvT, NE, 0, partV, NB, NV, NE, 87, 624);
    k_reduce_splitk<<<(NB*NV + 255)/256, 256, 0, stream>>>(
        partV, b_v0, NV, 0, bv, 0, 1, NB, NV, 87);

    // S6) q / attention / top-k
    k_q<<<(NB*NU*NDK + 255)/256, 256, 0, stream>>>(opt, hx, Wq, b_q);
    k_attn<<<NB*NU, 64, 0, stream>>>(b_q, b_k0, bk, b_v0, bv, b_at, b_re);
    k_topk<<<1, 256, 0, stream>>>(b_re, b_mk);

    // S7) LSTM pre in bf16 MFMA (fp32 accum/out) — proven round 10
    k_f2bt<<<dim3(16, 13, 8), 256, 0, stream>>>(Wi, WiT, NV, 512, (long)NV*512);
    k_f2bt<<<dim3(16, 4, 8), 256, 0, stream>>>(Wh, WhT, NH, 512, (long)NH*512);
    bgemm_f32<true><<<dim3(8, 4, NU), 256, 0, stream>>>(
        b_at, (long)NU*NV, NV, WiT, NV, (long)512*NV,
        b_pre, (long)NU*512, 512, NB, 512, NV);
    bgemm_f32<true><<<dim3(8, 4, NU), 256, 0, stream>>>(
        hx, (long)NU*NH, NH, WhT, NH, (long)512*NH,
        pre_h, (long)NU*512, 512, NB, 512, NH);
    k_gates<<<(NB*NU*NH + 255)/256, 256, 0, stream>>>(b_pre, pre_h, blstm, cx, b_cn, b_hn);

    // S8) convert Wvc/Wout (WvT dead after v0)
    k_f2bt<<<dim3(211, 4, 8), 256, 0, stream>>>(Wvc, WvcT, NH, NCV, (long)NH*NCV);
    k_f2bt<<<dim3(4, 211, 8), 256, 0, stream>>>(Wout, WoutT, NCV, NH, (long)NCV*NH);

    // S9) vc = h_new@Wvc (bf16 MFMA direct, bf16 out)  (v0 partials dead)
    bgemm_direct<true><<<dim3((NCV+127)/128, 2, NU), 256, 0, stream>>>(
        b_hn, (long)NU*NH, NH, WvcT, NH, (long)NCV*NH,
        vc16, (long)NU*NCV, NCV, NB, NCV, NH);

    // S10) comm probs + ctx
    k_qckc<<<(NB*NU*64 + 255)/256, 256, 0, stream>>>(b_hn, Wqc, Wkc, b_qc, b_kc);
    k_cp<<<NB, 64, 0, stream>>>(b_qc, b_kc, b_mk, b_cp);
    k_ctx<<<dim3((NCV+255)/256, NB), 256, 0, stream>>>(vc16, b_cp, ctx16);

    // S11) hcomm_w = ctx@Wout (bf16 MFMA split-K 16)
    bgemm_splitk<64,64,false><<<dim3(2,4,NU*16), 256, 0, stream>>>(
        ctx16, (long)NU*NCV, NCV, WoutT, NCV, (long)NCV*NH,
        partW, NB, NH, NCV, 16, 448);
    k_reduce_splitk<<<(NU*NB*NH + 255)/256, 256, 0, stream>>>(
        partW, b_hc, (long)NU*NH, NH, nullptr, 0, NU, NB, NH, 16);

    // S12) fused blend + hy-sum + logits
    k_tail<<<NB, 128, 0, stream>>>(b_hn, b_cn, b_hc, hx, cx, b_mk, piw, pib, hy, cy, out);
}

// Round 15
// 443.289 us; speedup vs baseline: 1.0961x; 1.0374x over previous
//
#include <hip/hip_runtime.h>
#include <math.h>

namespace {
constexpr int NB  = 256;
constexpr int NU  = 8;
constexpr int NKT = 4;
constexpr int NH  = 128;
constexpr int NO  = 4;
constexpr int NA  = 7;
constexpr int NV  = 400;
constexpr int NE  = 53824;
constexpr int NCV = 6728;
constexpr int NDK = 64;
constexpr int NDKC= 32;

constexpr int H1 = 31, W1 = 31;
constexpr int H2 = 30, W2 = 30;
constexpr int H3 = 29, W3 = 29;
}

typedef __attribute__((ext_vector_type(8))) short bf16x8_t;
typedef __attribute__((ext_vector_type(4))) float f32x4_t;

__device__ __forceinline__ unsigned short f2bf(float f) {
    unsigned int u = __float_as_uint(f);
    u += 0x7FFFu + ((u >> 16) & 1u);   // RNE
    return (unsigned short)(u >> 16);
}
__device__ __forceinline__ float bf2f(unsigned short h) {
    return __uint_as_float((unsigned int)h << 16);
}

// ---------------- conv1 (2x2, 3->16) + relu + maxpool2 ----------------
__global__ __launch_bounds__(256)
void k_conv1(const float* __restrict__ x, const float* __restrict__ w,
             const float* __restrict__ bias, float* __restrict__ out)
{
    __shared__ float ws[16*3*2*2];
    __shared__ float bs[16];
    int tid = threadIdx.x;
    if (tid < 192) ws[tid] = w[tid];
    if (tid < 16)  bs[tid] = bias[tid];
    __syncthreads();
    long idx = (long)blockIdx.x*256 + tid;
    if (idx >= (long)NB*16*H1*W1) return;
    int pw = idx % W1; long t = idx / W1;
    int ph = t % H1; t /= H1;
    int oc = t % 16; int b = t / 16;
    float mx = 0.f;
#pragma unroll
    for (int dh = 0; dh < 2; ++dh)
#pragma unroll
    for (int dw = 0; dw < 2; ++dw) {
        int h = 2*ph + dh, ww = 2*pw + dw;
        float s = bs[oc];
#pragma unroll
        for (int kh = 0; kh < 2; ++kh)
#pragma unroll
        for (int kw = 0; kw < 2; ++kw) {
            const float* xp = x + (((long)b*64 + (h+kh))*64 + (ww+kw))*3;
#pragma unroll
            for (int ic = 0; ic < 3; ++ic)
                s += xp[ic] * ws[((oc*3+ic)*2+kh)*2+kw];
        }
        mx = fmaxf(mx, s);
    }
    out[idx] = mx;
}

// ---------------- conv2 (2x2, 16->32) as implicit GEMM, 4x4 micro, dbuf ----------------
template<int OC, int IC, int HIN, int WIN, int HOUT, int WOUT>
__global__ __launch_bounds__(256)
void conv2x2_gemm(const float* __restrict__ in, const float* __restrict__ w,
                  const float* __restrict__ bias, float* __restrict__ out)
{
    constexpr int K    = IC*4;
    constexpr int TY   = OC/4;
    constexpr int TX   = 256/TY;
    constexpr int NT   = TX*4;
    constexpr int SPAT = HOUT*WOUT;
    constexpr int NBLK = (SPAT + NT - 1)/NT;
    constexpr int AIT  = OC*16/256;
    constexpr int BIT  = 16*NT/256;

    const int b  = blockIdx.x / NBLK;
    const int n0 = (blockIdx.x % NBLK) * NT;

    __shared__ __align__(16) float As[2][16][OC+4];
    __shared__ __align__(16) float Bs[2][16][NT];

    const int tid = threadIdx.x;
    const int tx = tid % TX, ty = tid / TX;
    float acc[4][4] = {};
    const float* inb = in + (long)b*IC*HIN*WIN;

    const int nIdx = tid & (NT-1);
    int ohw = 0; bool nOk = false;
    {
        int s = n0 + nIdx;
        if (s < SPAT) { ohw = (s / WOUT) * WIN + (s % WOUT); nOk = true; }
    }

    float aR[AIT], bR[BIT];
    auto loadAB = [&](int kk) {
#pragma unroll
        for (int i = 0; i < AIT; ++i) {
            int lin = tid + i*256;
            aR[i] = w[(lin/16)*K + kk + (lin%16)];
        }
#pragma unroll
        for (int i = 0; i < BIT; ++i) {
            int k = (tid + i*256) / NT;
            int gk = kk + k;
            int ic = gk >> 2, tap = gk & 3;
            bR[i] = nOk ? inb[ic*HIN*WIN + ohw + (tap>>1)*WIN + (tap&1)] : 0.f;
        }
    };
    auto storeAB = [&](int buf) {
#pragma unroll
        for (int i = 0; i < AIT; ++i) {
            int lin = tid + i*256;
            As[buf][lin%16][lin/16] = aR[i];
        }
#pragma unroll
        for (int i = 0; i < BIT; ++i) {
            int k = (tid + i*256) / NT;
            Bs[buf][k][nIdx] = bR[i];
        }
    };

    loadAB(0);
    storeAB(0);
    __syncthreads();
    int cur = 0;
    for (int kk = 0; kk < K; kk += 16) {
        const bool more = (kk + 16 < K);
        if (more) loadAB(kk + 16);
#pragma unroll
        for (int k = 0; k < 16; ++k) {
            float4 a4 = *reinterpret_cast<const float4*>(&As[cur][k][ty*4]);
            float4 b4 = *reinterpret_cast<const float4*>(&Bs[cur][k][tx*4]);
            float av[4] = {a4.x,a4.y,a4.z,a4.w};
            float bw[4] = {b4.x,b4.y,b4.z,b4.w};
#pragma unroll
            for (int i = 0; i < 4; ++i)
#pragma unroll
            for (int j = 0; j < 4; ++j) acc[i][j] += av[i]*bw[j];
        }
        if (more) {
            storeAB(cur ^ 1);
            __syncthreads();
            cur ^= 1;
        }
    }
#pragma unroll
    for (int i = 0; i < 4; ++i) {
        int gm = ty*4 + i;
        float bi = bias[gm];
#pragma unroll
        for (int j = 0; j < 4; ++j) {
            int s = n0 + tx*4 + j;
            if (s < SPAT)
                out[((long)b*OC + gm)*SPAT + s] = fmaxf(acc[i][j] + bi, 0.f);
        }
    }
}

// ---------------- conv3 via hi/lo-split bf16 MFMA (fp32-accurate, rel err ~2^-18) ----------------
// GEMM: emb[b][oc][s] = relu(sum_k W[oc][k] * im2col[k][s] + bias[oc])
// M=oc(64, BM=64), N=spatial(841, BN=128 tiles), K=128 (4 chunks of 32).
// a*b ~= ah*bh + ah*bl + al*bh where x = bf16(x) + bf16(x - bf16(x)).
__global__ __launch_bounds__(256)
void conv3_mfma(const float* __restrict__ c2, const float* __restrict__ w,
                const float* __restrict__ bias, float* __restrict__ emb)
{
    constexpr int SPAT = 29*29;   // 841
    constexpr int WIN  = 30;
    const int b  = blockIdx.y;
    const int n0 = blockIdx.x * 128;

    __shared__ __align__(16) unsigned short Ah[4*64*32], Al[4*64*32];  // W hi/lo, all K
    __shared__ __align__(16) unsigned short Bh[128*32],  Bl[128*32];   // im2col chunk

    const int tid = threadIdx.x;
    const int wave = tid >> 6, lane = tid & 63;
    const int wr = wave >> 1, wc = wave & 1;
    const int lr = lane & 15, lk = lane >> 4;
    const int rbase = wr*32, cbase = wc*64;    // BM/2=32, BN/2=64

    const float* c2b = c2 + (long)b*32*900;

    // stage all of W hi/lo: thread -> row(oc)=tid>>2, kblk=tid&3; 4 chunks
    {
        int row = tid >> 2, kb = tid & 3;
        int p = (kb ^ (row & 3)) << 3;
#pragma unroll
        for (int c = 0; c < 4; ++c) {
            unsigned short hh[8], ll[8];
#pragma unroll
            for (int j = 0; j < 8; ++j) {
                float v = w[(long)row*128 + c*32 + kb*8 + j];
                unsigned short h = f2bf(v);
                hh[j] = h; ll[j] = f2bf(v - bf2f(h));
            }
            *(ushort4*)&Ah[c*2048 + row*32 + p]     = make_ushort4(hh[0],hh[1],hh[2],hh[3]);
            *(ushort4*)&Ah[c*2048 + row*32 + p + 4] = make_ushort4(hh[4],hh[5],hh[6],hh[7]);
            *(ushort4*)&Al[c*2048 + row*32 + p]     = make_ushort4(ll[0],ll[1],ll[2],ll[3]);
            *(ushort4*)&Al[c*2048 + row*32 + p + 4] = make_ushort4(ll[4],ll[5],ll[6],ll[7]);
        }
    }

    // B (im2col) row assignment: spatial rows tid>>2 and +64; hoisted offsets
    const int br0 = tid >> 2, br1 = br0 + 64;
    const int kb  = tid & 3;
    int base0 = 0, base1 = 0; bool ok0, ok1;
    { int s = n0 + br0; ok0 = s < SPAT; if (ok0) base0 = (s/29)*WIN + (s%29); }
    { int s = n0 + br1; ok1 = s < SPAT; if (ok1) base1 = (s/29)*WIN + (s%29); }

    f32x4_t acc[2][4];
#pragma unroll
    for (int i = 0; i < 2; ++i)
#pragma unroll
    for (int j = 0; j < 4; ++j) acc[i][j] = (f32x4_t){0.f,0.f,0.f,0.f};

    for (int c = 0; c < 4; ++c) {
        __syncthreads();   // c=0: W-stage visible; c>0: prior readers done before overwrite
#pragma unroll
        for (int rr = 0; rr < 2; ++rr) {
            int row   = rr ? br1 : br0;
            bool ok   = rr ? ok1 : ok0;
            int base  = rr ? base1 : base0;
            int p = (kb ^ (row & 3)) << 3;
            unsigned short hh[8], ll[8];
#pragma unroll
            for (int j = 0; j < 8; ++j) {
                int gk = c*32 + kb*8 + j;
                int ic = gk >> 2, tap = gk & 3;
                float v = ok ? c2b[ic*900 + base + (tap>>1)*WIN + (tap&1)] : 0.f;
                unsigned short h = f2bf(v);
                hh[j] = h; ll[j] = f2bf(v - bf2f(h));
            }
            *(ushort4*)&Bh[row*32 + p]     = make_ushort4(hh[0],hh[1],hh[2],hh[3]);
            *(ushort4*)&Bh[row*32 + p + 4] = make_ushort4(hh[4],hh[5],hh[6],hh[7]);
            *(ushort4*)&Bl[row*32 + p]     = make_ushort4(ll[0],ll[1],ll[2],ll[3]);
            *(ushort4*)&Bl[row*32 + p + 4] = make_ushort4(ll[4],ll[5],ll[6],ll[7]);
        }
        __syncthreads();
        bf16x8_t ah[2], al[2], bh[4], bl[4];
#pragma unroll
        for (int i = 0; i < 2; ++i) {
            int row = rbase + i*16 + lr;
            int off = c*2048 + row*32 + ((lk ^ (row & 3)) << 3);
            ah[i] = *(const bf16x8_t*)&Ah[off];
            al[i] = *(const bf16x8_t*)&Al[off];
        }
#pragma unroll
        for (int j = 0; j < 4; ++j) {
            int col = cbase + j*16 + lr;
            int off = col*32 + ((lk ^ (col & 3)) << 3);
            bh[j] = *(const bf16x8_t*)&Bh[off];
            bl[j] = *(const bf16x8_t*)&Bl[off];
        }
#pragma unroll
        for (int i = 0; i < 2; ++i)
#pragma unroll
        for (int j = 0; j < 4; ++j) {
            acc[i][j] = __builtin_amdgcn_mfma_f32_16x16x32_bf16(ah[i], bh[j], acc[i][j], 0,0,0);
            acc[i][j] = __builtin_amdgcn_mfma_f32_16x16x32_bf16(ah[i], bl[j], acc[i][j], 0,0,0);
            acc[i][j] = __builtin_amdgcn_mfma_f32_16x16x32_bf16(al[i], bh[j], acc[i][j], 0,0,0);
        }
    }

    // epilogue: bias + relu; C[oc][s] -> emb[b][oc][s], lane-contiguous in s
#pragma unroll
    for (int i = 0; i < 2; ++i)
#pragma unroll
    for (int r = 0; r < 4; ++r) {
        int gm = rbase + i*16 + lk*4 + r;       // oc
        float bi = bias[gm];
#pragma unroll
        for (int j = 0; j < 4; ++j) {
            int gn = n0 + cbase + j*16 + lr;    // spatial
            if (gn < SPAT)
                emb[((long)b*64 + gm)*SPAT + gn] = fmaxf(acc[i][j][r] + bi, 0.f);
        }
    }
}

// ---------------- fp32 -> bf16 elementwise convert (n multiple of 8) ----------------
__global__ __launch_bounds__(256)
void k_cvt(const float* __restrict__ in, unsigned short* __restrict__ out, long n)
{
    long i = ((long)blockIdx.x*256 + threadIdx.x) * 8;
    if (i >= n) return;
    float4 a = *(const float4*)(in + i);
    float4 b = *(const float4*)(in + i + 4);
    uint4 u;
    u.x = (unsigned)f2bf(a.x) | ((unsigned)f2bf(a.y) << 16);
    u.y = (unsigned)f2bf(a.z) | ((unsigned)f2bf(a.w) << 16);
    u.z = (unsigned)f2bf(b.x) | ((unsigned)f2bf(b.y) << 16);
    u.w = (unsigned)f2bf(b.z) | ((unsigned)f2bf(b.w) << 16);
    *(uint4*)(out + i) = u;
}

// ---------------- fp32 -> bf16 transposed convert: in [B][R][Cc] -> out [B][Cc][R] ----------------
__global__ __launch_bounds__(256)
void k_f2bt(const float* __restrict__ in, unsigned short* __restrict__ out,
            int R, int Cc, long sIn)
{
    __shared__ unsigned short t[32][33];
    const int b = blockIdx.z;
    const int r0 = blockIdx.y * 32, c0 = blockIdx.x * 32;
    const float* ip = in + (long)b * sIn;
    unsigned short* op = out + (long)b * sIn;
    const int tid = threadIdx.x;
    {
        int rr = tid >> 3, c4 = (tid & 7) * 4;
        int gr = r0 + rr;
        unsigned short h0=0,h1=0,h2=0,h3=0;
        if (gr < R) {
            if (c0 + c4 + 3 < Cc) {
                float4 f = *(const float4*)(ip + (long)gr*Cc + c0 + c4);
                h0=f2bf(f.x); h1=f2bf(f.y); h2=f2bf(f.z); h3=f2bf(f.w);
            } else {
                if (c0+c4+0 < Cc) h0 = f2bf(ip[(long)gr*Cc + c0+c4+0]);
                if (c0+c4+1 < Cc) h1 = f2bf(ip[(long)gr*Cc + c0+c4+1]);
                if (c0+c4+2 < Cc) h2 = f2bf(ip[(long)gr*Cc + c0+c4+2]);
                if (c0+c4+3 < Cc) h3 = f2bf(ip[(long)gr*Cc + c0+c4+3]);
            }
        }
        t[rr][c4+0]=h0; t[rr][c4+1]=h1; t[rr][c4+2]=h2; t[rr][c4+3]=h3;
    }
    __syncthreads();
    {
        int cc = tid >> 3, r4 = (tid & 7) * 4;
        int gc = c0 + cc;
        if (gc < Cc && r0 + r4 < R) {
            if (r0 + r4 + 3 < R) {
                *(ushort4*)(op + (long)gc*R + r0 + r4) =
                    make_ushort4(t[r4+0][cc], t[r4+1][cc], t[r4+2][cc], t[r4+3][cc]);
            } else {
#pragma unroll
                for (int j = 0; j < 4; ++j)
                    if (r0 + r4 + j < R) op[(long)gc*R + r0 + r4 + j] = t[r4+j][cc];
            }
        }
    }
}

// ---------------- bf16 MFMA GEMM staging, 16B-wide ----------------
template<int ROWS, bool F32>
__device__ __forceinline__ void stage_tile(const void* __restrict__ Av, long lda,
                                           int m0, int kk, int kEnd, int Mlim,
                                           unsigned short* lds, int tid)
{
#pragma unroll
    for (int i = 0; i < ROWS/64; ++i) {
        int row = (tid >> 2) + i*64;
        int blk = tid & 3;
        long gm = m0 + row;
        long gk = kk + blk*8;
        ushort4 lo = make_ushort4(0,0,0,0), hi = make_ushort4(0,0,0,0);
        if (gm < Mlim && gk < kEnd) {
            if (F32) {
                const float* A = (const float*)Av + gm*lda + gk;
                float4 f0 = *(const float4*)(A);
                float4 f1 = *(const float4*)(A + 4);
                lo = make_ushort4(f2bf(f0.x),f2bf(f0.y),f2bf(f0.z),f2bf(f0.w));
                hi = make_ushort4(f2bf(f1.x),f2bf(f1.y),f2bf(f1.z),f2bf(f1.w));
            } else {
                const unsigned short* A = (const unsigned short*)Av + gm*lda + gk;
                lo = *(const ushort4*)(A);
                hi = *(const ushort4*)(A + 4);
            }
        }
        int p = (blk ^ (row & 3)) << 3;
        *(ushort4*)&lds[row*32 + p]     = lo;
        *(ushort4*)&lds[row*32 + p + 4] = hi;
    }
}

template<int BM, int BN, bool AF32>
__global__ __launch_bounds__(256)
void bgemm_splitk(const void* __restrict__ Av, long lda, long sA,
                  const unsigned short* __restrict__ BT, long ldbt, long sB,
                  float* __restrict__ Cpart,
                  int M, int N, int K, int nsplit, int kChunk)
{
    constexpr int MR = BM/32, NR = BN/32;
    const int z = blockIdx.z;
    const int batch = z / nsplit, split = z - batch*nsplit;
    const int kStart = split * kChunk;
    const int kEnd = (kStart + kChunk < K) ? (kStart + kChunk) : K;
    const int m0 = blockIdx.y * BM;
    const int n0 = blockIdx.x * BN;

    __shared__ __align__(16) unsigned short As[BM*32];
    __shared__ __align__(16) unsigned short Bs[BN*32];

    const int tid = threadIdx.x;
    const int wave = tid >> 6, lane = tid & 63;
    const int wr = wave >> 1, wc = wave & 1;
    const int lr = lane & 15, lk = lane >> 4;
    const int rbase = wr*(BM/2), cbase = wc*(BN/2);

    const void* Ab = AF32 ? (const void*)((const float*)Av + (long)batch*sA)
                          : (const void*)((const unsigned short*)Av + (long)batch*sA);
    const unsigned short* Bb = BT + (long)batch*sB;

    f32x4_t acc[MR][NR];
#pragma unroll
    for (int i = 0; i < MR; ++i)
#pragma unroll
    for (int j = 0; j < NR; ++j)
        acc[i][j] = (f32x4_t){0.f,0.f,0.f,0.f};

    for (int kk = kStart; kk < kEnd; kk += 32) {
        stage_tile<BM,AF32>(Ab, lda, m0, kk, kEnd, M, As, tid);
        stage_tile<BN,false>((const void*)Bb, ldbt, n0, kk, kEnd, N, Bs, tid);
        __syncthreads();
        bf16x8_t af[MR], bfv[NR];
#pragma unroll
        for (int i = 0; i < MR; ++i) {
            int row = rbase + i*16 + lr;
            af[i] = *(const bf16x8_t*)&As[row*32 + ((lk ^ (row & 3)) << 3)];
        }
#pragma unroll
        for (int j = 0; j < NR; ++j) {
            int col = cbase + j*16 + lr;
            bfv[j] = *(const bf16x8_t*)&Bs[col*32 + ((lk ^ (col & 3)) << 3)];
        }
#pragma unroll
        for (int i = 0; i < MR; ++i)
#pragma unroll
        for (int j = 0; j < NR; ++j)
            acc[i][j] = __builtin_amdgcn_mfma_f32_16x16x32_bf16(af[i], bfv[j], acc[i][j], 0, 0, 0);
        __syncthreads();
    }

    const long cb2 = (long)z * M * N;
#pragma unroll
    for (int i = 0; i < MR; ++i) {
#pragma unroll
        for (int r = 0; r < 4; ++r) {
            int gm = m0 + rbase + i*16 + lk*4 + r;
            if (gm >= M) continue;
#pragma unroll
            for (int j = 0; j < NR; ++j) {
                int gn = n0 + cbase + j*16 + lr;
                if (gn < N) Cpart[cb2 + (long)gm*N + gn] = acc[i][j][r];
            }
        }
    }
}

// direct bf16 GEMM (full K), bf16 output, 128x128 tile
template<bool AF32>
__global__ __launch_bounds__(256)
void bgemm_direct(const void* __restrict__ Av, long lda, long sA,
                  const unsigned short* __restrict__ BT, long ldbt, long sB,
                  unsigned short* __restrict__ Cout, long ldc, long sC,
                  int M, int N, int K)
{
    const int batch = blockIdx.z;
    const int m0 = blockIdx.y * 128;
    const int n0 = blockIdx.x * 128;

    __shared__ __align__(16) unsigned short As[128*32];
    __shared__ __align__(16) unsigned short Bs[128*32];

    const int tid = threadIdx.x;
    const int wave = tid >> 6, lane = tid & 63;
    const int wr = wave >> 1, wc = wave & 1;
    const int lr = lane & 15, lk = lane >> 4;

    const void* Ab = AF32 ? (const void*)((const float*)Av + (long)batch*sA)
                          : (const void*)((const unsigned short*)Av + (long)batch*sA);
    const unsigned short* Bb = BT + (long)batch*sB;

    f32x4_t acc[4][4];
#pragma unroll
    for (int i = 0; i < 4; ++i)
#pragma unroll
    for (int j = 0; j < 4; ++j)
        acc[i][j] = (f32x4_t){0.f,0.f,0.f,0.f};

    for (int kk = 0; kk < K; kk += 32) {
        stage_tile<128,AF32>(Ab, lda, m0, kk, K, M, As, tid);
        stage_tile<128,false>((const void*)Bb, ldbt, n0, kk, K, N, Bs, tid);
        __syncthreads();
        bf16x8_t af[4], bfv[4];
#pragma unroll
        for (int i = 0; i < 4; ++i) {
            int row = wr*64 + i*16 + lr;
            af[i]  = *(const bf16x8_t*)&As[row*32 + ((lk ^ (row & 3)) << 3)];
            int col = wc*64 + i*16 + lr;
            bfv[i] = *(const bf16x8_t*)&Bs[col*32 + ((lk ^ (col & 3)) << 3)];
        }
#pragma unroll
        for (int i = 0; i < 4; ++i)
#pragma unroll
        for (int j = 0; j < 4; ++j)
            acc[i][j] = __builtin_amdgcn_mfma_f32_16x16x32_bf16(af[i], bfv[j], acc[i][j], 0, 0, 0);
        __syncthreads();
    }

    unsigned short* C = Cout + (long)batch * sC;
#pragma unroll
    for (int i = 0; i < 4; ++i) {
#pragma unroll
        for (int r = 0; r < 4; ++r) {
            int gm = m0 + wr*64 + i*16 + lk*4 + r;
            if (gm >= M) continue;
#pragma unroll
            for (int j = 0; j < 4; ++j) {
                int gn = n0 + wc*64 + j*16 + lr;
                if (gn < N) C[(long)gm*ldc + gn] = f2bf(acc[i][j][r]);
            }
        }
    }
}

// direct bf16-input GEMM, fp32 output, 64x64 tile, batched over grid.z (pre path)
template<bool AF32>
__global__ __launch_bounds__(256)
void bgemm_f32(const void* __restrict__ Av, long lda, long sA,
               const unsigned short* __restrict__ BT, long ldbt, long sB,
               float* __restrict__ Cout, long ldc, long sC,
               int M, int N, int K)
{
    const int batch = blockIdx.z;
    const int m0 = blockIdx.y * 64;
    const int n0 = blockIdx.x * 64;

    __shared__ __align__(16) unsigned short As[64*32];
    __shared__ __align__(16) unsigned short Bs[64*32];

    const int tid = threadIdx.x;
    const int wave = tid >> 6, lane = tid & 63;
    const int wr = wave >> 1, wc = wave & 1;
    const int lr = lane & 15, lk = lane >> 4;
    const int rbase = wr*32, cbase = wc*32;

    const void* Ab = AF32 ? (const void*)((const float*)Av + (long)batch*sA)
                          : (const void*)((const unsigned short*)Av + (long)batch*sA);
    const unsigned short* Bb = BT + (long)batch*sB;

    f32x4_t acc[2][2];
#pragma unroll
    for (int i = 0; i < 2; ++i)
#pragma unroll
    for (int j = 0; j < 2; ++j)
        acc[i][j] = (f32x4_t){0.f,0.f,0.f,0.f};

    for (int kk = 0; kk < K; kk += 32) {
        stage_tile<64,AF32>(Ab, lda, m0, kk, K, M, As, tid);
        stage_tile<64,false>((const void*)Bb, ldbt, n0, kk, K, N, Bs, tid);
        __syncthreads();
        bf16x8_t af[2], bfv[2];
#pragma unroll
        for (int i = 0; i < 2; ++i) {
            int row = rbase + i*16 + lr;
            af[i] = *(const bf16x8_t*)&As[row*32 + ((lk ^ (row & 3)) << 3)];
            int col = cbase + i*16 + lr;
            bfv[i] = *(const bf16x8_t*)&Bs[col*32 + ((lk ^ (col & 3)) << 3)];
        }
#pragma unroll
        for (int i = 0; i < 2; ++i)
#pragma unroll
        for (int j = 0; j < 2; ++j)
            acc[i][j] = __builtin_amdgcn_mfma_f32_16x16x32_bf16(af[i], bfv[j], acc[i][j], 0, 0, 0);
        __syncthreads();
    }

    float* C = Cout + (long)batch * sC;
#pragma unroll
    for (int i = 0; i < 2; ++i) {
#pragma unroll
        for (int r = 0; r < 4; ++r) {
            int gm = m0 + rbase + i*16 + lk*4 + r;
            if (gm >= M) continue;
#pragma unroll
            for (int j = 0; j < 2; ++j) {
                int gn = n0 + cbase + j*16 + lr;
                if (gn < N) C[(long)gm*ldc + gn] = acc[i][j][r];
            }
        }
    }
}

// ---------------- k0: fp32 split-K GEMM, BM=256 (all M), BN=64 (all N) ----------------
__global__ __launch_bounds__(256)
void k0_gemm(const float* __restrict__ A, const float* __restrict__ B,
             float* __restrict__ Cpart, int K, int kChunk)
{
    const int z = blockIdx.x;
    const int kStart = z * kChunk;
    const int kEnd = (kStart + kChunk < K) ? (kStart + kChunk) : K;
    __shared__ __align__(16) float As[16][260];
    __shared__ __align__(16) float Bs[16][64];
    const int tid = threadIdx.x;
    const int tx = tid & 15, ty = tid >> 4;
    float acc[16][4] = {};
    for (int kk = kStart; kk < kEnd; kk += 16) {
#pragma unroll
        for (int i = 0; i < 4; ++i) {
            int row = (tid >> 2) + i*64;
            int k4 = (tid & 3) * 4;
            long gk = kk + k4;
            float4 f = {0,0,0,0};
            if (gk + 3 < (long)kEnd) f = *(const float4*)(A + (long)row*K + gk);
            else {
                if (gk+0 < kEnd) f.x = A[(long)row*K+gk+0];
                if (gk+1 < kEnd) f.y = A[(long)row*K+gk+1];
                if (gk+2 < kEnd) f.z = A[(long)row*K+gk+2];
                if (gk+3 < kEnd) f.w = A[(long)row*K+gk+3];
            }
            As[k4+0][row]=f.x; As[k4+1][row]=f.y; As[k4+2][row]=f.z; As[k4+3][row]=f.w;
        }
        {
            int k = tid >> 4, n = (tid & 15) * 4;
            long gk = kk + k;
            float4 f = {0,0,0,0};
            if (gk < kEnd) f = *(const float4*)(B + gk*64 + n);
            *(float4*)&Bs[k][n] = f;
        }
        __syncthreads();
#pragma unroll
        for (int k = 0; k < 16; ++k) {
            float4 b4 = *reinterpret_cast<const float4*>(&Bs[k][tx*4]);
            float bw[4] = {b4.x,b4.y,b4.z,b4.w};
#pragma unroll
            for (int i4 = 0; i4 < 4; ++i4) {
                float4 a4 = *reinterpret_cast<const float4*>(&As[k][ty*16 + i4*4]);
                float av[4] = {a4.x,a4.y,a4.z,a4.w};
#pragma unroll
                for (int r = 0; r < 4; ++r)
#pragma unroll
                for (int j = 0; j < 4; ++j) acc[i4*4+r][j] += av[r]*bw[j];
            }
        }
        __syncthreads();
    }
    float* cp = Cpart + (long)z*256*64;
#pragma unroll
    for (int i = 0; i < 16; ++i) {
        int gm = ty*16 + i;
#pragma unroll
        for (int j = 0; j < 4; ++j)
            cp[(long)gm*64 + tx*4 + j] = acc[i][j];
    }
}

__global__ __launch_bounds__(256)
void k_reduce_splitk(const float* __restrict__ Cpart, float* __restrict__ out,
                     long ldcOut, long sOut,
                     const float* __restrict__ bias, long sBias,
                     int nbatch, int M, int N, int nsplit)
{
    long idx = (long)blockIdx.x*256 + threadIdx.x;
    long total = (long)nbatch*M*N;
    if (idx >= total) return;
    int n = idx % N; long t = idx / N;
    int m = t % M; int bi = t / M;
    const float* p = Cpart + ((long)bi*nsplit)*((long)M*N) + (long)m*N + n;
    float s = bias ? bias[(long)bi*sBias + n] : 0.f;
#pragma unroll 8
    for (int si = 0; si < nsplit; ++si) s += p[(long)si*M*N];
    out[(long)bi*sOut + (long)m*ldcOut + n] = s;
}

// ---------------- q ----------------
__global__ __launch_bounds__(256)
void k_q(const float* __restrict__ opt, const float* __restrict__ hx,
         const float* __restrict__ Wq, float* __restrict__ q)
{
    int idx = blockIdx.x*256 + threadIdx.x;
    if (idx >= NB*NU*NDK) return;
    int k = idx & 63; int t = idx >> 6;
    int u = t & 7; int b = t >> 3;
    const float* hxr = hx + (long)(b*NU+u)*NH;
    float acc = 0.f;
    for (int o = 0; o < NO; ++o) {
        const float* w = Wq + ((long)(o*NU+u)*NH)*NDK + k;
        float s = 0.f;
        for (int h = 0; h < NH; ++h) s += hxr[h] * w[(long)h*NDK];
        acc += opt[b*NO+o] * s;
    }
    q[idx] = acc;
}

// ---------------- scores + softmax(2) + attn_in + real ----------------
__global__ __launch_bounds__(64)
void k_attn(const float* __restrict__ q, const float* __restrict__ k0,
            const float* __restrict__ bk, const float* __restrict__ v0,
            const float* __restrict__ bv, float* __restrict__ attn,
            float* __restrict__ real)
{
    int bu = blockIdx.x;
    int lane = threadIdx.x;
    int b = bu >> 3;
    float qv = q[(long)bu*NDK + lane];
    float s0 = qv * k0[(long)b*NDK + lane];
    float s1 = qv * bk[lane];
    for (int off = 32; off; off >>= 1) {
        s0 += __shfl_xor(s0, off);
        s1 += __shfl_xor(s1, off);
    }
    s0 *= 0.125f; s1 *= 0.125f;
    float mx = fmaxf(s0, s1);
    float e0 = expf(s0-mx), e1 = expf(s1-mx);
    float inv = 1.f/(e0+e1);
    float p0 = e0*inv, p1 = e1*inv;
    if (lane == 0) real[bu] = p0;
    for (int v = lane; v < NV; v += 64)
        attn[(long)bu*NV + v] = p0*v0[(long)b*NV + v] + p1*bv[v];
}

// ---------------- top-k mask ----------------
__global__ void k_topk(const float* __restrict__ real, float* __restrict__ mask)
{
    int b = blockIdx.x*blockDim.x + threadIdx.x;
    if (b >= NB) return;
    float v[NU]; bool sel[NU];
#pragma unroll
    for (int i = 0; i < NU; ++i) { v[i] = real[b*NU+i]; sel[i] = false; }
    for (int t = 0; t < NKT; ++t) {
        int best = 0; float bvv = -1e30f;
#pragma unroll
        for (int i = 0; i < NU; ++i)
            if (!sel[i] && v[i] > bvv) { bvv = v[i]; best = i; }
        sel[best] = true;
    }
#pragma unroll
    for (int i = 0; i < NU; ++i) mask[b*NU+i] = sel[i] ? 1.f : 0.f;
}

// ---------------- LSTM gates (pre = pre_i + pre_h + blstm) ----------------
__global__ __launch_bounds__(256)
void k_gates(const float* __restrict__ pre_i, const float* __restrict__ pre_h,
             const float* __restrict__ blstm, const float* __restrict__ cx,
             float* __restrict__ cn, float* __restrict__ hn)
{
    int idx = blockIdx.x*256 + threadIdx.x;
    if (idx >= NB*NU*NH) return;
    int h = idx & 127; int bu = idx >> 7;
    int u = bu & 7;
    const float* pi = pre_i + (long)bu*512;
    const float* ph = pre_h + (long)bu*512;
    const float* bl = blstm + (long)u*512;
    float ig = pi[h]     + ph[h]     + bl[h];
    float fg = pi[128+h] + ph[128+h] + bl[128+h];
    float gg = pi[256+h] + ph[256+h] + bl[256+h];
    float og = pi[384+h] + ph[384+h] + bl[384+h];
    float si = 1.f/(1.f+expf(-ig));
    float sf = 1.f/(1.f+expf(-fg));
    float so = 1.f/(1.f+expf(-og));
    float c = sf*cx[idx] + si*tanhf(gg);
    cn[idx] = c;
    hn[idx] = so*tanhf(c);
}

// ---------------- qc,kc ----------------
__global__ __launch_bounds__(256)
void k_qckc(const float* __restrict__ hn, const float* __restrict__ Wqc,
            const float* __restrict__ Wkc, float* __restrict__ qc,
            float* __restrict__ kc)
{
    int idx = blockIdx.x*256 + threadIdx.x;
    if (idx >= NB*NU*64) return;
    int j = idx & 63; int t = idx >> 6;
    int u = t & 7; int b = t >> 3;
    int k = j & 31;
    const float* W = (j < 32 ? Wqc : Wkc) + ((long)u*NH)*NDKC + k;
    const float* h = hn + (long)(b*NU+u)*NH;
    float s = 0.f;
    for (int hh = 0; hh < NH; ++hh) s += h[hh]*W[(long)hh*NDKC];
    (j < 32 ? qc : kc)[(b*NU+u)*NDKC + k] = s;
}

// ---------------- comm probs ----------------
__global__ __launch_bounds__(64)
void k_cp(const float* __restrict__ qc, const float* __restrict__ kc,
          const float* __restrict__ mask, float* __restrict__ cp)
{
    int b = blockIdx.x;
    int lane = threadIdx.x;
    int u = lane >> 3, n = lane & 7;
    const float* qr = qc + (long)(b*NU+u)*NDKC;
    const float* kr = kc + (long)(b*NU+n)*NDKC;
    float d = 0.f;
    for (int k = 0; k < NDKC; ++k) d += qr[k]*kr[k];
    d *= 0.17677669529663687f;
    float mx = d;
    for (int off = 4; off; off >>= 1) mx = fmaxf(mx, __shfl_xor(mx, off, 8));
    float e = expf(d-mx);
    float sm = e;
    for (int off = 4; off; off >>= 1) sm += __shfl_xor(sm, off, 8);
    cp[b*64 + lane] = (e/sm) * mask[b*NU+u];
}

// ---------------- ctx (bf16 in/out) ----------------
__global__ __launch_bounds__(256)
void k_ctx(const unsigned short* __restrict__ vc, const float* __restrict__ cp,
           unsigned short* __restrict__ ctx)
{
    int b = blockIdx.y;
    int v = blockIdx.x*256 + threadIdx.x;
    __shared__ float cps[64];
    if (threadIdx.x < 64) cps[threadIdx.x] = cp[b*64 + threadIdx.x];
    __syncthreads();
    if (v >= NCV) return;
    float vv[NU];
#pragma unroll
    for (int n = 0; n < NU; ++n) vv[n] = bf2f(vc[((long)(b*NU+n))*NCV + v]);
#pragma unroll
    for (int u = 0; u < NU; ++u) {
        float s = 0.f;
#pragma unroll
        for (int n = 0; n < NU; ++n) s += cps[u*8+n]*vv[n];
        ctx[((long)(b*NU+u))*NCV + v] = f2bf(s);
    }
}

// ---------------- fused tail: blend + hy-sum + logits-softmax ----------------
__global__ __launch_bounds__(128)
void k_tail(const float* __restrict__ hn, const float* __restrict__ cn,
            const float* __restrict__ hcw, const float* __restrict__ hx,
            const float* __restrict__ cx, const float* __restrict__ mask,
            const float* __restrict__ piw, const float* __restrict__ pib,
            float* __restrict__ hy, float* __restrict__ cy,
            float* __restrict__ out)
{
    const int b = blockIdx.x;
    const int h = threadIdx.x;
    __shared__ float hs[128];
    __shared__ float lg[28];
    float s = 0.f;
#pragma unroll
    for (int u = 0; u < NU; ++u) {
        int idx = (b*NU+u)*NH + h;
        float m = mask[b*NU+u];
        float hyv = m*(hn[idx]+hcw[idx]) + (1.f-m)*hx[idx];
        float cyv = m*cn[idx] + (1.f-m)*cx[idx];
        hy[idx] = hyv; cy[idx] = cyv;
        s += hyv;
    }
    hs[h] = s;
    __syncthreads();
    if (h < 28) {
        int o = h / 7, a = h - o*7;
        float acc = pib[o*NA+a];
        for (int k = 0; k < NH; ++k) acc += hs[k] * piw[((long)o*NH+k)*NA + a];
        lg[h] = acc;
    }
    __syncthreads();
    if (h < NO) {
        float mx = lg[h*NA];
#pragma unroll
        for (int a = 1; a < NA; ++a) mx = fmaxf(mx, lg[h*NA+a]);
        float e[NA]; float sm = 0.f;
#pragma unroll
        for (int a = 0; a < NA; ++a) { e[a] = expf(lg[h*NA+a]-mx); sm += e[a]; }
        float inv = 1.f/sm;
#pragma unroll
        for (int a = 0; a < NA; ++a) out[(long)b*NO*NA + h*NA + a] = e[a]*inv;
    }
}

extern "C" void kernel_launch(void* const* d_in, const int* in_sizes, int n_in,
                              void* d_out, int out_size, void* d_ws, size_t ws_size,
                              hipStream_t stream) {
    const float* x    = (const float*)d_in[0];
    const float* hx   = (const float*)d_in[1];
    const float* cx   = (const float*)d_in[2];
    const float* opt  = (const float*)d_in[3];
    const float* c1w  = (const float*)d_in[4];
    const float* c1b  = (const float*)d_in[5];
    const float* c2w  = (const float*)d_in[6];
    const float* c2b  = (const float*)d_in[7];
    const float* c3w  = (const float*)d_in[8];
    const float* c3b  = (const float*)d_in[9];
    const float* Wk   = (const float*)d_in[10];
    const float* bk   = (const float*)d_in[11];
    const float* Wv   = (const float*)d_in[12];
    const float* bv   = (const float*)d_in[13];
    const float* Wq   = (const float*)d_in[14];
    const float* Wi   = (const float*)d_in[15];
    const float* Wh   = (const float*)d_in[16];
    const float* blstm= (const float*)d_in[17];
    const float* Wqc  = (const float*)d_in[18];
    const float* Wkc  = (const float*)d_in[19];
    const float* Wvc  = (const float*)d_in[20];
    const float* Wout = (const float*)d_in[21];
    const float* piw  = (const float*)d_in[22];
    const float* pib  = (const float*)d_in[23];

    float* out = (float*)d_out;
    float* hy  = out + (long)NB*NO*NA;
    float* cy  = hy + (long)NB*NU*NH;

    float* ws = (float*)d_ws;
    long o = 0;
    float* b_k0  = ws + o; o += 16384;
    float* b_v0  = ws + o; o += 102400;
    float* b_q   = ws + o; o += 131072;
    float* b_at  = ws + o; o += 819200;
    float* b_re  = ws + o; o += 2048;
    float* b_mk  = ws + o; o += 2048;
    float* b_pre = ws + o; o += 1048576;
    float* b_cn  = ws + o; o += 262144;
    float* b_hn  = ws + o; o += 262144;
    float* b_qc  = ws + o; o += 65536;
    float* b_kc  = ws + o; o += 65536;
    float* b_cp  = ws + o; o += 16384;
    float* b_hc  = ws + o; o += 262144;
    float* b_hs  = ws + o; o += 32768;
    // o == 3088384 — layout identical to the proven 459.9 µs round:
    //  P1OFF: p1 -> WvT -> WvcT+WoutT+partW | C2OFF: c2
    //  EMBOFF: emb32 -> v0 partials -> vc16+ctx16
    //  TOFF: k0 partials -> emb16 -> WiT+WhT+pre_h
    constexpr long P1OFF  = 3088384;
    constexpr long C2OFF  = 7024640;
    constexpr long EMBOFF = 14397440;
    constexpr long TOFF   = 28176384;
    constexpr long NEED   = TOFF + 5242880;   // 33,419,264 floats (proven)
    if (ws_size < (size_t)NEED * sizeof(float)) return;

    float* p1    = ws + P1OFF;
    float* c2    = ws + C2OFF;
    float* emb   = ws + EMBOFF;
    float* partK = ws + TOFF;
    float* partV = ws + EMBOFF;
    unsigned short* emb16 = (unsigned short*)(ws + TOFF);
    unsigned short* WvT   = (unsigned short*)(ws + P1OFF);
    unsigned short* WiT   = (unsigned short*)(ws + TOFF);
    unsigned short* WhT   = (unsigned short*)(ws + TOFF + 819200);
    float* pre_h          = ws + TOFF + 819200 + 262144;
    unsigned short* WvcT  = (unsigned short*)(ws + P1OFF);
    unsigned short* WoutT = (unsigned short*)(ws + P1OFF + 3444736);
    float* partW          = ws + P1OFF + 2*3444736;
    unsigned short* vc16  = (unsigned short*)(ws + EMBOFF);
    unsigned short* ctx16 = (unsigned short*)(ws + EMBOFF + 6889472);

    // S1) conv stack (conv3 via hi/lo MFMA — emb rel err ~4e-6, top-K safe)
    k_conv1<<<(NB*16*H1*W1 + 255)/256, 256, 0, stream>>>(x, c1w, c1b, p1);
    conv2x2_gemm<32,16,H1,W1,H2,W2><<<NB*((H2*W2+127)/128), 256, 0, stream>>>(p1, c2w, c2b, c2);
    conv3_mfma<<<dim3((H3*W3+127)/128, NB), 256, 0, stream>>>(c2, c3w, c3b, emb);

    // S2) Wv -> bf16 transposed [400][53824]  (p1/c2 dead)
    k_f2bt<<<dim3(13, 1682, 1), 256, 0, stream>>>(Wv, WvT, NE, NV, 0);

    // S3) k0 = emb@Wk + bk  (fp32 — precision-critical for top-k; S=320)
    k0_gemm<<<320, 256, 0, stream>>>(emb, Wk, partK, NE, 176);
    k_reduce_splitk<<<(NB*NDK + 255)/256, 256, 0, stream>>>(
        partK, b_k0, NDK, 0, bk, 0, 1, NB, NDK, 320);

    // S4) emb -> bf16 (RNE; k0 partials dead)
    k_cvt<<<((long)NB*NE/8 + 255)/256, 256, 0, stream>>>(emb, emb16, (long)NB*NE);

    // S5) v0 = emb16@Wv + bv  (bf16 MFMA, 128x128, S=87; partials at EMBOFF)
    bgemm_splitk<128,128,false><<<dim3(4,2,87), 256, 0, stream>>>(
        emb16, NE, 0, WvT, NE, 0, partV, NB, NV, NE, 87, 624);
    k_reduce_splitk<<<(NB*NV + 255)/256, 256, 0, stream>>>(
        partV, b_v0, NV, 0, bv, 0, 1, NB, NV, 87);

    // S6) q / attention / top-k
    k_q<<<(NB*NU*NDK + 255)/256, 256, 0, stream>>>(opt, hx, Wq, b_q);
    k_attn<<<NB*NU, 64, 0, stream>>>(b_q, b_k0, bk, b_v0, bv, b_at, b_re);
    k_topk<<<1, 256, 0, stream>>>(b_re, b_mk);

    // S7) LSTM pre in bf16 MFMA (fp32 accum/out) — proven round 10
    k_f2bt<<<dim3(16, 13, 8), 256, 0, stream>>>(Wi, WiT, NV, 512, (long)NV*512);
    k_f2bt<<<dim3(16, 4, 8), 256, 0, stream>>>(Wh, WhT, NH, 512, (long)NH*512);
    bgemm_f32<true><<<dim3(8, 4, NU), 256, 0, stream>>>(
        b_at, (long)NU*NV, NV, WiT, NV, (long)512*NV,
        b_pre, (long)NU*512, 512, NB, 512, NV);
    bgemm_f32<true><<<dim3(8, 4, NU), 256, 0, stream>>>(
        hx, (long)NU*NH, NH, WhT, NH, (long)512*NH,
        pre_h, (long)NU*512, 512, NB, 512, NH);
    k_gates<<<(NB*NU*NH + 255)/256, 256, 0, stream>>>(b_pre, pre_h, blstm, cx, b_cn, b_hn);

    // S8) convert Wvc/Wout (WvT dead after v0)
    k_f2bt<<<dim3(211, 4, 8), 256, 0, stream>>>(Wvc, WvcT, NH, NCV, (long)NH*NCV);
    k_f2bt<<<dim3(4, 211, 8), 256, 0, stream>>>(Wout, WoutT, NCV, NH, (long)NCV*NH);

    // S9) vc = h_new@Wvc (bf16 MFMA direct, bf16 out)  (v0 partials dead)
    bgemm_direct<true><<<dim3((NCV+127)/128, 2, NU), 256, 0, stream>>>(
        b_hn, (long)NU*NH, NH, WvcT, NH, (long)NCV*NH,
        vc16, (long)NU*NCV, NCV, NB, NCV, NH);

    // S10) comm probs + ctx
    k_qckc<<<(NB*NU*64 + 255)/256, 256, 0, stream>>>(b_hn, Wqc, Wkc, b_qc, b_kc);
    k_cp<<<NB, 64, 0, stream>>>(b_qc, b_kc, b_mk, b_cp);
    k_ctx<<<dim3((NCV+255)/256, NB), 256, 0, stream>>>(vc16, b_cp, ctx16);

    // S11) hcomm_w = ctx@Wout (bf16 MFMA split-K 16)
    bgemm_splitk<64,64,false><<<dim3(2,4,NU*16), 256, 0, stream>>>(
        ctx16, (long)NU*NCV, NCV, WoutT, NCV, (long)NCV*NH,
        partW, NB, NH, NCV, 16, 448);
    k_reduce_splitk<<<(NU*NB*NH + 255)/256, 256, 0, stream>>>(
        partW, b_hc, (long)NU*NH, NH, nullptr, 0, NU, NB, NH, 16);

    // S12) fused blend + hy-sum + logits
    k_tail<<<NB, 128, 0, stream>>>(b_hn, b_cn, b_hc, hx, cx, b_mk, piw, pib, hy, cy, out);
}

// Round 16
// 440.913 us; speedup vs baseline: 1.1020x; 1.0054x over previous
//
#include <hip/hip_runtime.h>
#include <math.h>

namespace {
constexpr int NB  = 256;
constexpr int NU  = 8;
constexpr int NKT = 4;
constexpr int NH  = 128;
constexpr int NO  = 4;
constexpr int NA  = 7;
constexpr int NV  = 400;
constexpr int NE  = 53824;
constexpr int NCV = 6728;
constexpr int NDK = 64;
constexpr int NDKC= 32;

constexpr int H1 = 31, W1 = 31;
constexpr int H2 = 30, W2 = 30;
constexpr int H3 = 29, W3 = 29;
}

typedef __attribute__((ext_vector_type(8))) short bf16x8_t;
typedef __attribute__((ext_vector_type(4))) float f32x4_t;

__device__ __forceinline__ unsigned short f2bf(float f) {
    unsigned int u = __float_as_uint(f);
    u += 0x7FFFu + ((u >> 16) & 1u);   // RNE
    return (unsigned short)(u >> 16);
}
__device__ __forceinline__ float bf2f(unsigned short h) {
    return __uint_as_float((unsigned int)h << 16);
}

// ---------------- conv1 (2x2, 3->16) + relu + maxpool2 ----------------
__global__ __launch_bounds__(256)
void k_conv1(const float* __restrict__ x, const float* __restrict__ w,
             const float* __restrict__ bias, float* __restrict__ out)
{
    __shared__ float ws[16*3*2*2];
    __shared__ float bs[16];
    int tid = threadIdx.x;
    if (tid < 192) ws[tid] = w[tid];
    if (tid < 16)  bs[tid] = bias[tid];
    __syncthreads();
    long idx = (long)blockIdx.x*256 + tid;
    if (idx >= (long)NB*16*H1*W1) return;
    int pw = idx % W1; long t = idx / W1;
    int ph = t % H1; t /= H1;
    int oc = t % 16; int b = t / 16;
    float mx = 0.f;
#pragma unroll
    for (int dh = 0; dh < 2; ++dh)
#pragma unroll
    for (int dw = 0; dw < 2; ++dw) {
        int h = 2*ph + dh, ww = 2*pw + dw;
        float s = bs[oc];
#pragma unroll
        for (int kh = 0; kh < 2; ++kh)
#pragma unroll
        for (int kw = 0; kw < 2; ++kw) {
            const float* xp = x + (((long)b*64 + (h+kh))*64 + (ww+kw))*3;
#pragma unroll
            for (int ic = 0; ic < 3; ++ic)
                s += xp[ic] * ws[((oc*3+ic)*2+kh)*2+kw];
        }
        mx = fmaxf(mx, s);
    }
    out[idx] = mx;
}

// ---------------- conv2 (2x2, 16->32) as implicit GEMM, 4x4 micro, dbuf ----------------
template<int OC, int IC, int HIN, int WIN, int HOUT, int WOUT>
__global__ __launch_bounds__(256)
void conv2x2_gemm(const float* __restrict__ in, const float* __restrict__ w,
                  const float* __restrict__ bias, float* __restrict__ out)
{
    constexpr int K    = IC*4;
    constexpr int TY   = OC/4;
    constexpr int TX   = 256/TY;
    constexpr int NT   = TX*4;
    constexpr int SPAT = HOUT*WOUT;
    constexpr int NBLK = (SPAT + NT - 1)/NT;
    constexpr int AIT  = OC*16/256;
    constexpr int BIT  = 16*NT/256;

    const int b  = blockIdx.x / NBLK;
    const int n0 = (blockIdx.x % NBLK) * NT;

    __shared__ __align__(16) float As[2][16][OC+4];
    __shared__ __align__(16) float Bs[2][16][NT];

    const int tid = threadIdx.x;
    const int tx = tid % TX, ty = tid / TX;
    float acc[4][4] = {};
    const float* inb = in + (long)b*IC*HIN*WIN;

    const int nIdx = tid & (NT-1);
    int ohw = 0; bool nOk = false;
    {
        int s = n0 + nIdx;
        if (s < SPAT) { ohw = (s / WOUT) * WIN + (s % WOUT); nOk = true; }
    }

    float aR[AIT], bR[BIT];
    auto loadAB = [&](int kk) {
#pragma unroll
        for (int i = 0; i < AIT; ++i) {
            int lin = tid + i*256;
            aR[i] = w[(lin/16)*K + kk + (lin%16)];
        }
#pragma unroll
        for (int i = 0; i < BIT; ++i) {
            int k = (tid + i*256) / NT;
            int gk = kk + k;
            int ic = gk >> 2, tap = gk & 3;
            bR[i] = nOk ? inb[ic*HIN*WIN + ohw + (tap>>1)*WIN + (tap&1)] : 0.f;
        }
    };
    auto storeAB = [&](int buf) {
#pragma unroll
        for (int i = 0; i < AIT; ++i) {
            int lin = tid + i*256;
            As[buf][lin%16][lin/16] = aR[i];
        }
#pragma unroll
        for (int i = 0; i < BIT; ++i) {
            int k = (tid + i*256) / NT;
            Bs[buf][k][nIdx] = bR[i];
        }
    };

    loadAB(0);
    storeAB(0);
    __syncthreads();
    int cur = 0;
    for (int kk = 0; kk < K; kk += 16) {
        const bool more = (kk + 16 < K);
        if (more) loadAB(kk + 16);
#pragma unroll
        for (int k = 0; k < 16; ++k) {
            float4 a4 = *reinterpret_cast<const float4*>(&As[cur][k][ty*4]);
            float4 b4 = *reinterpret_cast<const float4*>(&Bs[cur][k][tx*4]);
            float av[4] = {a4.x,a4.y,a4.z,a4.w};
            float bw[4] = {b4.x,b4.y,b4.z,b4.w};
#pragma unroll
            for (int i = 0; i < 4; ++i)
#pragma unroll
            for (int j = 0; j < 4; ++j) acc[i][j] += av[i]*bw[j];
        }
        if (more) {
            storeAB(cur ^ 1);
            __syncthreads();
            cur ^= 1;
        }
    }
#pragma unroll
    for (int i = 0; i < 4; ++i) {
        int gm = ty*4 + i;
        float bi = bias[gm];
#pragma unroll
        for (int j = 0; j < 4; ++j) {
            int s = n0 + tx*4 + j;
            if (s < SPAT)
                out[((long)b*OC + gm)*SPAT + s] = fmaxf(acc[i][j] + bi, 0.f);
        }
    }
}

// ---------------- conv3 via hi/lo-split bf16 MFMA (fp32-accurate, rel err ~2^-18) ----------------
__global__ __launch_bounds__(256)
void conv3_mfma(const float* __restrict__ c2, const float* __restrict__ w,
                const float* __restrict__ bias, float* __restrict__ emb)
{
    constexpr int SPAT = 29*29;   // 841
    constexpr int WIN  = 30;
    const int b  = blockIdx.y;
    const int n0 = blockIdx.x * 128;

    __shared__ __align__(16) unsigned short Ah[4*64*32], Al[4*64*32];
    __shared__ __align__(16) unsigned short Bh[128*32],  Bl[128*32];

    const int tid = threadIdx.x;
    const int wave = tid >> 6, lane = tid & 63;
    const int wr = wave >> 1, wc = wave & 1;
    const int lr = lane & 15, lk = lane >> 4;
    const int rbase = wr*32, cbase = wc*64;

    const float* c2b = c2 + (long)b*32*900;

    {
        int row = tid >> 2, kb = tid & 3;
        int p = (kb ^ (row & 3)) << 3;
#pragma unroll
        for (int c = 0; c < 4; ++c) {
            unsigned short hh[8], ll[8];
#pragma unroll
            for (int j = 0; j < 8; ++j) {
                float v = w[(long)row*128 + c*32 + kb*8 + j];
                unsigned short h = f2bf(v);
                hh[j] = h; ll[j] = f2bf(v - bf2f(h));
            }
            *(ushort4*)&Ah[c*2048 + row*32 + p]     = make_ushort4(hh[0],hh[1],hh[2],hh[3]);
            *(ushort4*)&Ah[c*2048 + row*32 + p + 4] = make_ushort4(hh[4],hh[5],hh[6],hh[7]);
            *(ushort4*)&Al[c*2048 + row*32 + p]     = make_ushort4(ll[0],ll[1],ll[2],ll[3]);
            *(ushort4*)&Al[c*2048 + row*32 + p + 4] = make_ushort4(ll[4],ll[5],ll[6],ll[7]);
        }
    }

    const int br0 = tid >> 2, br1 = br0 + 64;
    const int kb  = tid & 3;
    int base0 = 0, base1 = 0; bool ok0, ok1;
    { int s = n0 + br0; ok0 = s < SPAT; if (ok0) base0 = (s/29)*WIN + (s%29); }
    { int s = n0 + br1; ok1 = s < SPAT; if (ok1) base1 = (s/29)*WIN + (s%29); }

    f32x4_t acc[2][4];
#pragma unroll
    for (int i = 0; i < 2; ++i)
#pragma unroll
    for (int j = 0; j < 4; ++j) acc[i][j] = (f32x4_t){0.f,0.f,0.f,0.f};

    for (int c = 0; c < 4; ++c) {
        __syncthreads();
#pragma unroll
        for (int rr = 0; rr < 2; ++rr) {
            int row   = rr ? br1 : br0;
            bool ok   = rr ? ok1 : ok0;
            int base  = rr ? base1 : base0;
            int p = (kb ^ (row & 3)) << 3;
            unsigned short hh[8], ll[8];
#pragma unroll
            for (int j = 0; j < 8; ++j) {
                int gk = c*32 + kb*8 + j;
                int ic = gk >> 2, tap = gk & 3;
                float v = ok ? c2b[ic*900 + base + (tap>>1)*WIN + (tap&1)] : 0.f;
                unsigned short h = f2bf(v);
                hh[j] = h; ll[j] = f2bf(v - bf2f(h));
            }
            *(ushort4*)&Bh[row*32 + p]     = make_ushort4(hh[0],hh[1],hh[2],hh[3]);
            *(ushort4*)&Bh[row*32 + p + 4] = make_ushort4(hh[4],hh[5],hh[6],hh[7]);
            *(ushort4*)&Bl[row*32 + p]     = make_ushort4(ll[0],ll[1],ll[2],ll[3]);
            *(ushort4*)&Bl[row*32 + p + 4] = make_ushort4(ll[4],ll[5],ll[6],ll[7]);
        }
        __syncthreads();
        bf16x8_t ah[2], al[2], bh[4], bl[4];
#pragma unroll
        for (int i = 0; i < 2; ++i) {
            int row = rbase + i*16 + lr;
            int off = c*2048 + row*32 + ((lk ^ (row & 3)) << 3);
            ah[i] = *(const bf16x8_t*)&Ah[off];
            al[i] = *(const bf16x8_t*)&Al[off];
        }
#pragma unroll
        for (int j = 0; j < 4; ++j) {
            int col = cbase + j*16 + lr;
            int off = col*32 + ((lk ^ (col & 3)) << 3);
            bh[j] = *(const bf16x8_t*)&Bh[off];
            bl[j] = *(const bf16x8_t*)&Bl[off];
        }
#pragma unroll
        for (int i = 0; i < 2; ++i)
#pragma unroll
        for (int j = 0; j < 4; ++j) {
            acc[i][j] = __builtin_amdgcn_mfma_f32_16x16x32_bf16(ah[i], bh[j], acc[i][j], 0,0,0);
            acc[i][j] = __builtin_amdgcn_mfma_f32_16x16x32_bf16(ah[i], bl[j], acc[i][j], 0,0,0);
            acc[i][j] = __builtin_amdgcn_mfma_f32_16x16x32_bf16(al[i], bh[j], acc[i][j], 0,0,0);
        }
    }

#pragma unroll
    for (int i = 0; i < 2; ++i)
#pragma unroll
    for (int r = 0; r < 4; ++r) {
        int gm = rbase + i*16 + lk*4 + r;
        float bi = bias[gm];
#pragma unroll
        for (int j = 0; j < 4; ++j) {
            int gn = n0 + cbase + j*16 + lr;
            if (gn < SPAT)
                emb[((long)b*64 + gm)*SPAT + gn] = fmaxf(acc[i][j][r] + bi, 0.f);
        }
    }
}

// ---------------- fp32 -> bf16 elementwise convert (n multiple of 8) ----------------
__global__ __launch_bounds__(256)
void k_cvt(const float* __restrict__ in, unsigned short* __restrict__ out, long n)
{
    long i = ((long)blockIdx.x*256 + threadIdx.x) * 8;
    if (i >= n) return;
    float4 a = *(const float4*)(in + i);
    float4 b = *(const float4*)(in + i + 4);
    uint4 u;
    u.x = (unsigned)f2bf(a.x) | ((unsigned)f2bf(a.y) << 16);
    u.y = (unsigned)f2bf(a.z) | ((unsigned)f2bf(a.w) << 16);
    u.z = (unsigned)f2bf(b.x) | ((unsigned)f2bf(b.y) << 16);
    u.w = (unsigned)f2bf(b.z) | ((unsigned)f2bf(b.w) << 16);
    *(uint4*)(out + i) = u;
}

// ---------------- fp32 -> bf16 transposed convert: in [B][R][Cc] -> out [B][Cc][R] ----------------
__global__ __launch_bounds__(256)
void k_f2bt(const float* __restrict__ in, unsigned short* __restrict__ out,
            int R, int Cc, long sIn)
{
    __shared__ unsigned short t[32][33];
    const int b = blockIdx.z;
    const int r0 = blockIdx.y * 32, c0 = blockIdx.x * 32;
    const float* ip = in + (long)b * sIn;
    unsigned short* op = out + (long)b * sIn;
    const int tid = threadIdx.x;
    {
        int rr = tid >> 3, c4 = (tid & 7) * 4;
        int gr = r0 + rr;
        unsigned short h0=0,h1=0,h2=0,h3=0;
        if (gr < R) {
            if (c0 + c4 + 3 < Cc) {
                float4 f = *(const float4*)(ip + (long)gr*Cc + c0 + c4);
                h0=f2bf(f.x); h1=f2bf(f.y); h2=f2bf(f.z); h3=f2bf(f.w);
            } else {
                if (c0+c4+0 < Cc) h0 = f2bf(ip[(long)gr*Cc + c0+c4+0]);
                if (c0+c4+1 < Cc) h1 = f2bf(ip[(long)gr*Cc + c0+c4+1]);
                if (c0+c4+2 < Cc) h2 = f2bf(ip[(long)gr*Cc + c0+c4+2]);
                if (c0+c4+3 < Cc) h3 = f2bf(ip[(long)gr*Cc + c0+c4+3]);
            }
        }
        t[rr][c4+0]=h0; t[rr][c4+1]=h1; t[rr][c4+2]=h2; t[rr][c4+3]=h3;
    }
    __syncthreads();
    {
        int cc = tid >> 3, r4 = (tid & 7) * 4;
        int gc = c0 + cc;
        if (gc < Cc && r0 + r4 < R) {
            if (r0 + r4 + 3 < R) {
                *(ushort4*)(op + (long)gc*R + r0 + r4) =
                    make_ushort4(t[r4+0][cc], t[r4+1][cc], t[r4+2][cc], t[r4+3][cc]);
            } else {
#pragma unroll
                for (int j = 0; j < 4; ++j)
                    if (r0 + r4 + j < R) op[(long)gc*R + r0 + r4 + j] = t[r4+j][cc];
            }
        }
    }
}

// ---------------- bf16 MFMA GEMM staging, 16B-wide ----------------
template<int ROWS, bool F32>
__device__ __forceinline__ void stage_tile(const void* __restrict__ Av, long lda,
                                           int m0, int kk, int kEnd, int Mlim,
                                           unsigned short* lds, int tid)
{
#pragma unroll
    for (int i = 0; i < ROWS/64; ++i) {
        int row = (tid >> 2) + i*64;
        int blk = tid & 3;
        long gm = m0 + row;
        long gk = kk + blk*8;
        ushort4 lo = make_ushort4(0,0,0,0), hi = make_ushort4(0,0,0,0);
        if (gm < Mlim && gk < kEnd) {
            if (F32) {
                const float* A = (const float*)Av + gm*lda + gk;
                float4 f0 = *(const float4*)(A);
                float4 f1 = *(const float4*)(A + 4);
                lo = make_ushort4(f2bf(f0.x),f2bf(f0.y),f2bf(f0.z),f2bf(f0.w));
                hi = make_ushort4(f2bf(f1.x),f2bf(f1.y),f2bf(f1.z),f2bf(f1.w));
            } else {
                const unsigned short* A = (const unsigned short*)Av + gm*lda + gk;
                lo = *(const ushort4*)(A);
                hi = *(const ushort4*)(A + 4);
            }
        }
        int p = (blk ^ (row & 3)) << 3;
        *(ushort4*)&lds[row*32 + p]     = lo;
        *(ushort4*)&lds[row*32 + p + 4] = hi;
    }
}

template<int BM, int BN, bool AF32>
__global__ __launch_bounds__(256)
void bgemm_splitk(const void* __restrict__ Av, long lda, long sA,
                  const unsigned short* __restrict__ BT, long ldbt, long sB,
                  float* __restrict__ Cpart,
                  int M, int N, int K, int nsplit, int kChunk)
{
    constexpr int MR = BM/32, NR = BN/32;
    const int z = blockIdx.z;
    const int batch = z / nsplit, split = z - batch*nsplit;
    const int kStart = split * kChunk;
    const int kEnd = (kStart + kChunk < K) ? (kStart + kChunk) : K;
    const int m0 = blockIdx.y * BM;
    const int n0 = blockIdx.x * BN;

    __shared__ __align__(16) unsigned short As[BM*32];
    __shared__ __align__(16) unsigned short Bs[BN*32];

    const int tid = threadIdx.x;
    const int wave = tid >> 6, lane = tid & 63;
    const int wr = wave >> 1, wc = wave & 1;
    const int lr = lane & 15, lk = lane >> 4;
    const int rbase = wr*(BM/2), cbase = wc*(BN/2);

    const void* Ab = AF32 ? (const void*)((const float*)Av + (long)batch*sA)
                          : (const void*)((const unsigned short*)Av + (long)batch*sA);
    const unsigned short* Bb = BT + (long)batch*sB;

    f32x4_t acc[MR][NR];
#pragma unroll
    for (int i = 0; i < MR; ++i)
#pragma unroll
    for (int j = 0; j < NR; ++j)
        acc[i][j] = (f32x4_t){0.f,0.f,0.f,0.f};

    for (int kk = kStart; kk < kEnd; kk += 32) {
        stage_tile<BM,AF32>(Ab, lda, m0, kk, kEnd, M, As, tid);
        stage_tile<BN,false>((const void*)Bb, ldbt, n0, kk, kEnd, N, Bs, tid);
        __syncthreads();
        bf16x8_t af[MR], bfv[NR];
#pragma unroll
        for (int i = 0; i < MR; ++i) {
            int row = rbase + i*16 + lr;
            af[i] = *(const bf16x8_t*)&As[row*32 + ((lk ^ (row & 3)) << 3)];
        }
#pragma unroll
        for (int j = 0; j < NR; ++j) {
            int col = cbase + j*16 + lr;
            bfv[j] = *(const bf16x8_t*)&Bs[col*32 + ((lk ^ (col & 3)) << 3)];
        }
#pragma unroll
        for (int i = 0; i < MR; ++i)
#pragma unroll
        for (int j = 0; j < NR; ++j)
            acc[i][j] = __builtin_amdgcn_mfma_f32_16x16x32_bf16(af[i], bfv[j], acc[i][j], 0, 0, 0);
        __syncthreads();
    }

    const long cb2 = (long)z * M * N;
#pragma unroll
    for (int i = 0; i < MR; ++i) {
#pragma unroll
        for (int r = 0; r < 4; ++r) {
            int gm = m0 + rbase + i*16 + lk*4 + r;
            if (gm >= M) continue;
#pragma unroll
            for (int j = 0; j < NR; ++j) {
                int gn = n0 + cbase + j*16 + lr;
                if (gn < N) Cpart[cb2 + (long)gm*N + gn] = acc[i][j][r];
            }
        }
    }
}

// direct bf16 GEMM (full K), bf16 output, 128x128 tile
template<bool AF32>
__global__ __launch_bounds__(256)
void bgemm_direct(const void* __restrict__ Av, long lda, long sA,
                  const unsigned short* __restrict__ BT, long ldbt, long sB,
                  unsigned short* __restrict__ Cout, long ldc, long sC,
                  int M, int N, int K)
{
    const int batch = blockIdx.z;
    const int m0 = blockIdx.y * 128;
    const int n0 = blockIdx.x * 128;

    __shared__ __align__(16) unsigned short As[128*32];
    __shared__ __align__(16) unsigned short Bs[128*32];

    const int tid = threadIdx.x;
    const int wave = tid >> 6, lane = tid & 63;
    const int wr = wave >> 1, wc = wave & 1;
    const int lr = lane & 15, lk = lane >> 4;

    const void* Ab = AF32 ? (const void*)((const float*)Av + (long)batch*sA)
                          : (const void*)((const unsigned short*)Av + (long)batch*sA);
    const unsigned short* Bb = BT + (long)batch*sB;

    f32x4_t acc[4][4];
#pragma unroll
    for (int i = 0; i < 4; ++i)
#pragma unroll
    for (int j = 0; j < 4; ++j)
        acc[i][j] = (f32x4_t){0.f,0.f,0.f,0.f};

    for (int kk = 0; kk < K; kk += 32) {
        stage_tile<128,AF32>(Ab, lda, m0, kk, K, M, As, tid);
        stage_tile<128,false>((const void*)Bb, ldbt, n0, kk, K, N, Bs, tid);
        __syncthreads();
        bf16x8_t af[4], bfv[4];
#pragma unroll
        for (int i = 0; i < 4; ++i) {
            int row = wr*64 + i*16 + lr;
            af[i]  = *(const bf16x8_t*)&As[row*32 + ((lk ^ (row & 3)) << 3)];
            int col = wc*64 + i*16 + lr;
            bfv[i] = *(const bf16x8_t*)&Bs[col*32 + ((lk ^ (col & 3)) << 3)];
        }
#pragma unroll
        for (int i = 0; i < 4; ++i)
#pragma unroll
        for (int j = 0; j < 4; ++j)
            acc[i][j] = __builtin_amdgcn_mfma_f32_16x16x32_bf16(af[i], bfv[j], acc[i][j], 0, 0, 0);
        __syncthreads();
    }

    unsigned short* C = Cout + (long)batch * sC;
#pragma unroll
    for (int i = 0; i < 4; ++i) {
#pragma unroll
        for (int r = 0; r < 4; ++r) {
            int gm = m0 + wr*64 + i*16 + lk*4 + r;
            if (gm >= M) continue;
#pragma unroll
            for (int j = 0; j < 4; ++j) {
                int gn = n0 + wc*64 + j*16 + lr;
                if (gn < N) C[(long)gm*ldc + gn] = f2bf(acc[i][j][r]);
            }
        }
    }
}

// direct bf16-input GEMM, fp32 output, 64x64 tile, batched over grid.z (pre path)
template<bool AF32>
__global__ __launch_bounds__(256)
void bgemm_f32(const void* __restrict__ Av, long lda, long sA,
               const unsigned short* __restrict__ BT, long ldbt, long sB,
               float* __restrict__ Cout, long ldc, long sC,
               int M, int N, int K)
{
    const int batch = blockIdx.z;
    const int m0 = blockIdx.y * 64;
    const int n0 = blockIdx.x * 64;

    __shared__ __align__(16) unsigned short As[64*32];
    __shared__ __align__(16) unsigned short Bs[64*32];

    const int tid = threadIdx.x;
    const int wave = tid >> 6, lane = tid & 63;
    const int wr = wave >> 1, wc = wave & 1;
    const int lr = lane & 15, lk = lane >> 4;
    const int rbase = wr*32, cbase = wc*32;

    const void* Ab = AF32 ? (const void*)((const float*)Av + (long)batch*sA)
                          : (const void*)((const unsigned short*)Av + (long)batch*sA);
    const unsigned short* Bb = BT + (long)batch*sB;

    f32x4_t acc[2][2];
#pragma unroll
    for (int i = 0; i < 2; ++i)
#pragma unroll
    for (int j = 0; j < 2; ++j)
        acc[i][j] = (f32x4_t){0.f,0.f,0.f,0.f};

    for (int kk = 0; kk < K; kk += 32) {
        stage_tile<64,AF32>(Ab, lda, m0, kk, K, M, As, tid);
        stage_tile<64,false>((const void*)Bb, ldbt, n0, kk, K, N, Bs, tid);
        __syncthreads();
        bf16x8_t af[2], bfv[2];
#pragma unroll
        for (int i = 0; i < 2; ++i) {
            int row = rbase + i*16 + lr;
            af[i] = *(const bf16x8_t*)&As[row*32 + ((lk ^ (row & 3)) << 3)];
            int col = cbase + i*16 + lr;
            bfv[i] = *(const bf16x8_t*)&Bs[col*32 + ((lk ^ (col & 3)) << 3)];
        }
#pragma unroll
        for (int i = 0; i < 2; ++i)
#pragma unroll
        for (int j = 0; j < 2; ++j)
            acc[i][j] = __builtin_amdgcn_mfma_f32_16x16x32_bf16(af[i], bfv[j], acc[i][j], 0, 0, 0);
        __syncthreads();
    }

    float* C = Cout + (long)batch * sC;
#pragma unroll
    for (int i = 0; i < 2; ++i) {
#pragma unroll
        for (int r = 0; r < 4; ++r) {
            int gm = m0 + rbase + i*16 + lk*4 + r;
            if (gm >= M) continue;
#pragma unroll
            for (int j = 0; j < 2; ++j) {
                int gn = n0 + cbase + j*16 + lr;
                if (gn < N) C[(long)gm*ldc + gn] = acc[i][j][r];
            }
        }
    }
}

// ---------------- k0: fp32 split-K GEMM, BM=256 (all M), BN=64 (all N) ----------------
__global__ __launch_bounds__(256)
void k0_gemm(const float* __restrict__ A, const float* __restrict__ B,
             float* __restrict__ Cpart, int K, int kChunk)
{
    const int z = blockIdx.x;
    const int kStart = z * kChunk;
    const int kEnd = (kStart + kChunk < K) ? (kStart + kChunk) : K;
    __shared__ __align__(16) float As[16][260];
    __shared__ __align__(16) float Bs[16][64];
    const int tid = threadIdx.x;
    const int tx = tid & 15, ty = tid >> 4;
    float acc[16][4] = {};
    for (int kk = kStart; kk < kEnd; kk += 16) {
#pragma unroll
        for (int i = 0; i < 4; ++i) {
            int row = (tid >> 2) + i*64;
            int k4 = (tid & 3) * 4;
            long gk = kk + k4;
            float4 f = {0,0,0,0};
            if (gk + 3 < (long)kEnd) f = *(const float4*)(A + (long)row*K + gk);
            else {
                if (gk+0 < kEnd) f.x = A[(long)row*K+gk+0];
                if (gk+1 < kEnd) f.y = A[(long)row*K+gk+1];
                if (gk+2 < kEnd) f.z = A[(long)row*K+gk+2];
                if (gk+3 < kEnd) f.w = A[(long)row*K+gk+3];
            }
            As[k4+0][row]=f.x; As[k4+1][row]=f.y; As[k4+2][row]=f.z; As[k4+3][row]=f.w;
        }
        {
            int k = tid >> 4, n = (tid & 15) * 4;
            long gk = kk + k;
            float4 f = {0,0,0,0};
            if (gk < kEnd) f = *(const float4*)(B + gk*64 + n);
            *(float4*)&Bs[k][n] = f;
        }
        __syncthreads();
#pragma unroll
        for (int k = 0; k < 16; ++k) {
            float4 b4 = *reinterpret_cast<const float4*>(&Bs[k][tx*4]);
            float bw[4] = {b4.x,b4.y,b4.z,b4.w};
#pragma unroll
            for (int i4 = 0; i4 < 4; ++i4) {
                float4 a4 = *reinterpret_cast<const float4*>(&As[k][ty*16 + i4*4]);
                float av[4] = {a4.x,a4.y,a4.z,a4.w};
#pragma unroll
                for (int r = 0; r < 4; ++r)
#pragma unroll
                for (int j = 0; j < 4; ++j) acc[i4*4+r][j] += av[r]*bw[j];
            }
        }
        __syncthreads();
    }
    float* cp = Cpart + (long)z*256*64;
#pragma unroll
    for (int i = 0; i < 16; ++i) {
        int gm = ty*16 + i;
#pragma unroll
        for (int j = 0; j < 4; ++j)
            cp[(long)gm*64 + tx*4 + j] = acc[i][j];
    }
}

__global__ __launch_bounds__(256)
void k_reduce_splitk(const float* __restrict__ Cpart, float* __restrict__ out,
                     long ldcOut, long sOut,
                     const float* __restrict__ bias, long sBias,
                     int nbatch, int M, int N, int nsplit)
{
    long idx = (long)blockIdx.x*256 + threadIdx.x;
    long total = (long)nbatch*M*N;
    if (idx >= total) return;
    int n = idx % N; long t = idx / N;
    int m = t % M; int bi = t / M;
    const float* p = Cpart + ((long)bi*nsplit)*((long)M*N) + (long)m*N + n;
    float s = bias ? bias[(long)bi*sBias + n] : 0.f;
#pragma unroll 8
    for (int si = 0; si < nsplit; ++si) s += p[(long)si*M*N];
    out[(long)bi*sOut + (long)m*ldcOut + n] = s;
}

// ---------------- q ----------------
__global__ __launch_bounds__(256)
void k_q(const float* __restrict__ opt, const float* __restrict__ hx,
         const float* __restrict__ Wq, float* __restrict__ q)
{
    int idx = blockIdx.x*256 + threadIdx.x;
    if (idx >= NB*NU*NDK) return;
    int k = idx & 63; int t = idx >> 6;
    int u = t & 7; int b = t >> 3;
    const float* hxr = hx + (long)(b*NU+u)*NH;
    float acc = 0.f;
    for (int o = 0; o < NO; ++o) {
        const float* w = Wq + ((long)(o*NU+u)*NH)*NDK + k;
        float s = 0.f;
        for (int h = 0; h < NH; ++h) s += hxr[h] * w[(long)h*NDK];
        acc += opt[b*NO+o] * s;
    }
    q[idx] = acc;
}

// ---------------- scores + softmax(2) + attn_in + real ----------------
__global__ __launch_bounds__(64)
void k_attn(const float* __restrict__ q, const float* __restrict__ k0,
            const float* __restrict__ bk, const float* __restrict__ v0,
            const float* __restrict__ bv, float* __restrict__ attn,
            float* __restrict__ real)
{
    int bu = blockIdx.x;
    int lane = threadIdx.x;
    int b = bu >> 3;
    float qv = q[(long)bu*NDK + lane];
    float s0 = qv * k0[(long)b*NDK + lane];
    float s1 = qv * bk[lane];
    for (int off = 32; off; off >>= 1) {
        s0 += __shfl_xor(s0, off);
        s1 += __shfl_xor(s1, off);
    }
    s0 *= 0.125f; s1 *= 0.125f;
    float mx = fmaxf(s0, s1);
    float e0 = expf(s0-mx), e1 = expf(s1-mx);
    float inv = 1.f/(e0+e1);
    float p0 = e0*inv, p1 = e1*inv;
    if (lane == 0) real[bu] = p0;
    for (int v = lane; v < NV; v += 64)
        attn[(long)bu*NV + v] = p0*v0[(long)b*NV + v] + p1*bv[v];
}

// ---------------- top-k mask ----------------
__global__ void k_topk(const float* __restrict__ real, float* __restrict__ mask)
{
    int b = blockIdx.x*blockDim.x + threadIdx.x;
    if (b >= NB) return;
    float v[NU]; bool sel[NU];
#pragma unroll
    for (int i = 0; i < NU; ++i) { v[i] = real[b*NU+i]; sel[i] = false; }
    for (int t = 0; t < NKT; ++t) {
        int best = 0; float bvv = -1e30f;
#pragma unroll
        for (int i = 0; i < NU; ++i)
            if (!sel[i] && v[i] > bvv) { bvv = v[i]; best = i; }
        sel[best] = true;
    }
#pragma unroll
    for (int i = 0; i < NU; ++i) mask[b*NU+i] = sel[i] ? 1.f : 0.f;
}

// ---------------- LSTM gates (pre = pre_i + pre_h + blstm) ----------------
__global__ __launch_bounds__(256)
void k_gates(const float* __restrict__ pre_i, const float* __restrict__ pre_h,
             const float* __restrict__ blstm, const float* __restrict__ cx,
             float* __restrict__ cn, float* __restrict__ hn)
{
    int idx = blockIdx.x*256 + threadIdx.x;
    if (idx >= NB*NU*NH) return;
    int h = idx & 127; int bu = idx >> 7;
    int u = bu & 7;
    const float* pi = pre_i + (long)bu*512;
    const float* ph = pre_h + (long)bu*512;
    const float* bl = blstm + (long)u*512;
    float ig = pi[h]     + ph[h]     + bl[h];
    float fg = pi[128+h] + ph[128+h] + bl[128+h];
    float gg = pi[256+h] + ph[256+h] + bl[256+h];
    float og = pi[384+h] + ph[384+h] + bl[384+h];
    float si = 1.f/(1.f+expf(-ig));
    float sf = 1.f/(1.f+expf(-fg));
    float so = 1.f/(1.f+expf(-og));
    float c = sf*cx[idx] + si*tanhf(gg);
    cn[idx] = c;
    hn[idx] = so*tanhf(c);
}

// ---------------- qc,kc ----------------
__global__ __launch_bounds__(256)
void k_qckc(const float* __restrict__ hn, const float* __restrict__ Wqc,
            const float* __restrict__ Wkc, float* __restrict__ qc,
            float* __restrict__ kc)
{
    int idx = blockIdx.x*256 + threadIdx.x;
    if (idx >= NB*NU*64) return;
    int j = idx & 63; int t = idx >> 6;
    int u = t & 7; int b = t >> 3;
    int k = j & 31;
    const float* W = (j < 32 ? Wqc : Wkc) + ((long)u*NH)*NDKC + k;
    const float* h = hn + (long)(b*NU+u)*NH;
    float s = 0.f;
    for (int hh = 0; hh < NH; ++hh) s += h[hh]*W[(long)hh*NDKC];
    (j < 32 ? qc : kc)[(b*NU+u)*NDKC + k] = s;
}

// ---------------- comm probs ----------------
__global__ __launch_bounds__(64)
void k_cp(const float* __restrict__ qc, const float* __restrict__ kc,
          const float* __restrict__ mask, float* __restrict__ cp)
{
    int b = blockIdx.x;
    int lane = threadIdx.x;
    int u = lane >> 3, n = lane & 7;
    const float* qr = qc + (long)(b*NU+u)*NDKC;
    const float* kr = kc + (long)(b*NU+n)*NDKC;
    float d = 0.f;
    for (int k = 0; k < NDKC; ++k) d += qr[k]*kr[k];
    d *= 0.17677669529663687f;
    float mx = d;
    for (int off = 4; off; off >>= 1) mx = fmaxf(mx, __shfl_xor(mx, off, 8));
    float e = expf(d-mx);
    float sm = e;
    for (int off = 4; off; off >>= 1) sm += __shfl_xor(sm, off, 8);
    cp[b*64 + lane] = (e/sm) * mask[b*NU+u];
}

// ---------------- ctx (bf16 in/out) ----------------
__global__ __launch_bounds__(256)
void k_ctx(const unsigned short* __restrict__ vc, const float* __restrict__ cp,
           unsigned short* __restrict__ ctx)
{
    int b = blockIdx.y;
    int v = blockIdx.x*256 + threadIdx.x;
    __shared__ float cps[64];
    if (threadIdx.x < 64) cps[threadIdx.x] = cp[b*64 + threadIdx.x];
    __syncthreads();
    if (v >= NCV) return;
    float vv[NU];
#pragma unroll
    for (int n = 0; n < NU; ++n) vv[n] = bf2f(vc[((long)(b*NU+n))*NCV + v]);
#pragma unroll
    for (int u = 0; u < NU; ++u) {
        float s = 0.f;
#pragma unroll
        for (int n = 0; n < NU; ++n) s += cps[u*8+n]*vv[n];
        ctx[((long)(b*NU+u))*NCV + v] = f2bf(s);
    }
}

// ---------------- fused tail: blend + hy-sum + logits-softmax ----------------
__global__ __launch_bounds__(128)
void k_tail(const float* __restrict__ hn, const float* __restrict__ cn,
            const float* __restrict__ hcw, const float* __restrict__ hx,
            const float* __restrict__ cx, const float* __restrict__ mask,
            const float* __restrict__ piw, const float* __restrict__ pib,
            float* __restrict__ hy, float* __restrict__ cy,
            float* __restrict__ out)
{
    const int b = blockIdx.x;
    const int h = threadIdx.x;
    __shared__ float hs[128];
    __shared__ float lg[28];
    float s = 0.f;
#pragma unroll
    for (int u = 0; u < NU; ++u) {
        int idx = (b*NU+u)*NH + h;
        float m = mask[b*NU+u];
        float hyv = m*(hn[idx]+hcw[idx]) + (1.f-m)*hx[idx];
        float cyv = m*cn[idx] + (1.f-m)*cx[idx];
        hy[idx] = hyv; cy[idx] = cyv;
        s += hyv;
    }
    hs[h] = s;
    __syncthreads();
    if (h < 28) {
        int o = h / 7, a = h - o*7;
        float acc = pib[o*NA+a];
        for (int k = 0; k < NH; ++k) acc += hs[k] * piw[((long)o*NH+k)*NA + a];
        lg[h] = acc;
    }
    __syncthreads();
    if (h < NO) {
        float mx = lg[h*NA];
#pragma unroll
        for (int a = 1; a < NA; ++a) mx = fmaxf(mx, lg[h*NA+a]);
        float e[NA]; float sm = 0.f;
#pragma unroll
        for (int a = 0; a < NA; ++a) { e[a] = expf(lg[h*NA+a]-mx); sm += e[a]; }
        float inv = 1.f/sm;
#pragma unroll
        for (int a = 0; a < NA; ++a) out[(long)b*NO*NA + h*NA + a] = e[a]*inv;
    }
}

extern "C" void kernel_launch(void* const* d_in, const int* in_sizes, int n_in,
                              void* d_out, int out_size, void* d_ws, size_t ws_size,
                              hipStream_t stream) {
    const float* x    = (const float*)d_in[0];
    const float* hx   = (const float*)d_in[1];
    const float* cx   = (const float*)d_in[2];
    const float* opt  = (const float*)d_in[3];
    const float* c1w  = (const float*)d_in[4];
    const float* c1b  = (const float*)d_in[5];
    const float* c2w  = (const float*)d_in[6];
    const float* c2b  = (const float*)d_in[7];
    const float* c3w  = (const float*)d_in[8];
    const float* c3b  = (const float*)d_in[9];
    const float* Wk   = (const float*)d_in[10];
    const float* bk   = (const float*)d_in[11];
    const float* Wv   = (const float*)d_in[12];
    const float* bv   = (const float*)d_in[13];
    const float* Wq   = (const float*)d_in[14];
    const float* Wi   = (const float*)d_in[15];
    const float* Wh   = (const float*)d_in[16];
    const float* blstm= (const float*)d_in[17];
    const float* Wqc  = (const float*)d_in[18];
    const float* Wkc  = (const float*)d_in[19];
    const float* Wvc  = (const float*)d_in[20];
    const float* Wout = (const float*)d_in[21];
    const float* piw  = (const float*)d_in[22];
    const float* pib  = (const float*)d_in[23];

    float* out = (float*)d_out;
    float* hy  = out + (long)NB*NO*NA;
    float* cy  = hy + (long)NB*NU*NH;

    float* ws = (float*)d_ws;
    long o = 0;
    float* b_k0  = ws + o; o += 16384;
    float* b_v0  = ws + o; o += 102400;
    float* b_q   = ws + o; o += 131072;
    float* b_at  = ws + o; o += 819200;
    float* b_re  = ws + o; o += 2048;
    float* b_mk  = ws + o; o += 2048;
    float* b_pre = ws + o; o += 1048576;
    float* b_cn  = ws + o; o += 262144;
    float* b_hn  = ws + o; o += 262144;
    float* b_qc  = ws + o; o += 65536;
    float* b_kc  = ws + o; o += 65536;
    float* b_cp  = ws + o; o += 16384;
    float* b_hc  = ws + o; o += 262144;
    float* b_hs  = ws + o; o += 32768;
    // o == 3088384
    // Region spans (floats), all < NEED = 33,419,264 (proven):
    //  P1OFF  3,088,384: S1 p1 [-> 7,024,640]
    //                    S2 k0 partials S=561 [9,191,424 -> 12,279,808]  (p1/c2 dead)
    //                    S3-S5 WvT [10,764,800 -> 13,853,184]            (after k0 reduce)
    //                    S8+ WvcT [-> 6,533,120], WoutT [-> 9,977,856], partW [-> 14,172,160]
    //  C2OFF  7,024,640: S1 c2 [-> 14,397,440]  (dead after conv3)
    //  EMBOFF 14,397,440: S1-S4 emb32 [-> 28,176,384]
    //                     S5 v0 partials [8,908,800 -> 23,306,240]
    //                     S9+ vc16 [-> 21,286,912], ctx16 [-> 28,176,384]
    //  TOFF   28,176,384: S4-S5 emb16 [3,444,736 -> 31,621,120]  (k0 partials moved out)
    //                     S7 WiT/WhT/pre_h [-> 30,306,304]
    constexpr long P1OFF  = 3088384;
    constexpr long C2OFF  = 7024640;
    constexpr long EMBOFF = 14397440;
    constexpr long TOFF   = 28176384;
    constexpr long NEED   = TOFF + 5242880;   // 33,419,264 floats (proven)
    if (ws_size < (size_t)NEED * sizeof(float)) return;

    float* p1    = ws + P1OFF;
    float* c2    = ws + C2OFF;
    float* emb   = ws + EMBOFF;
    float* partK = ws + P1OFF;                                   // S2 (p1/c2 dead)
    float* partV = ws + EMBOFF;                                  // S5 (emb32 dead)
    unsigned short* emb16 = (unsigned short*)(ws + TOFF);        // S4-S5
    unsigned short* WvT   = (unsigned short*)(ws + P1OFF);       // S3-S5 (after k0 reduce)
    unsigned short* WiT   = (unsigned short*)(ws + TOFF);        // S7 (emb16 dead)
    unsigned short* WhT   = (unsigned short*)(ws + TOFF + 819200);
    float* pre_h          = ws + TOFF + 819200 + 262144;
    unsigned short* WvcT  = (unsigned short*)(ws + P1OFF);       // S8 (WvT dead)
    unsigned short* WoutT = (unsigned short*)(ws + P1OFF + 3444736);
    float* partW          = ws + P1OFF + 2*3444736;
    unsigned short* vc16  = (unsigned short*)(ws + EMBOFF);      // S9 (v0 partials dead)
    unsigned short* ctx16 = (unsigned short*)(ws + EMBOFF + 6889472);

    // S1) conv stack (conv3 via hi/lo MFMA)
    k_conv1<<<(NB*16*H1*W1 + 255)/256, 256, 0, stream>>>(x, c1w, c1b, p1);
    conv2x2_gemm<32,16,H1,W1,H2,W2><<<NB*((H2*W2+127)/128), 256, 0, stream>>>(p1, c2w, c2b, c2);
    conv3_mfma<<<dim3((H3*W3+127)/128, NB), 256, 0, stream>>>(c2, c3w, c3b, emb);

    // S2) k0 = emb@Wk + bk  (fp32; S=561 -> 2.2 blocks/CU; partials in dead p1/c2)
    k0_gemm<<<561, 256, 0, stream>>>(emb, Wk, partK, NE, 96);
    k_reduce_splitk<<<(NB*NDK + 255)/256, 256, 0, stream>>>(
        partK, b_k0, NDK, 0, bk, 0, 1, NB, NDK, 561);

    // S3) Wv -> bf16 transposed [400][53824]  (k0 partials dead)
    k_f2bt<<<dim3(13, 1682, 1), 256, 0, stream>>>(Wv, WvT, NE, NV, 0);

    // S4) emb -> bf16 (RNE; TOFF free)
    k_cvt<<<((long)NB*NE/8 + 255)/256, 256, 0, stream>>>(emb, emb16, (long)NB*NE);

    // S5) v0 = emb16@Wv + bv  (bf16 MFMA, 128x128, S=87; partials at EMBOFF)
    bgemm_splitk<128,128,false><<<dim3(4,2,87), 256, 0, stream>>>(
        emb16, NE, 0, WvT, NE, 0, partV, NB, NV, NE, 87, 624);
    k_reduce_splitk<<<(NB*NV + 255)/256, 256, 0, stream>>>(
        partV, b_v0, NV, 0, bv, 0, 1, NB, NV, 87);

    // S6) q / attention / top-k
    k_q<<<(NB*NU*NDK + 255)/256, 256, 0, stream>>>(opt, hx, Wq, b_q);
    k_attn<<<NB*NU, 64, 0, stream>>>(b_q, b_k0, bk, b_v0, bv, b_at, b_re);
    k_topk<<<1, 256, 0, stream>>>(b_re, b_mk);

    // S7) LSTM pre in bf16 MFMA (fp32 accum/out)
    k_f2bt<<<dim3(16, 13, 8), 256, 0, stream>>>(Wi, WiT, NV, 512, (long)NV*512);
    k_f2bt<<<dim3(16, 4, 8), 256, 0, stream>>>(Wh, WhT, NH, 512, (long)NH*512);
    bgemm_f32<true><<<dim3(8, 4, NU), 256, 0, stream>>>(
        b_at, (long)NU*NV, NV, WiT, NV, (long)512*NV,
        b_pre, (long)NU*512, 512, NB, 512, NV);
    bgemm_f32<true><<<dim3(8, 4, NU), 256, 0, stream>>>(
        hx, (long)NU*NH, NH, WhT, NH, (long)512*NH,
        pre_h, (long)NU*512, 512, NB, 512, NH);
    k_gates<<<(NB*NU*NH + 255)/256, 256, 0, stream>>>(b_pre, pre_h, blstm, cx, b_cn, b_hn);

    // S8) convert Wvc/Wout (WvT dead after v0)
    k_f2bt<<<dim3(211, 4, 8), 256, 0, stream>>>(Wvc, WvcT, NH, NCV, (long)NH*NCV);
    k_f2bt<<<dim3(4, 211, 8), 256, 0, stream>>>(Wout, WoutT, NCV, NH, (long)NCV*NH);

    // S9) vc = h_new@Wvc (bf16 MFMA direct, bf16 out)  (v0 partials dead)
    bgemm_direct<true><<<dim3((NCV+127)/128, 2, NU), 256, 0, stream>>>(
        b_hn, (long)NU*NH, NH, WvcT, NH, (long)NCV*NH,
        vc16, (long)NU*NCV, NCV, NB, NCV, NH);

    // S10) comm probs + ctx
    k_qckc<<<(NB*NU*64 + 255)/256, 256, 0, stream>>>(b_hn, Wqc, Wkc, b_qc, b_kc);
    k_cp<<<NB, 64, 0, stream>>>(b_qc, b_kc, b_mk, b_cp);
    k_ctx<<<dim3((NCV+255)/256, NB), 256, 0, stream>>>(vc16, b_cp, ctx16);

    // S11) hcomm_w = ctx@Wout (bf16 MFMA split-K 16)
    bgemm_splitk<64,64,false><<<dim3(2,4,NU*16), 256, 0, stream>>>(
        ctx16, (long)NU*NCV, NCV, WoutT, NCV, (long)NCV*NH,
        partW, NB, NH, NCV, 16, 448);
    k_reduce_splitk<<<(NU*NB*NH + 255)/256, 256, 0, stream>>>(
        partW, b_hc, (long)NU*NH, NH, nullptr, 0, NU, NB, NH, 16);

    // S12) fused blend + hy-sum + logits
    k_tail<<<NB, 128, 0, stream>>>(b_hn, b_cn, b_hc, hx, cx, b_mk, piw, pib, hy, cy, out);
}

// Round 17
// 432.374 us; speedup vs baseline: 1.1238x; 1.0197x over previous
//
#include <hip/hip_runtime.h>
#include <math.h>

namespace {
constexpr int NB  = 256;
constexpr int NU  = 8;
constexpr int NKT = 4;
constexpr int NH  = 128;
constexpr int NO  = 4;
constexpr int NA  = 7;
constexpr int NV  = 400;
constexpr int NE  = 53824;
constexpr int NCV = 6728;
constexpr int NDK = 64;
constexpr int NDKC= 32;

constexpr int H1 = 31, W1 = 31;
constexpr int H2 = 30, W2 = 30;
constexpr int H3 = 29, W3 = 29;
}

typedef __attribute__((ext_vector_type(8))) short bf16x8_t;
typedef __attribute__((ext_vector_type(4))) float f32x4_t;

__device__ __forceinline__ unsigned short f2bf(float f) {
    unsigned int u = __float_as_uint(f);
    u += 0x7FFFu + ((u >> 16) & 1u);   // RNE
    return (unsigned short)(u >> 16);
}
__device__ __forceinline__ float bf2f(unsigned short h) {
    return __uint_as_float((unsigned int)h << 16);
}

// ---------------- conv1 (2x2, 3->16) + relu + maxpool2 ----------------
__global__ __launch_bounds__(256)
void k_conv1(const float* __restrict__ x, const float* __restrict__ w,
             const float* __restrict__ bias, float* __restrict__ out)
{
    __shared__ float ws[16*3*2*2];
    __shared__ float bs[16];
    int tid = threadIdx.x;
    if (tid < 192) ws[tid] = w[tid];
    if (tid < 16)  bs[tid] = bias[tid];
    __syncthreads();
    long idx = (long)blockIdx.x*256 + tid;
    if (idx >= (long)NB*16*H1*W1) return;
    int pw = idx % W1; long t = idx / W1;
    int ph = t % H1; t /= H1;
    int oc = t % 16; int b = t / 16;
    float mx = 0.f;
#pragma unroll
    for (int dh = 0; dh < 2; ++dh)
#pragma unroll
    for (int dw = 0; dw < 2; ++dw) {
        int h = 2*ph + dh, ww = 2*pw + dw;
        float s = bs[oc];
#pragma unroll
        for (int kh = 0; kh < 2; ++kh)
#pragma unroll
        for (int kw = 0; kw < 2; ++kw) {
            const float* xp = x + (((long)b*64 + (h+kh))*64 + (ww+kw))*3;
#pragma unroll
            for (int ic = 0; ic < 3; ++ic)
                s += xp[ic] * ws[((oc*3+ic)*2+kh)*2+kw];
        }
        mx = fmaxf(mx, s);
    }
    out[idx] = mx;
}

// ---------------- conv2 (2x2, 16->32) as implicit GEMM, 4x4 micro, dbuf ----------------
template<int OC, int IC, int HIN, int WIN, int HOUT, int WOUT>
__global__ __launch_bounds__(256)
void conv2x2_gemm(const float* __restrict__ in, const float* __restrict__ w,
                  const float* __restrict__ bias, float* __restrict__ out)
{
    constexpr int K    = IC*4;
    constexpr int TY   = OC/4;
    constexpr int TX   = 256/TY;
    constexpr int NT   = TX*4;
    constexpr int SPAT = HOUT*WOUT;
    constexpr int NBLK = (SPAT + NT - 1)/NT;
    constexpr int AIT  = OC*16/256;
    constexpr int BIT  = 16*NT/256;

    const int b  = blockIdx.x / NBLK;
    const int n0 = (blockIdx.x % NBLK) * NT;

    __shared__ __align__(16) float As[2][16][OC+4];
    __shared__ __align__(16) float Bs[2][16][NT];

    const int tid = threadIdx.x;
    const int tx = tid % TX, ty = tid / TX;
    float acc[4][4] = {};
    const float* inb = in + (long)b*IC*HIN*WIN;

    const int nIdx = tid & (NT-1);
    int ohw = 0; bool nOk = false;
    {
        int s = n0 + nIdx;
        if (s < SPAT) { ohw = (s / WOUT) * WIN + (s % WOUT); nOk = true; }
    }

    float aR[AIT], bR[BIT];
    auto loadAB = [&](int kk) {
#pragma unroll
        for (int i = 0; i < AIT; ++i) {
            int lin = tid + i*256;
            aR[i] = w[(lin/16)*K + kk + (lin%16)];
        }
#pragma unroll
        for (int i = 0; i < BIT; ++i) {
            int k = (tid + i*256) / NT;
            int gk = kk + k;
            int ic = gk >> 2, tap = gk & 3;
            bR[i] = nOk ? inb[ic*HIN*WIN + ohw + (tap>>1)*WIN + (tap&1)] : 0.f;
        }
    };
    auto storeAB = [&](int buf) {
#pragma unroll
        for (int i = 0; i < AIT; ++i) {
            int lin = tid + i*256;
            As[buf][lin%16][lin/16] = aR[i];
        }
#pragma unroll
        for (int i = 0; i < BIT; ++i) {
            int k = (tid + i*256) / NT;
            Bs[buf][k][nIdx] = bR[i];
        }
    };

    loadAB(0);
    storeAB(0);
    __syncthreads();
    int cur = 0;
    for (int kk = 0; kk < K; kk += 16) {
        const bool more = (kk + 16 < K);
        if (more) loadAB(kk + 16);
#pragma unroll
        for (int k = 0; k < 16; ++k) {
            float4 a4 = *reinterpret_cast<const float4*>(&As[cur][k][ty*4]);
            float4 b4 = *reinterpret_cast<const float4*>(&Bs[cur][k][tx*4]);
            float av[4] = {a4.x,a4.y,a4.z,a4.w};
            float bw[4] = {b4.x,b4.y,b4.z,b4.w};
#pragma unroll
            for (int i = 0; i < 4; ++i)
#pragma unroll
            for (int j = 0; j < 4; ++j) acc[i][j] += av[i]*bw[j];
        }
        if (more) {
            storeAB(cur ^ 1);
            __syncthreads();
            cur ^= 1;
        }
    }
#pragma unroll
    for (int i = 0; i < 4; ++i) {
        int gm = ty*4 + i;
        float bi = bias[gm];
#pragma unroll
        for (int j = 0; j < 4; ++j) {
            int s = n0 + tx*4 + j;
            if (s < SPAT)
                out[((long)b*OC + gm)*SPAT + s] = fmaxf(acc[i][j] + bi, 0.f);
        }
    }
}

// ---------------- conv3 via hi/lo-split bf16 MFMA; dual-writes emb fp32 + bf16 ----------------
__global__ __launch_bounds__(256)
void conv3_mfma(const float* __restrict__ c2, const float* __restrict__ w,
                const float* __restrict__ bias, float* __restrict__ emb,
                unsigned short* __restrict__ emb16)
{
    constexpr int SPAT = 29*29;   // 841
    constexpr int WIN  = 30;
    const int b  = blockIdx.y;
    const int n0 = blockIdx.x * 128;

    __shared__ __align__(16) unsigned short Ah[4*64*32], Al[4*64*32];
    __shared__ __align__(16) unsigned short Bh[128*32],  Bl[128*32];

    const int tid = threadIdx.x;
    const int wave = tid >> 6, lane = tid & 63;
    const int wr = wave >> 1, wc = wave & 1;
    const int lr = lane & 15, lk = lane >> 4;
    const int rbase = wr*32, cbase = wc*64;

    const float* c2b = c2 + (long)b*32*900;

    {
        int row = tid >> 2, kb = tid & 3;
        int p = (kb ^ (row & 3)) << 3;
#pragma unroll
        for (int c = 0; c < 4; ++c) {
            unsigned short hh[8], ll[8];
#pragma unroll
            for (int j = 0; j < 8; ++j) {
                float v = w[(long)row*128 + c*32 + kb*8 + j];
                unsigned short h = f2bf(v);
                hh[j] = h; ll[j] = f2bf(v - bf2f(h));
            }
            *(ushort4*)&Ah[c*2048 + row*32 + p]     = make_ushort4(hh[0],hh[1],hh[2],hh[3]);
            *(ushort4*)&Ah[c*2048 + row*32 + p + 4] = make_ushort4(hh[4],hh[5],hh[6],hh[7]);
            *(ushort4*)&Al[c*2048 + row*32 + p]     = make_ushort4(ll[0],ll[1],ll[2],ll[3]);
            *(ushort4*)&Al[c*2048 + row*32 + p + 4] = make_ushort4(ll[4],ll[5],ll[6],ll[7]);
        }
    }

    const int br0 = tid >> 2, br1 = br0 + 64;
    const int kb  = tid & 3;
    int base0 = 0, base1 = 0; bool ok0, ok1;
    { int s = n0 + br0; ok0 = s < SPAT; if (ok0) base0 = (s/29)*WIN + (s%29); }
    { int s = n0 + br1; ok1 = s < SPAT; if (ok1) base1 = (s/29)*WIN + (s%29); }

    f32x4_t acc[2][4];
#pragma unroll
    for (int i = 0; i < 2; ++i)
#pragma unroll
    for (int j = 0; j < 4; ++j) acc[i][j] = (f32x4_t){0.f,0.f,0.f,0.f};

    for (int c = 0; c < 4; ++c) {
        __syncthreads();
#pragma unroll
        for (int rr = 0; rr < 2; ++rr) {
            int row   = rr ? br1 : br0;
            bool ok   = rr ? ok1 : ok0;
            int base  = rr ? base1 : base0;
            int p = (kb ^ (row & 3)) << 3;
            unsigned short hh[8], ll[8];
#pragma unroll
            for (int j = 0; j < 8; ++j) {
                int gk = c*32 + kb*8 + j;
                int ic = gk >> 2, tap = gk & 3;
                float v = ok ? c2b[ic*900 + base + (tap>>1)*WIN + (tap&1)] : 0.f;
                unsigned short h = f2bf(v);
                hh[j] = h; ll[j] = f2bf(v - bf2f(h));
            }
            *(ushort4*)&Bh[row*32 + p]     = make_ushort4(hh[0],hh[1],hh[2],hh[3]);
            *(ushort4*)&Bh[row*32 + p + 4] = make_ushort4(hh[4],hh[5],hh[6],hh[7]);
            *(ushort4*)&Bl[row*32 + p]     = make_ushort4(ll[0],ll[1],ll[2],ll[3]);
            *(ushort4*)&Bl[row*32 + p + 4] = make_ushort4(ll[4],ll[5],ll[6],ll[7]);
        }
        __syncthreads();
        bf16x8_t ah[2], al[2], bh[4], bl[4];
#pragma unroll
        for (int i = 0; i < 2; ++i) {
            int row = rbase + i*16 + lr;
            int off = c*2048 + row*32 + ((lk ^ (row & 3)) << 3);
            ah[i] = *(const bf16x8_t*)&Ah[off];
            al[i] = *(const bf16x8_t*)&Al[off];
        }
#pragma unroll
        for (int j = 0; j < 4; ++j) {
            int col = cbase + j*16 + lr;
            int off = col*32 + ((lk ^ (col & 3)) << 3);
            bh[j] = *(const bf16x8_t*)&Bh[off];
            bl[j] = *(const bf16x8_t*)&Bl[off];
        }
#pragma unroll
        for (int i = 0; i < 2; ++i)
#pragma unroll
        for (int j = 0; j < 4; ++j) {
            acc[i][j] = __builtin_amdgcn_mfma_f32_16x16x32_bf16(ah[i], bh[j], acc[i][j], 0,0,0);
            acc[i][j] = __builtin_amdgcn_mfma_f32_16x16x32_bf16(ah[i], bl[j], acc[i][j], 0,0,0);
            acc[i][j] = __builtin_amdgcn_mfma_f32_16x16x32_bf16(al[i], bh[j], acc[i][j], 0,0,0);
        }
    }

#pragma unroll
    for (int i = 0; i < 2; ++i)
#pragma unroll
    for (int r = 0; r < 4; ++r) {
        int gm = rbase + i*16 + lk*4 + r;
        float bi = bias[gm];
#pragma unroll
        for (int j = 0; j < 4; ++j) {
            int gn = n0 + cbase + j*16 + lr;
            if (gn < SPAT) {
                float v = fmaxf(acc[i][j][r] + bi, 0.f);
                long off = ((long)b*64 + gm)*SPAT + gn;
                emb[off]   = v;
                emb16[off] = f2bf(v);
            }
        }
    }
}

// ---------------- fp32 -> bf16 transposed convert: in [B][R][Cc] -> out [B][Cc][R] ----------------
__global__ __launch_bounds__(256)
void k_f2bt(const float* __restrict__ in, unsigned short* __restrict__ out,
            int R, int Cc, long sIn)
{
    __shared__ unsigned short t[32][33];
    const int b = blockIdx.z;
    const int r0 = blockIdx.y * 32, c0 = blockIdx.x * 32;
    const float* ip = in + (long)b * sIn;
    unsigned short* op = out + (long)b * sIn;
    const int tid = threadIdx.x;
    {
        int rr = tid >> 3, c4 = (tid & 7) * 4;
        int gr = r0 + rr;
        unsigned short h0=0,h1=0,h2=0,h3=0;
        if (gr < R) {
            if (c0 + c4 + 3 < Cc) {
                float4 f = *(const float4*)(ip + (long)gr*Cc + c0 + c4);
                h0=f2bf(f.x); h1=f2bf(f.y); h2=f2bf(f.z); h3=f2bf(f.w);
            } else {
                if (c0+c4+0 < Cc) h0 = f2bf(ip[(long)gr*Cc + c0+c4+0]);
                if (c0+c4+1 < Cc) h1 = f2bf(ip[(long)gr*Cc + c0+c4+1]);
                if (c0+c4+2 < Cc) h2 = f2bf(ip[(long)gr*Cc + c0+c4+2]);
                if (c0+c4+3 < Cc) h3 = f2bf(ip[(long)gr*Cc + c0+c4+3]);
            }
        }
        t[rr][c4+0]=h0; t[rr][c4+1]=h1; t[rr][c4+2]=h2; t[rr][c4+3]=h3;
    }
    __syncthreads();
    {
        int cc = tid >> 3, r4 = (tid & 7) * 4;
        int gc = c0 + cc;
        if (gc < Cc && r0 + r4 < R) {
            if (r0 + r4 + 3 < R) {
                *(ushort4*)(op + (long)gc*R + r0 + r4) =
                    make_ushort4(t[r4+0][cc], t[r4+1][cc], t[r4+2][cc], t[r4+3][cc]);
            } else {
#pragma unroll
                for (int j = 0; j < 4; ++j)
                    if (r0 + r4 + j < R) op[(long)gc*R + r0 + r4 + j] = t[r4+j][cc];
            }
        }
    }
}

// ---------------- bf16 MFMA GEMM staging, 16B-wide ----------------
template<int ROWS, bool F32>
__device__ __forceinline__ void stage_tile(const void* __restrict__ Av, long lda,
                                           int m0, int kk, int kEnd, int Mlim,
                                           unsigned short* lds, int tid)
{
#pragma unroll
    for (int i = 0; i < ROWS/64; ++i) {
        int row = (tid >> 2) + i*64;
        int blk = tid & 3;
        long gm = m0 + row;
        long gk = kk + blk*8;
        ushort4 lo = make_ushort4(0,0,0,0), hi = make_ushort4(0,0,0,0);
        if (gm < Mlim && gk < kEnd) {
            if (F32) {
                const float* A = (const float*)Av + gm*lda + gk;
                float4 f0 = *(const float4*)(A);
                float4 f1 = *(const float4*)(A + 4);
                lo = make_ushort4(f2bf(f0.x),f2bf(f0.y),f2bf(f0.z),f2bf(f0.w));
                hi = make_ushort4(f2bf(f1.x),f2bf(f1.y),f2bf(f1.z),f2bf(f1.w));
            } else {
                const unsigned short* A = (const unsigned short*)Av + gm*lda + gk;
                lo = *(const ushort4*)(A);
                hi = *(const ushort4*)(A + 4);
            }
        }
        int p = (blk ^ (row & 3)) << 3;
        *(ushort4*)&lds[row*32 + p]     = lo;
        *(ushort4*)&lds[row*32 + p + 4] = hi;
    }
}

template<int BM, int BN, bool AF32>
__global__ __launch_bounds__(256)
void bgemm_splitk(const void* __restrict__ Av, long lda, long sA,
                  const unsigned short* __restrict__ BT, long ldbt, long sB,
                  float* __restrict__ Cpart,
                  int M, int N, int K, int nsplit, int kChunk)
{
    constexpr int MR = BM/32, NR = BN/32;
    const int z = blockIdx.z;
    const int batch = z / nsplit, split = z - batch*nsplit;
    const int kStart = split * kChunk;
    const int kEnd = (kStart + kChunk < K) ? (kStart + kChunk) : K;
    const int m0 = blockIdx.y * BM;
    const int n0 = blockIdx.x * BN;

    __shared__ __align__(16) unsigned short As[BM*32];
    __shared__ __align__(16) unsigned short Bs[BN*32];

    const int tid = threadIdx.x;
    const int wave = tid >> 6, lane = tid & 63;
    const int wr = wave >> 1, wc = wave & 1;
    const int lr = lane & 15, lk = lane >> 4;
    const int rbase = wr*(BM/2), cbase = wc*(BN/2);

    const void* Ab = AF32 ? (const void*)((const float*)Av + (long)batch*sA)
                          : (const void*)((const unsigned short*)Av + (long)batch*sA);
    const unsigned short* Bb = BT + (long)batch*sB;

    f32x4_t acc[MR][NR];
#pragma unroll
    for (int i = 0; i < MR; ++i)
#pragma unroll
    for (int j = 0; j < NR; ++j)
        acc[i][j] = (f32x4_t){0.f,0.f,0.f,0.f};

    for (int kk = kStart; kk < kEnd; kk += 32) {
        stage_tile<BM,AF32>(Ab, lda, m0, kk, kEnd, M, As, tid);
        stage_tile<BN,false>((const void*)Bb, ldbt, n0, kk, kEnd, N, Bs, tid);
        __syncthreads();
        bf16x8_t af[MR], bfv[NR];
#pragma unroll
        for (int i = 0; i < MR; ++i) {
            int row = rbase + i*16 + lr;
            af[i] = *(const bf16x8_t*)&As[row*32 + ((lk ^ (row & 3)) << 3)];
        }
#pragma unroll
        for (int j = 0; j < NR; ++j) {
            int col = cbase + j*16 + lr;
            bfv[j] = *(const bf16x8_t*)&Bs[col*32 + ((lk ^ (col & 3)) << 3)];
        }
#pragma unroll
        for (int i = 0; i < MR; ++i)
#pragma unroll
        for (int j = 0; j < NR; ++j)
            acc[i][j] = __builtin_amdgcn_mfma_f32_16x16x32_bf16(af[i], bfv[j], acc[i][j], 0, 0, 0);
        __syncthreads();
    }

    const long cb2 = (long)z * M * N;
#pragma unroll
    for (int i = 0; i < MR; ++i) {
#pragma unroll
        for (int r = 0; r < 4; ++r) {
            int gm = m0 + rbase + i*16 + lk*4 + r;
            if (gm >= M) continue;
#pragma unroll
            for (int j = 0; j < NR; ++j) {
                int gn = n0 + cbase + j*16 + lr;
                if (gn < N) Cpart[cb2 + (long)gm*N + gn] = acc[i][j][r];
            }
        }
    }
}

// direct bf16 GEMM (full K), bf16 output, 128x128 tile
template<bool AF32>
__global__ __launch_bounds__(256)
void bgemm_direct(const void* __restrict__ Av, long lda, long sA,
                  const unsigned short* __restrict__ BT, long ldbt, long sB,
                  unsigned short* __restrict__ Cout, long ldc, long sC,
                  int M, int N, int K)
{
    const int batch = blockIdx.z;
    const int m0 = blockIdx.y * 128;
    const int n0 = blockIdx.x * 128;

    __shared__ __align__(16) unsigned short As[128*32];
    __shared__ __align__(16) unsigned short Bs[128*32];

    const int tid = threadIdx.x;
    const int wave = tid >> 6, lane = tid & 63;
    const int wr = wave >> 1, wc = wave & 1;
    const int lr = lane & 15, lk = lane >> 4;

    const void* Ab = AF32 ? (const void*)((const float*)Av + (long)batch*sA)
                          : (const void*)((const unsigned short*)Av + (long)batch*sA);
    const unsigned short* Bb = BT + (long)batch*sB;

    f32x4_t acc[4][4];
#pragma unroll
    for (int i = 0; i < 4; ++i)
#pragma unroll
    for (int j = 0; j < 4; ++j)
        acc[i][j] = (f32x4_t){0.f,0.f,0.f,0.f};

    for (int kk = 0; kk < K; kk += 32) {
        stage_tile<128,AF32>(Ab, lda, m0, kk, K, M, As, tid);
        stage_tile<128,false>((const void*)Bb, ldbt, n0, kk, K, N, Bs, tid);
        __syncthreads();
        bf16x8_t af[4], bfv[4];
#pragma unroll
        for (int i = 0; i < 4; ++i) {
            int row = wr*64 + i*16 + lr;
            af[i]  = *(const bf16x8_t*)&As[row*32 + ((lk ^ (row & 3)) << 3)];
            int col = wc*64 + i*16 + lr;
            bfv[i] = *(const bf16x8_t*)&Bs[col*32 + ((lk ^ (col & 3)) << 3)];
        }
#pragma unroll
        for (int i = 0; i < 4; ++i)
#pragma unroll
        for (int j = 0; j < 4; ++j)
            acc[i][j] = __builtin_amdgcn_mfma_f32_16x16x32_bf16(af[i], bfv[j], acc[i][j], 0, 0, 0);
        __syncthreads();
    }

    unsigned short* C = Cout + (long)batch * sC;
#pragma unroll
    for (int i = 0; i < 4; ++i) {
#pragma unroll
        for (int r = 0; r < 4; ++r) {
            int gm = m0 + wr*64 + i*16 + lk*4 + r;
            if (gm >= M) continue;
#pragma unroll
            for (int j = 0; j < 4; ++j) {
                int gn = n0 + wc*64 + j*16 + lr;
                if (gn < N) C[(long)gm*ldc + gn] = f2bf(acc[i][j][r]);
            }
        }
    }
}

// direct bf16-input GEMM, fp32 output, 64x64 tile, batched over grid.z (pre path)
template<bool AF32>
__global__ __launch_bounds__(256)
void bgemm_f32(const void* __restrict__ Av, long lda, long sA,
               const unsigned short* __restrict__ BT, long ldbt, long sB,
               float* __restrict__ Cout, long ldc, long sC,
               int M, int N, int K)
{
    const int batch = blockIdx.z;
    const int m0 = blockIdx.y * 64;
    const int n0 = blockIdx.x * 64;

    __shared__ __align__(16) unsigned short As[64*32];
    __shared__ __align__(16) unsigned short Bs[64*32];

    const int tid = threadIdx.x;
    const int wave = tid >> 6, lane = tid & 63;
    const int wr = wave >> 1, wc = wave & 1;
    const int lr = lane & 15, lk = lane >> 4;
    const int rbase = wr*32, cbase = wc*32;

    const void* Ab = AF32 ? (const void*)((const float*)Av + (long)batch*sA)
                          : (const void*)((const unsigned short*)Av + (long)batch*sA);
    const unsigned short* Bb = BT + (long)batch*sB;

    f32x4_t acc[2][2];
#pragma unroll
    for (int i = 0; i < 2; ++i)
#pragma unroll
    for (int j = 0; j < 2; ++j)
        acc[i][j] = (f32x4_t){0.f,0.f,0.f,0.f};

    for (int kk = 0; kk < K; kk += 32) {
        stage_tile<64,AF32>(Ab, lda, m0, kk, K, M, As, tid);
        stage_tile<64,false>((const void*)Bb, ldbt, n0, kk, K, N, Bs, tid);
        __syncthreads();
        bf16x8_t af[2], bfv[2];
#pragma unroll
        for (int i = 0; i < 2; ++i) {
            int row = rbase + i*16 + lr;
            af[i] = *(const bf16x8_t*)&As[row*32 + ((lk ^ (row & 3)) << 3)];
            int col = cbase + i*16 + lr;
            bfv[i] = *(const bf16x8_t*)&Bs[col*32 + ((lk ^ (col & 3)) << 3)];
        }
#pragma unroll
        for (int i = 0; i < 2; ++i)
#pragma unroll
        for (int j = 0; j < 2; ++j)
            acc[i][j] = __builtin_amdgcn_mfma_f32_16x16x32_bf16(af[i], bfv[j], acc[i][j], 0, 0, 0);
        __syncthreads();
    }

    float* C = Cout + (long)batch * sC;
#pragma unroll
    for (int i = 0; i < 2; ++i) {
#pragma unroll
        for (int r = 0; r < 4; ++r) {
            int gm = m0 + rbase + i*16 + lk*4 + r;
            if (gm >= M) continue;
#pragma unroll
            for (int j = 0; j < 2; ++j) {
                int gn = n0 + cbase + j*16 + lr;
                if (gn < N) C[(long)gm*ldc + gn] = acc[i][j][r];
            }
        }
    }
}

// ---------------- k0: fp32 split-K GEMM, BM=256 (all M), BN=64 (all N) ----------------
__global__ __launch_bounds__(256)
void k0_gemm(const float* __restrict__ A, const float* __restrict__ B,
             float* __restrict__ Cpart, int K, int kChunk)
{
    const int z = blockIdx.x;
    const int kStart = z * kChunk;
    const int kEnd = (kStart + kChunk < K) ? (kStart + kChunk) : K;
    __shared__ __align__(16) float As[16][260];
    __shared__ __align__(16) float Bs[16][64];
    const int tid = threadIdx.x;
    const int tx = tid & 15, ty = tid >> 4;
    float acc[16][4] = {};
    for (int kk = kStart; kk < kEnd; kk += 16) {
#pragma unroll
        for (int i = 0; i < 4; ++i) {
            int row = (tid >> 2) + i*64;
            int k4 = (tid & 3) * 4;
            long gk = kk + k4;
            float4 f = {0,0,0,0};
            if (gk + 3 < (long)kEnd) f = *(const float4*)(A + (long)row*K + gk);
            else {
                if (gk+0 < kEnd) f.x = A[(long)row*K+gk+0];
                if (gk+1 < kEnd) f.y = A[(long)row*K+gk+1];
                if (gk+2 < kEnd) f.z = A[(long)row*K+gk+2];
                if (gk+3 < kEnd) f.w = A[(long)row*K+gk+3];
            }
            As[k4+0][row]=f.x; As[k4+1][row]=f.y; As[k4+2][row]=f.z; As[k4+3][row]=f.w;
        }
        {
            int k = tid >> 4, n = (tid & 15) * 4;
            long gk = kk + k;
            float4 f = {0,0,0,0};
            if (gk < kEnd) f = *(const float4*)(B + gk*64 + n);
            *(float4*)&Bs[k][n] = f;
        }
        __syncthreads();
#pragma unroll
        for (int k = 0; k < 16; ++k) {
            float4 b4 = *reinterpret_cast<const float4*>(&Bs[k][tx*4]);
            float bw[4] = {b4.x,b4.y,b4.z,b4.w};
#pragma unroll
            for (int i4 = 0; i4 < 4; ++i4) {
                float4 a4 = *reinterpret_cast<const float4*>(&As[k][ty*16 + i4*4]);
                float av[4] = {a4.x,a4.y,a4.z,a4.w};
#pragma unroll
                for (int r = 0; r < 4; ++r)
#pragma unroll
                for (int j = 0; j < 4; ++j) acc[i4*4+r][j] += av[r]*bw[j];
            }
        }
        __syncthreads();
    }
    float* cp = Cpart + (long)z*256*64;
#pragma unroll
    for (int i = 0; i < 16; ++i) {
        int gm = ty*16 + i;
#pragma unroll
        for (int j = 0; j < 4; ++j)
            cp[(long)gm*64 + tx*4 + j] = acc[i][j];
    }
}

__global__ __launch_bounds__(256)
void k_reduce_splitk(const float* __restrict__ Cpart, float* __restrict__ out,
                     long ldcOut, long sOut,
                     const float* __restrict__ bias, long sBias,
                     int nbatch, int M, int N, int nsplit)
{
    long idx = (long)blockIdx.x*256 + threadIdx.x;
    long total = (long)nbatch*M*N;
    if (idx >= total) return;
    int n = idx % N; long t = idx / N;
    int m = t % M; int bi = t / M;
    const float* p = Cpart + ((long)bi*nsplit)*((long)M*N) + (long)m*N + n;
    float s = bias ? bias[(long)bi*sBias + n] : 0.f;
#pragma unroll 8
    for (int si = 0; si < nsplit; ++si) s += p[(long)si*M*N];
    out[(long)bi*sOut + (long)m*ldcOut + n] = s;
}

// ---------------- q ----------------
__global__ __launch_bounds__(256)
void k_q(const float* __restrict__ opt, const float* __restrict__ hx,
         const float* __restrict__ Wq, float* __restrict__ q)
{
    int idx = blockIdx.x*256 + threadIdx.x;
    if (idx >= NB*NU*NDK) return;
    int k = idx & 63; int t = idx >> 6;
    int u = t & 7; int b = t >> 3;
    const float* hxr = hx + (long)(b*NU+u)*NH;
    float acc = 0.f;
    for (int o = 0; o < NO; ++o) {
        const float* w = Wq + ((long)(o*NU+u)*NH)*NDK + k;
        float s = 0.f;
        for (int h = 0; h < NH; ++h) s += hxr[h] * w[(long)h*NDK];
        acc += opt[b*NO+o] * s;
    }
    q[idx] = acc;
}

// ---------------- scores + softmax(2) + attn_in + real ----------------
__global__ __launch_bounds__(64)
void k_attn(const float* __restrict__ q, const float* __restrict__ k0,
            const float* __restrict__ bk, const float* __restrict__ v0,
            const float* __restrict__ bv, float* __restrict__ attn,
            float* __restrict__ real)
{
    int bu = blockIdx.x;
    int lane = threadIdx.x;
    int b = bu >> 3;
    float qv = q[(long)bu*NDK + lane];
    float s0 = qv * k0[(long)b*NDK + lane];
    float s1 = qv * bk[lane];
    for (int off = 32; off; off >>= 1) {
        s0 += __shfl_xor(s0, off);
        s1 += __shfl_xor(s1, off);
    }
    s0 *= 0.125f; s1 *= 0.125f;
    float mx = fmaxf(s0, s1);
    float e0 = expf(s0-mx), e1 = expf(s1-mx);
    float inv = 1.f/(e0+e1);
    float p0 = e0*inv, p1 = e1*inv;
    if (lane == 0) real[bu] = p0;
    for (int v = lane; v < NV; v += 64)
        attn[(long)bu*NV + v] = p0*v0[(long)b*NV + v] + p1*bv[v];
}

// ---------------- top-k mask ----------------
__global__ void k_topk(const float* __restrict__ real, float* __restrict__ mask)
{
    int b = blockIdx.x*blockDim.x + threadIdx.x;
    if (b >= NB) return;
    float v[NU]; bool sel[NU];
#pragma unroll
    for (int i = 0; i < NU; ++i) { v[i] = real[b*NU+i]; sel[i] = false; }
    for (int t = 0; t < NKT; ++t) {
        int best = 0; float bvv = -1e30f;
#pragma unroll
        for (int i = 0; i < NU; ++i)
            if (!sel[i] && v[i] > bvv) { bvv = v[i]; best = i; }
        sel[best] = true;
    }
#pragma unroll
    for (int i = 0; i < NU; ++i) mask[b*NU+i] = sel[i] ? 1.f : 0.f;
}

// ---------------- LSTM gates (pre = pre_i + pre_h + blstm) ----------------
__global__ __launch_bounds__(256)
void k_gates(const float* __restrict__ pre_i, const float* __restrict__ pre_h,
             const float* __restrict__ blstm, const float* __restrict__ cx,
             float* __restrict__ cn, float* __restrict__ hn)
{
    int idx = blockIdx.x*256 + threadIdx.x;
    if (idx >= NB*NU*NH) return;
    int h = idx & 127; int bu = idx >> 7;
    int u = bu & 7;
    const float* pi = pre_i + (long)bu*512;
    const float* ph = pre_h + (long)bu*512;
    const float* bl = blstm + (long)u*512;
    float ig = pi[h]     + ph[h]     + bl[h];
    float fg = pi[128+h] + ph[128+h] + bl[128+h];
    float gg = pi[256+h] + ph[256+h] + bl[256+h];
    float og = pi[384+h] + ph[384+h] + bl[384+h];
    float si = 1.f/(1.f+expf(-ig));
    float sf = 1.f/(1.f+expf(-fg));
    float so = 1.f/(1.f+expf(-og));
    float c = sf*cx[idx] + si*tanhf(gg);
    cn[idx] = c;
    hn[idx] = so*tanhf(c);
}

// ---------------- qc,kc ----------------
__global__ __launch_bounds__(256)
void k_qckc(const float* __restrict__ hn, const float* __restrict__ Wqc,
            const float* __restrict__ Wkc, float* __restrict__ qc,
            float* __restrict__ kc)
{
    int idx = blockIdx.x*256 + threadIdx.x;
    if (idx >= NB*NU*64) return;
    int j = idx & 63; int t = idx >> 6;
    int u = t & 7; int b = t >> 3;
    int k = j & 31;
    const float* W = (j < 32 ? Wqc : Wkc) + ((long)u*NH)*NDKC + k;
    const float* h = hn + (long)(b*NU+u)*NH;
    float s = 0.f;
    for (int hh = 0; hh < NH; ++hh) s += h[hh]*W[(long)hh*NDKC];
    (j < 32 ? qc : kc)[(b*NU+u)*NDKC + k] = s;
}

// ---------------- comm probs ----------------
__global__ __launch_bounds__(64)
void k_cp(const float* __restrict__ qc, const float* __restrict__ kc,
          const float* __restrict__ mask, float* __restrict__ cp)
{
    int b = blockIdx.x;
    int lane = threadIdx.x;
    int u = lane >> 3, n = lane & 7;
    const float* qr = qc + (long)(b*NU+u)*NDKC;
    const float* kr = kc + (long)(b*NU+n)*NDKC;
    float d = 0.f;
    for (int k = 0; k < NDKC; ++k) d += qr[k]*kr[k];
    d *= 0.17677669529663687f;
    float mx = d;
    for (int off = 4; off; off >>= 1) mx = fmaxf(mx, __shfl_xor(mx, off, 8));
    float e = expf(d-mx);
    float sm = e;
    for (int off = 4; off; off >>= 1) sm += __shfl_xor(sm, off, 8);
    cp[b*64 + lane] = (e/sm) * mask[b*NU+u];
}

// ---------------- ctx (bf16 in/out) ----------------
__global__ __launch_bounds__(256)
void k_ctx(const unsigned short* __restrict__ vc, const float* __restrict__ cp,
           unsigned short* __restrict__ ctx)
{
    int b = blockIdx.y;
    int v = blockIdx.x*256 + threadIdx.x;
    __shared__ float cps[64];
    if (threadIdx.x < 64) cps[threadIdx.x] = cp[b*64 + threadIdx.x];
    __syncthreads();
    if (v >= NCV) return;
    float vv[NU];
#pragma unroll
    for (int n = 0; n < NU; ++n) vv[n] = bf2f(vc[((long)(b*NU+n))*NCV + v]);
#pragma unroll
    for (int u = 0; u < NU; ++u) {
        float s = 0.f;
#pragma unroll
        for (int n = 0; n < NU; ++n) s += cps[u*8+n]*vv[n];
        ctx[((long)(b*NU+u))*NCV + v] = f2bf(s);
    }
}

// ---------------- fused tail: blend + hy-sum + logits-softmax ----------------
__global__ __launch_bounds__(128)
void k_tail(const float* __restrict__ hn, const float* __restrict__ cn,
            const float* __restrict__ hcw, const float* __restrict__ hx,
            const float* __restrict__ cx, const float* __restrict__ mask,
            const float* __restrict__ piw, const float* __restrict__ pib,
            float* __restrict__ hy, float* __restrict__ cy,
            float* __restrict__ out)
{
    const int b = blockIdx.x;
    const int h = threadIdx.x;
    __shared__ float hs[128];
    __shared__ float lg[28];
    float s = 0.f;
#pragma unroll
    for (int u = 0; u < NU; ++u) {
        int idx = (b*NU+u)*NH + h;
        float m = mask[b*NU+u];
        float hyv = m*(hn[idx]+hcw[idx]) + (1.f-m)*hx[idx];
        float cyv = m*cn[idx] + (1.f-m)*cx[idx];
        hy[idx] = hyv; cy[idx] = cyv;
        s += hyv;
    }
    hs[h] = s;
    __syncthreads();
    if (h < 28) {
        int o = h / 7, a = h - o*7;
        float acc = pib[o*NA+a];
        for (int k = 0; k < NH; ++k) acc += hs[k] * piw[((long)o*NH+k)*NA + a];
        lg[h] = acc;
    }
    __syncthreads();
    if (h < NO) {
        float mx = lg[h*NA];
#pragma unroll
        for (int a = 1; a < NA; ++a) mx = fmaxf(mx, lg[h*NA+a]);
        float e[NA]; float sm = 0.f;
#pragma unroll
        for (int a = 0; a < NA; ++a) { e[a] = expf(lg[h*NA+a]-mx); sm += e[a]; }
        float inv = 1.f/sm;
#pragma unroll
        for (int a = 0; a < NA; ++a) out[(long)b*NO*NA + h*NA + a] = e[a]*inv;
    }
}

extern "C" void kernel_launch(void* const* d_in, const int* in_sizes, int n_in,
                              void* d_out, int out_size, void* d_ws, size_t ws_size,
                              hipStream_t stream) {
    const float* x    = (const float*)d_in[0];
    const float* hx   = (const float*)d_in[1];
    const float* cx   = (const float*)d_in[2];
    const float* opt  = (const float*)d_in[3];
    const float* c1w  = (const float*)d_in[4];
    const float* c1b  = (const float*)d_in[5];
    const float* c2w  = (const float*)d_in[6];
    const float* c2b  = (const float*)d_in[7];
    const float* c3w  = (const float*)d_in[8];
    const float* c3b  = (const float*)d_in[9];
    const float* Wk   = (const float*)d_in[10];
    const float* bk   = (const float*)d_in[11];
    const float* Wv   = (const float*)d_in[12];
    const float* bv   = (const float*)d_in[13];
    const float* Wq   = (const float*)d_in[14];
    const float* Wi   = (const float*)d_in[15];
    const float* Wh   = (const float*)d_in[16];
    const float* blstm= (const float*)d_in[17];
    const float* Wqc  = (const float*)d_in[18];
    const float* Wkc  = (const float*)d_in[19];
    const float* Wvc  = (const float*)d_in[20];
    const float* Wout = (const float*)d_in[21];
    const float* piw  = (const float*)d_in[22];
    const float* pib  = (const float*)d_in[23];

    float* out = (float*)d_out;
    float* hy  = out + (long)NB*NO*NA;
    float* cy  = hy + (long)NB*NU*NH;

    float* ws = (float*)d_ws;
    long o = 0;
    float* b_k0  = ws + o; o += 16384;
    float* b_v0  = ws + o; o += 102400;
    float* b_q   = ws + o; o += 131072;
    float* b_at  = ws + o; o += 819200;
    float* b_re  = ws + o; o += 2048;
    float* b_mk  = ws + o; o += 2048;
    float* b_pre = ws + o; o += 1048576;
    float* b_cn  = ws + o; o += 262144;
    float* b_hn  = ws + o; o += 262144;
    float* b_qc  = ws + o; o += 65536;
    float* b_kc  = ws + o; o += 65536;
    float* b_cp  = ws + o; o += 16384;
    float* b_hc  = ws + o; o += 262144;
    float* b_hs  = ws + o; o += 32768;
    // o == 3088384
    // Region spans (floats), all < NEED = 33,419,264 (proven):
    //  P1OFF  3,088,384: S1 p1 [-> 7,024,640]
    //                    S2 k0 partials S=561 [-> 12,279,808]  (p1/c2 dead)
    //                    S3-S5 WvT [-> 13,853,184]
    //                    S8+ WvcT/WoutT/partW [-> 14,172,160]
    //  C2OFF  7,024,640: S1 c2 [-> 14,397,440]
    //  EMBOFF 14,397,440: S1-S2 emb32 [-> 28,176,384]
    //                     S5 v0 partials S=121 [12,390,400 -> 26,787,840]
    //                     S9+ vc16/ctx16 [-> 28,176,384]
    //  TOFF   28,176,384: S1-S5 emb16 [3,444,736 -> 31,621,120]  (conv3 dual-write)
    //                     S7 WiT/WhT/pre_h [-> 30,306,304]
    constexpr long P1OFF  = 3088384;
    constexpr long C2OFF  = 7024640;
    constexpr long EMBOFF = 14397440;
    constexpr long TOFF   = 28176384;
    constexpr long NEED   = TOFF + 5242880;   // 33,419,264 floats (proven)
    if (ws_size < (size_t)NEED * sizeof(float)) return;

    float* p1    = ws + P1OFF;
    float* c2    = ws + C2OFF;
    float* emb   = ws + EMBOFF;
    float* partK = ws + P1OFF;                                   // S2 (p1/c2 dead)
    float* partV = ws + EMBOFF;                                  // S5 (emb32 dead)
    unsigned short* emb16 = (unsigned short*)(ws + TOFF);        // S1-S5 (conv3 dual-write)
    unsigned short* WvT   = (unsigned short*)(ws + P1OFF);       // S3-S5 (after k0 reduce)
    unsigned short* WiT   = (unsigned short*)(ws + TOFF);        // S7 (emb16 dead)
    unsigned short* WhT   = (unsigned short*)(ws + TOFF + 819200);
    float* pre_h          = ws + TOFF + 819200 + 262144;
    unsigned short* WvcT  = (unsigned short*)(ws + P1OFF);       // S8 (WvT dead)
    unsigned short* WoutT = (unsigned short*)(ws + P1OFF + 3444736);
    float* partW          = ws + P1OFF + 2*3444736;
    unsigned short* vc16  = (unsigned short*)(ws + EMBOFF);      // S9 (v0 partials dead)
    unsigned short* ctx16 = (unsigned short*)(ws + EMBOFF + 6889472);

    // S1) conv stack (conv3 hi/lo MFMA, dual-writes emb32 + emb16 into free TOFF)
    k_conv1<<<(NB*16*H1*W1 + 255)/256, 256, 0, stream>>>(x, c1w, c1b, p1);
    conv2x2_gemm<32,16,H1,W1,H2,W2><<<NB*((H2*W2+127)/128), 256, 0, stream>>>(p1, c2w, c2b, c2);
    conv3_mfma<<<dim3((H3*W3+127)/128, NB), 256, 0, stream>>>(c2, c3w, c3b, emb, emb16);

    // S2) k0 = emb@Wk + bk  (fp32; S=561; partials in dead p1/c2)
    k0_gemm<<<561, 256, 0, stream>>>(emb, Wk, partK, NE, 96);
    k_reduce_splitk<<<(NB*NDK + 255)/256, 256, 0, stream>>>(
        partK, b_k0, NDK, 0, bk, 0, 1, NB, NDK, 561);

    // S3) Wv -> bf16 transposed [400][53824]  (k0 partials dead)
    k_f2bt<<<dim3(13, 1682, 1), 256, 0, stream>>>(Wv, WvT, NE, NV, 0);

    // S5) v0 = emb16@Wv + bv  (bf16 MFMA, 128x128, S=121 -> 968 blocks; partials at EMBOFF)
    bgemm_splitk<128,128,false><<<dim3(4,2,121), 256, 0, stream>>>(
        emb16, NE, 0, WvT, NE, 0, partV, NB, NV, NE, 121, 448);
    k_reduce_splitk<<<(NB*NV + 255)/256, 256, 0, stream>>>(
        partV, b_v0, NV, 0, bv, 0, 1, NB, NV, 121);

    // S6) q / attention / top-k
    k_q<<<(NB*NU*NDK + 255)/256, 256, 0, stream>>>(opt, hx, Wq, b_q);
    k_attn<<<NB*NU, 64, 0, stream>>>(b_q, b_k0, bk, b_v0, bv, b_at, b_re);
    k_topk<<<1, 256, 0, stream>>>(b_re, b_mk);

    // S7) LSTM pre in bf16 MFMA (fp32 accum/out)
    k_f2bt<<<dim3(16, 13, 8), 256, 0, stream>>>(Wi, WiT, NV, 512, (long)NV*512);
    k_f2bt<<<dim3(16, 4, 8), 256, 0, stream>>>(Wh, WhT, NH, 512, (long)NH*512);
    bgemm_f32<true><<<dim3(8, 4, NU), 256, 0, stream>>>(
        b_at, (long)NU*NV, NV, WiT, NV, (long)512*NV,
        b_pre, (long)NU*512, 512, NB, 512, NV);
    bgemm_f32<true><<<dim3(8, 4, NU), 256, 0, stream>>>(
        hx, (long)NU*NH, NH, WhT, NH, (long)512*NH,
        pre_h, (long)NU*512, 512, NB, 512, NH);
    k_gates<<<(NB*NU*NH + 255)/256, 256, 0, stream>>>(b_pre, pre_h, blstm, cx, b_cn, b_hn);

    // S8) convert Wvc/Wout (WvT dead after v0)
    k_f2bt<<<dim3(211, 4, 8), 256, 0, stream>>>(Wvc, WvcT, NH, NCV, (long)NH*NCV);
    k_f2bt<<<dim3(4, 211, 8), 256, 0, stream>>>(Wout, WoutT, NCV, NH, (long)NCV*NH);

    // S9) vc = h_new@Wvc (bf16 MFMA direct, bf16 out)  (v0 partials dead)
    bgemm_direct<true><<<dim3((NCV+127)/128, 2, NU), 256, 0, stream>>>(
        b_hn, (long)NU*NH, NH, WvcT, NH, (long)NCV*NH,
        vc16, (long)NU*NCV, NCV, NB, NCV, NH);

    // S10) comm probs + ctx
    k_qckc<<<(NB*NU*64 + 255)/256, 256, 0, stream>>>(b_hn, Wqc, Wkc, b_qc, b_kc);
    k_cp<<<NB, 64, 0, stream>>>(b_qc, b_kc, b_mk, b_cp);
    k_ctx<<<dim3((NCV+255)/256, NB), 256, 0, stream>>>(vc16, b_cp, ctx16);

    // S11) hcomm_w = ctx@Wout (bf16 MFMA split-K 16)
    bgemm_splitk<64,64,false><<<dim3(2,4,NU*16), 256, 0, stream>>>(
        ctx16, (long)NU*NCV, NCV, WoutT, NCV, (long)NCV*NH,
        partW, NB, NH, NCV, 16, 448);
    k_reduce_splitk<<<(NU*NB*NH + 255)/256, 256, 0, stream>>>(
        partW, b_hc, (long)NU*NH, NH, nullptr, 0, NU, NB, NH, 16);

    // S12) fused blend + hy-sum + logits
    k_tail<<<NB, 128, 0, stream>>>(b_hn, b_cn, b_hc, hx, cx, b_mk, piw, pib, hy, cy, out);
}

// Round 18
// 423.982 us; speedup vs baseline: 1.1460x; 1.0198x over previous
//
#include <hip/hip_runtime.h>
#include <math.h>

namespace {
constexpr int NB  = 256;
constexpr int NU  = 8;
constexpr int NKT = 4;
constexpr int NH  = 128;
constexpr int NO  = 4;
constexpr int NA  = 7;
constexpr int NV  = 400;
constexpr int NE  = 53824;
constexpr int NCV = 6728;
constexpr int NDK = 64;
constexpr int NDKC= 32;

constexpr int H1 = 31, W1 = 31;
constexpr int H2 = 30, W2 = 30;
constexpr int H3 = 29, W3 = 29;
}

typedef __attribute__((ext_vector_type(8))) short bf16x8_t;
typedef __attribute__((ext_vector_type(4))) float f32x4_t;

__device__ __forceinline__ unsigned short f2bf(float f) {
    unsigned int u = __float_as_uint(f);
    u += 0x7FFFu + ((u >> 16) & 1u);   // RNE
    return (unsigned short)(u >> 16);
}
__device__ __forceinline__ float bf2f(unsigned short h) {
    return __uint_as_float((unsigned int)h << 16);
}

// ---------------- conv1 (2x2, 3->16) + relu + maxpool2 ----------------
__global__ __launch_bounds__(256)
void k_conv1(const float* __restrict__ x, const float* __restrict__ w,
             const float* __restrict__ bias, float* __restrict__ out)
{
    __shared__ float ws[16*3*2*2];
    __shared__ float bs[16];
    int tid = threadIdx.x;
    if (tid < 192) ws[tid] = w[tid];
    if (tid < 16)  bs[tid] = bias[tid];
    __syncthreads();
    long idx = (long)blockIdx.x*256 + tid;
    if (idx >= (long)NB*16*H1*W1) return;
    int pw = idx % W1; long t = idx / W1;
    int ph = t % H1; t /= H1;
    int oc = t % 16; int b = t / 16;
    float mx = 0.f;
#pragma unroll
    for (int dh = 0; dh < 2; ++dh)
#pragma unroll
    for (int dw = 0; dw < 2; ++dw) {
        int h = 2*ph + dh, ww = 2*pw + dw;
        float s = bs[oc];
#pragma unroll
        for (int kh = 0; kh < 2; ++kh)
#pragma unroll
        for (int kw = 0; kw < 2; ++kw) {
            const float* xp = x + (((long)b*64 + (h+kh))*64 + (ww+kw))*3;
#pragma unroll
            for (int ic = 0; ic < 3; ++ic)
                s += xp[ic] * ws[((oc*3+ic)*2+kh)*2+kw];
        }
        mx = fmaxf(mx, s);
    }
    out[idx] = mx;
}

// ---------------- conv2 (2x2, 16->32) as implicit GEMM, 4x4 micro, dbuf ----------------
template<int OC, int IC, int HIN, int WIN, int HOUT, int WOUT>
__global__ __launch_bounds__(256)
void conv2x2_gemm(const float* __restrict__ in, const float* __restrict__ w,
                  const float* __restrict__ bias, float* __restrict__ out)
{
    constexpr int K    = IC*4;
    constexpr int TY   = OC/4;
    constexpr int TX   = 256/TY;
    constexpr int NT   = TX*4;
    constexpr int SPAT = HOUT*WOUT;
    constexpr int NBLK = (SPAT + NT - 1)/NT;
    constexpr int AIT  = OC*16/256;
    constexpr int BIT  = 16*NT/256;

    const int b  = blockIdx.x / NBLK;
    const int n0 = (blockIdx.x % NBLK) * NT;

    __shared__ __align__(16) float As[2][16][OC+4];
    __shared__ __align__(16) float Bs[2][16][NT];

    const int tid = threadIdx.x;
    const int tx = tid % TX, ty = tid / TX;
    float acc[4][4] = {};
    const float* inb = in + (long)b*IC*HIN*WIN;

    const int nIdx = tid & (NT-1);
    int ohw = 0; bool nOk = false;
    {
        int s = n0 + nIdx;
        if (s < SPAT) { ohw = (s / WOUT) * WIN + (s % WOUT); nOk = true; }
    }

    float aR[AIT], bR[BIT];
    auto loadAB = [&](int kk) {
#pragma unroll
        for (int i = 0; i < AIT; ++i) {
            int lin = tid + i*256;
            aR[i] = w[(lin/16)*K + kk + (lin%16)];
        }
#pragma unroll
        for (int i = 0; i < BIT; ++i) {
            int k = (tid + i*256) / NT;
            int gk = kk + k;
            int ic = gk >> 2, tap = gk & 3;
            bR[i] = nOk ? inb[ic*HIN*WIN + ohw + (tap>>1)*WIN + (tap&1)] : 0.f;
        }
    };
    auto storeAB = [&](int buf) {
#pragma unroll
        for (int i = 0; i < AIT; ++i) {
            int lin = tid + i*256;
            As[buf][lin%16][lin/16] = aR[i];
        }
#pragma unroll
        for (int i = 0; i < BIT; ++i) {
            int k = (tid + i*256) / NT;
            Bs[buf][k][nIdx] = bR[i];
        }
    };

    loadAB(0);
    storeAB(0);
    __syncthreads();
    int cur = 0;
    for (int kk = 0; kk < K; kk += 16) {
        const bool more = (kk + 16 < K);
        if (more) loadAB(kk + 16);
#pragma unroll
        for (int k = 0; k < 16; ++k) {
            float4 a4 = *reinterpret_cast<const float4*>(&As[cur][k][ty*4]);
            float4 b4 = *reinterpret_cast<const float4*>(&Bs[cur][k][tx*4]);
            float av[4] = {a4.x,a4.y,a4.z,a4.w};
            float bw[4] = {b4.x,b4.y,b4.z,b4.w};
#pragma unroll
            for (int i = 0; i < 4; ++i)
#pragma unroll
            for (int j = 0; j < 4; ++j) acc[i][j] += av[i]*bw[j];
        }
        if (more) {
            storeAB(cur ^ 1);
            __syncthreads();
            cur ^= 1;
        }
    }
#pragma unroll
    for (int i = 0; i < 4; ++i) {
        int gm = ty*4 + i;
        float bi = bias[gm];
#pragma unroll
        for (int j = 0; j < 4; ++j) {
            int s = n0 + tx*4 + j;
            if (s < SPAT)
                out[((long)b*OC + gm)*SPAT + s] = fmaxf(acc[i][j] + bi, 0.f);
        }
    }
}

// ---------------- conv3 via hi/lo-split bf16 MFMA; per-chunk staging (24 KB LDS) ----------------
// Dual-writes emb fp32 + bf16. a*b ~= ah*bh + ah*bl + al*bh, rel err ~2^-18.
__global__ __launch_bounds__(256)
void conv3_mfma(const float* __restrict__ c2, const float* __restrict__ w,
                const float* __restrict__ bias, float* __restrict__ emb,
                unsigned short* __restrict__ emb16)
{
    constexpr int SPAT = 29*29;   // 841
    constexpr int WIN  = 30;
    const int b  = blockIdx.y;
    const int n0 = blockIdx.x * 128;

    __shared__ __align__(16) unsigned short Ah[64*32],  Al[64*32];   // per-chunk W hi/lo (8 KB)
    __shared__ __align__(16) unsigned short Bh[128*32], Bl[128*32];  // per-chunk im2col (16 KB)

    const int tid = threadIdx.x;
    const int wave = tid >> 6, lane = tid & 63;
    const int wr = wave >> 1, wc = wave & 1;
    const int lr = lane & 15, lk = lane >> 4;
    const int rbase = wr*32, cbase = wc*64;

    const float* c2b = c2 + (long)b*32*900;

    // A staging assignment: row(oc)=tid>>2, 8-elem k block kb=tid&3 (exactly 256 slots)
    const int arow = tid >> 2, akb = tid & 3;
    const int ap = (akb ^ (arow & 3)) << 3;

    // B (im2col) row assignment: spatial rows tid>>2 and +64; hoisted offsets
    const int br0 = tid >> 2, br1 = br0 + 64;
    const int kb  = tid & 3;
    int base0 = 0, base1 = 0; bool ok0, ok1;
    { int s = n0 + br0; ok0 = s < SPAT; if (ok0) base0 = (s/29)*WIN + (s%29); }
    { int s = n0 + br1; ok1 = s < SPAT; if (ok1) base1 = (s/29)*WIN + (s%29); }

    f32x4_t acc[2][4];
#pragma unroll
    for (int i = 0; i < 2; ++i)
#pragma unroll
    for (int j = 0; j < 4; ++j) acc[i][j] = (f32x4_t){0.f,0.f,0.f,0.f};

    for (int c = 0; c < 4; ++c) {
        if (c) __syncthreads();   // prior chunk's fragment reads complete before overwrite
        {   // stage W chunk hi/lo
            unsigned short hh[8], ll[8];
#pragma unroll
            for (int j = 0; j < 8; ++j) {
                float v = w[(long)arow*128 + c*32 + akb*8 + j];
                unsigned short h = f2bf(v);
                hh[j] = h; ll[j] = f2bf(v - bf2f(h));
            }
            *(ushort4*)&Ah[arow*32 + ap]     = make_ushort4(hh[0],hh[1],hh[2],hh[3]);
            *(ushort4*)&Ah[arow*32 + ap + 4] = make_ushort4(hh[4],hh[5],hh[6],hh[7]);
            *(ushort4*)&Al[arow*32 + ap]     = make_ushort4(ll[0],ll[1],ll[2],ll[3]);
            *(ushort4*)&Al[arow*32 + ap + 4] = make_ushort4(ll[4],ll[5],ll[6],ll[7]);
        }
#pragma unroll
        for (int rr = 0; rr < 2; ++rr) {
            int row   = rr ? br1 : br0;
            bool ok   = rr ? ok1 : ok0;
            int base  = rr ? base1 : base0;
            int p = (kb ^ (row & 3)) << 3;
            unsigned short hh[8], ll[8];
#pragma unroll
            for (int j = 0; j < 8; ++j) {
                int gk = c*32 + kb*8 + j;
                int ic = gk >> 2, tap = gk & 3;
                float v = ok ? c2b[ic*900 + base + (tap>>1)*WIN + (tap&1)] : 0.f;
                unsigned short h = f2bf(v);
                hh[j] = h; ll[j] = f2bf(v - bf2f(h));
            }
            *(ushort4*)&Bh[row*32 + p]     = make_ushort4(hh[0],hh[1],hh[2],hh[3]);
            *(ushort4*)&Bh[row*32 + p + 4] = make_ushort4(hh[4],hh[5],hh[6],hh[7]);
            *(ushort4*)&Bl[row*32 + p]     = make_ushort4(ll[0],ll[1],ll[2],ll[3]);
            *(ushort4*)&Bl[row*32 + p + 4] = make_ushort4(ll[4],ll[5],ll[6],ll[7]);
        }
        __syncthreads();
        bf16x8_t ah[2], al[2], bh[4], bl[4];
#pragma unroll
        for (int i = 0; i < 2; ++i) {
            int row = rbase + i*16 + lr;
            int off = row*32 + ((lk ^ (row & 3)) << 3);
            ah[i] = *(const bf16x8_t*)&Ah[off];
            al[i] = *(const bf16x8_t*)&Al[off];
        }
#pragma unroll
        for (int j = 0; j < 4; ++j) {
            int col = cbase + j*16 + lr;
            int off = col*32 + ((lk ^ (col & 3)) << 3);
            bh[j] = *(const bf16x8_t*)&Bh[off];
            bl[j] = *(const bf16x8_t*)&Bl[off];
        }
#pragma unroll
        for (int i = 0; i < 2; ++i)
#pragma unroll
        for (int j = 0; j < 4; ++j) {
            acc[i][j] = __builtin_amdgcn_mfma_f32_16x16x32_bf16(ah[i], bh[j], acc[i][j], 0,0,0);
            acc[i][j] = __builtin_amdgcn_mfma_f32_16x16x32_bf16(ah[i], bl[j], acc[i][j], 0,0,0);
            acc[i][j] = __builtin_amdgcn_mfma_f32_16x16x32_bf16(al[i], bh[j], acc[i][j], 0,0,0);
        }
    }

#pragma unroll
    for (int i = 0; i < 2; ++i)
#pragma unroll
    for (int r = 0; r < 4; ++r) {
        int gm = rbase + i*16 + lk*4 + r;
        float bi = bias[gm];
#pragma unroll
        for (int j = 0; j < 4; ++j) {
            int gn = n0 + cbase + j*16 + lr;
            if (gn < SPAT) {
                float v = fmaxf(acc[i][j][r] + bi, 0.f);
                long off = ((long)b*64 + gm)*SPAT + gn;
                emb[off]   = v;
                emb16[off] = f2bf(v);
            }
        }
    }
}

// ---------------- fp32 -> bf16 transposed convert: in [B][R][Cc] -> out [B][Cc][R] ----------------
__global__ __launch_bounds__(256)
void k_f2bt(const float* __restrict__ in, unsigned short* __restrict__ out,
            int R, int Cc, long sIn)
{
    __shared__ unsigned short t[32][33];
    const int b = blockIdx.z;
    const int r0 = blockIdx.y * 32, c0 = blockIdx.x * 32;
    const float* ip = in + (long)b * sIn;
    unsigned short* op = out + (long)b * sIn;
    const int tid = threadIdx.x;
    {
        int rr = tid >> 3, c4 = (tid & 7) * 4;
        int gr = r0 + rr;
        unsigned short h0=0,h1=0,h2=0,h3=0;
        if (gr < R) {
            if (c0 + c4 + 3 < Cc) {
                float4 f = *(const float4*)(ip + (long)gr*Cc + c0 + c4);
                h0=f2bf(f.x); h1=f2bf(f.y); h2=f2bf(f.z); h3=f2bf(f.w);
            } else {
                if (c0+c4+0 < Cc) h0 = f2bf(ip[(long)gr*Cc + c0+c4+0]);
                if (c0+c4+1 < Cc) h1 = f2bf(ip[(long)gr*Cc + c0+c4+1]);
                if (c0+c4+2 < Cc) h2 = f2bf(ip[(long)gr*Cc + c0+c4+2]);
                if (c0+c4+3 < Cc) h3 = f2bf(ip[(long)gr*Cc + c0+c4+3]);
            }
        }
        t[rr][c4+0]=h0; t[rr][c4+1]=h1; t[rr][c4+2]=h2; t[rr][c4+3]=h3;
    }
    __syncthreads();
    {
        int cc = tid >> 3, r4 = (tid & 7) * 4;
        int gc = c0 + cc;
        if (gc < Cc && r0 + r4 < R) {
            if (r0 + r4 + 3 < R) {
                *(ushort4*)(op + (long)gc*R + r0 + r4) =
                    make_ushort4(t[r4+0][cc], t[r4+1][cc], t[r4+2][cc], t[r4+3][cc]);
            } else {
#pragma unroll
                for (int j = 0; j < 4; ++j)
                    if (r0 + r4 + j < R) op[(long)gc*R + r0 + r4 + j] = t[r4+j][cc];
            }
        }
    }
}

// ---------------- bf16 MFMA GEMM staging, 16B-wide ----------------
template<int ROWS, bool F32>
__device__ __forceinline__ void stage_tile(const void* __restrict__ Av, long lda,
                                           int m0, int kk, int kEnd, int Mlim,
                                           unsigned short* lds, int tid)
{
#pragma unroll
    for (int i = 0; i < ROWS/64; ++i) {
        int row = (tid >> 2) + i*64;
        int blk = tid & 3;
        long gm = m0 + row;
        long gk = kk + blk*8;
        ushort4 lo = make_ushort4(0,0,0,0), hi = make_ushort4(0,0,0,0);
        if (gm < Mlim && gk < kEnd) {
            if (F32) {
                const float* A = (const float*)Av + gm*lda + gk;
                float4 f0 = *(const float4*)(A);
                float4 f1 = *(const float4*)(A + 4);
                lo = make_ushort4(f2bf(f0.x),f2bf(f0.y),f2bf(f0.z),f2bf(f0.w));
                hi = make_ushort4(f2bf(f1.x),f2bf(f1.y),f2bf(f1.z),f2bf(f1.w));
            } else {
                const unsigned short* A = (const unsigned short*)Av + gm*lda + gk;
                lo = *(const ushort4*)(A);
                hi = *(const ushort4*)(A + 4);
            }
        }
        int p = (blk ^ (row & 3)) << 3;
        *(ushort4*)&lds[row*32 + p]     = lo;
        *(ushort4*)&lds[row*32 + p + 4] = hi;
    }
}

template<int BM, int BN, bool AF32>
__global__ __launch_bounds__(256)
void bgemm_splitk(const void* __restrict__ Av, long lda, long sA,
                  const unsigned short* __restrict__ BT, long ldbt, long sB,
                  float* __restrict__ Cpart,
                  int M, int N, int K, int nsplit, int kChunk)
{
    constexpr int MR = BM/32, NR = BN/32;
    const int z = blockIdx.z;
    const int batch = z / nsplit, split = z - batch*nsplit;
    const int kStart = split * kChunk;
    const int kEnd = (kStart + kChunk < K) ? (kStart + kChunk) : K;
    const int m0 = blockIdx.y * BM;
    const int n0 = blockIdx.x * BN;

    __shared__ __align__(16) unsigned short As[BM*32];
    __shared__ __align__(16) unsigned short Bs[BN*32];

    const int tid = threadIdx.x;
    const int wave = tid >> 6, lane = tid & 63;
    const int wr = wave >> 1, wc = wave & 1;
    const int lr = lane & 15, lk = lane >> 4;
    const int rbase = wr*(BM/2), cbase = wc*(BN/2);

    const void* Ab = AF32 ? (const void*)((const float*)Av + (long)batch*sA)
                          : (const void*)((const unsigned short*)Av + (long)batch*sA);
    const unsigned short* Bb = BT + (long)batch*sB;

    f32x4_t acc[MR][NR];
#pragma unroll
    for (int i = 0; i < MR; ++i)
#pragma unroll
    for (int j = 0; j < NR; ++j)
        acc[i][j] = (f32x4_t){0.f,0.f,0.f,0.f};

    for (int kk = kStart; kk < kEnd; kk += 32) {
        stage_tile<BM,AF32>(Ab, lda, m0, kk, kEnd, M, As, tid);
        stage_tile<BN,false>((const void*)Bb, ldbt, n0, kk, kEnd, N, Bs, tid);
        __syncthreads();
        bf16x8_t af[MR], bfv[NR];
#pragma unroll
        for (int i = 0; i < MR; ++i) {
            int row = rbase + i*16 + lr;
            af[i] = *(const bf16x8_t*)&As[row*32 + ((lk ^ (row & 3)) << 3)];
        }
#pragma unroll
        for (int j = 0; j < NR; ++j) {
            int col = cbase + j*16 + lr;
            bfv[j] = *(const bf16x8_t*)&Bs[col*32 + ((lk ^ (col & 3)) << 3)];
        }
#pragma unroll
        for (int i = 0; i < MR; ++i)
#pragma unroll
        for (int j = 0; j < NR; ++j)
            acc[i][j] = __builtin_amdgcn_mfma_f32_16x16x32_bf16(af[i], bfv[j], acc[i][j], 0, 0, 0);
        __syncthreads();
    }

    const long cb2 = (long)z * M * N;
#pragma unroll
    for (int i = 0; i < MR; ++i) {
#pragma unroll
        for (int r = 0; r < 4; ++r) {
            int gm = m0 + rbase + i*16 + lk*4 + r;
            if (gm >= M) continue;
#pragma unroll
            for (int j = 0; j < NR; ++j) {
                int gn = n0 + cbase + j*16 + lr;
                if (gn < N) Cpart[cb2 + (long)gm*N + gn] = acc[i][j][r];
            }
        }
    }
}

// direct bf16 GEMM (full K), bf16 output, 128x128 tile
template<bool AF32>
__global__ __launch_bounds__(256)
void bgemm_direct(const void* __restrict__ Av, long lda, long sA,
                  const unsigned short* __restrict__ BT, long ldbt, long sB,
                  unsigned short* __restrict__ Cout, long ldc, long sC,
                  int M, int N, int K)
{
    const int batch = blockIdx.z;
    const int m0 = blockIdx.y * 128;
    const int n0 = blockIdx.x * 128;

    __shared__ __align__(16) unsigned short As[128*32];
    __shared__ __align__(16) unsigned short Bs[128*32];

    const int tid = threadIdx.x;
    const int wave = tid >> 6, lane = tid & 63;
    const int wr = wave >> 1, wc = wave & 1;
    const int lr = lane & 15, lk = lane >> 4;

    const void* Ab = AF32 ? (const void*)((const float*)Av + (long)batch*sA)
                          : (const void*)((const unsigned short*)Av + (long)batch*sA);
    const unsigned short* Bb = BT + (long)batch*sB;

    f32x4_t acc[4][4];
#pragma unroll
    for (int i = 0; i < 4; ++i)
#pragma unroll
    for (int j = 0; j < 4; ++j)
        acc[i][j] = (f32x4_t){0.f,0.f,0.f,0.f};

    for (int kk = 0; kk < K; kk += 32) {
        stage_tile<128,AF32>(Ab, lda, m0, kk, K, M, As, tid);
        stage_tile<128,false>((const void*)Bb, ldbt, n0, kk, K, N, Bs, tid);
        __syncthreads();
        bf16x8_t af[4], bfv[4];
#pragma unroll
        for (int i = 0; i < 4; ++i) {
            int row = wr*64 + i*16 + lr;
            af[i]  = *(const bf16x8_t*)&As[row*32 + ((lk ^ (row & 3)) << 3)];
            int col = wc*64 + i*16 + lr;
            bfv[i] = *(const bf16x8_t*)&Bs[col*32 + ((lk ^ (col & 3)) << 3)];
        }
#pragma unroll
        for (int i = 0; i < 4; ++i)
#pragma unroll
        for (int j = 0; j < 4; ++j)
            acc[i][j] = __builtin_amdgcn_mfma_f32_16x16x32_bf16(af[i], bfv[j], acc[i][j], 0, 0, 0);
        __syncthreads();
    }

    unsigned short* C = Cout + (long)batch * sC;
#pragma unroll
    for (int i = 0; i < 4; ++i) {
#pragma unroll
        for (int r = 0; r < 4; ++r) {
            int gm = m0 + wr*64 + i*16 + lk*4 + r;
            if (gm >= M) continue;
#pragma unroll
            for (int j = 0; j < 4; ++j) {
                int gn = n0 + wc*64 + j*16 + lr;
                if (gn < N) C[(long)gm*ldc + gn] = f2bf(acc[i][j][r]);
            }
        }
    }
}

// direct bf16-input GEMM, fp32 output, 64x64 tile, batched over grid.z (pre path)
template<bool AF32>
__global__ __launch_bounds__(256)
void bgemm_f32(const void* __restrict__ Av, long lda, long sA,
               const unsigned short* __restrict__ BT, long ldbt, long sB,
               float* __restrict__ Cout, long ldc, long sC,
               int M, int N, int K)
{
    const int batch = blockIdx.z;
    const int m0 = blockIdx.y * 64;
    const int n0 = blockIdx.x * 64;

    __shared__ __align__(16) unsigned short As[64*32];
    __shared__ __align__(16) unsigned short Bs[64*32];

    const int tid = threadIdx.x;
    const int wave = tid >> 6, lane = tid & 63;
    const int wr = wave >> 1, wc = wave & 1;
    const int lr = lane & 15, lk = lane >> 4;
    const int rbase = wr*32, cbase = wc*32;

    const void* Ab = AF32 ? (const void*)((const float*)Av + (long)batch*sA)
                          : (const void*)((const unsigned short*)Av + (long)batch*sA);
    const unsigned short* Bb = BT + (long)batch*sB;

    f32x4_t acc[2][2];
#pragma unroll
    for (int i = 0; i < 2; ++i)
#pragma unroll
    for (int j = 0; j < 2; ++j)
        acc[i][j] = (f32x4_t){0.f,0.f,0.f,0.f};

    for (int kk = 0; kk < K; kk += 32) {
        stage_tile<64,AF32>(Ab, lda, m0, kk, K, M, As, tid);
        stage_tile<64,false>((const void*)Bb, ldbt, n0, kk, K, N, Bs, tid);
        __syncthreads();
        bf16x8_t af[2], bfv[2];
#pragma unroll
        for (int i = 0; i < 2; ++i) {
            int row = rbase + i*16 + lr;
            af[i] = *(const bf16x8_t*)&As[row*32 + ((lk ^ (row & 3)) << 3)];
            int col = cbase + i*16 + lr;
            bfv[i] = *(const bf16x8_t*)&Bs[col*32 + ((lk ^ (col & 3)) << 3)];
        }
#pragma unroll
        for (int i = 0; i < 2; ++i)
#pragma unroll
        for (int j = 0; j < 2; ++j)
            acc[i][j] = __builtin_amdgcn_mfma_f32_16x16x32_bf16(af[i], bfv[j], acc[i][j], 0, 0, 0);
        __syncthreads();
    }

    float* C = Cout + (long)batch * sC;
#pragma unroll
    for (int i = 0; i < 2; ++i) {
#pragma unroll
        for (int r = 0; r < 4; ++r) {
            int gm = m0 + rbase + i*16 + lk*4 + r;
            if (gm >= M) continue;
#pragma unroll
            for (int j = 0; j < 2; ++j) {
                int gn = n0 + cbase + j*16 + lr;
                if (gn < N) C[(long)gm*ldc + gn] = acc[i][j][r];
            }
        }
    }
}

// ---------------- k0: fp32 split-K GEMM, BM=256 (all M), BN=64 (all N) ----------------
__global__ __launch_bounds__(256)
void k0_gemm(const float* __restrict__ A, const float* __restrict__ B,
             float* __restrict__ Cpart, int K, int kChunk)
{
    const int z = blockIdx.x;
    const int kStart = z * kChunk;
    const int kEnd = (kStart + kChunk < K) ? (kStart + kChunk) : K;
    __shared__ __align__(16) float As[16][260];
    __shared__ __align__(16) float Bs[16][64];
    const int tid = threadIdx.x;
    const int tx = tid & 15, ty = tid >> 4;
    float acc[16][4] = {};
    for (int kk = kStart; kk < kEnd; kk += 16) {
#pragma unroll
        for (int i = 0; i < 4; ++i) {
            int row = (tid >> 2) + i*64;
            int k4 = (tid & 3) * 4;
            long gk = kk + k4;
            float4 f = {0,0,0,0};
            if (gk + 3 < (long)kEnd) f = *(const float4*)(A + (long)row*K + gk);
            else {
                if (gk+0 < kEnd) f.x = A[(long)row*K+gk+0];
                if (gk+1 < kEnd) f.y = A[(long)row*K+gk+1];
                if (gk+2 < kEnd) f.z = A[(long)row*K+gk+2];
                if (gk+3 < kEnd) f.w = A[(long)row*K+gk+3];
            }
            As[k4+0][row]=f.x; As[k4+1][row]=f.y; As[k4+2][row]=f.z; As[k4+3][row]=f.w;
        }
        {
            int k = tid >> 4, n = (tid & 15) * 4;
            long gk = kk + k;
            float4 f = {0,0,0,0};
            if (gk < kEnd) f = *(const float4*)(B + gk*64 + n);
            *(float4*)&Bs[k][n] = f;
        }
        __syncthreads();
#pragma unroll
        for (int k = 0; k < 16; ++k) {
            float4 b4 = *reinterpret_cast<const float4*>(&Bs[k][tx*4]);
            float bw[4] = {b4.x,b4.y,b4.z,b4.w};
#pragma unroll
            for (int i4 = 0; i4 < 4; ++i4) {
                float4 a4 = *reinterpret_cast<const float4*>(&As[k][ty*16 + i4*4]);
                float av[4] = {a4.x,a4.y,a4.z,a4.w};
#pragma unroll
                for (int r = 0; r < 4; ++r)
#pragma unroll
                for (int j = 0; j < 4; ++j) acc[i4*4+r][j] += av[r]*bw[j];
            }
        }
        __syncthreads();
    }
    float* cp = Cpart + (long)z*256*64;
#pragma unroll
    for (int i = 0; i < 16; ++i) {
        int gm = ty*16 + i;
#pragma unroll
        for (int j = 0; j < 4; ++j)
            cp[(long)gm*64 + tx*4 + j] = acc[i][j];
    }
}

__global__ __launch_bounds__(256)
void k_reduce_splitk(const float* __restrict__ Cpart, float* __restrict__ out,
                     long ldcOut, long sOut,
                     const float* __restrict__ bias, long sBias,
                     int nbatch, int M, int N, int nsplit)
{
    long idx = (long)blockIdx.x*256 + threadIdx.x;
    long total = (long)nbatch*M*N;
    if (idx >= total) return;
    int n = idx % N; long t = idx / N;
    int m = t % M; int bi = t / M;
    const float* p = Cpart + ((long)bi*nsplit)*((long)M*N) + (long)m*N + n;
    float s = bias ? bias[(long)bi*sBias + n] : 0.f;
#pragma unroll 8
    for (int si = 0; si < nsplit; ++si) s += p[(long)si*M*N];
    out[(long)bi*sOut + (long)m*ldcOut + n] = s;
}

// ---------------- q ----------------
__global__ __launch_bounds__(256)
void k_q(const float* __restrict__ opt, const float* __restrict__ hx,
         const float* __restrict__ Wq, float* __restrict__ q)
{
    int idx = blockIdx.x*256 + threadIdx.x;
    if (idx >= NB*NU*NDK) return;
    int k = idx & 63; int t = idx >> 6;
    int u = t & 7; int b = t >> 3;
    const float* hxr = hx + (long)(b*NU+u)*NH;
    float acc = 0.f;
    for (int o = 0; o < NO; ++o) {
        const float* w = Wq + ((long)(o*NU+u)*NH)*NDK + k;
        float s = 0.f;
        for (int h = 0; h < NH; ++h) s += hxr[h] * w[(long)h*NDK];
        acc += opt[b*NO+o] * s;
    }
    q[idx] = acc;
}

// ---------------- scores + softmax(2) + attn_in + real ----------------
__global__ __launch_bounds__(64)
void k_attn(const float* __restrict__ q, const float* __restrict__ k0,
            const float* __restrict__ bk, const float* __restrict__ v0,
            const float* __restrict__ bv, float* __restrict__ attn,
            float* __restrict__ real)
{
    int bu = blockIdx.x;
    int lane = threadIdx.x;
    int b = bu >> 3;
    float qv = q[(long)bu*NDK + lane];
    float s0 = qv * k0[(long)b*NDK + lane];
    float s1 = qv * bk[lane];
    for (int off = 32; off; off >>= 1) {
        s0 += __shfl_xor(s0, off);
        s1 += __shfl_xor(s1, off);
    }
    s0 *= 0.125f; s1 *= 0.125f;
    float mx = fmaxf(s0, s1);
    float e0 = expf(s0-mx), e1 = expf(s1-mx);
    float inv = 1.f/(e0+e1);
    float p0 = e0*inv, p1 = e1*inv;
    if (lane == 0) real[bu] = p0;
    for (int v = lane; v < NV; v += 64)
        attn[(long)bu*NV + v] = p0*v0[(long)b*NV + v] + p1*bv[v];
}

// ---------------- top-k mask ----------------
__global__ void k_topk(const float* __restrict__ real, float* __restrict__ mask)
{
    int b = blockIdx.x*blockDim.x + threadIdx.x;
    if (b >= NB) return;
    float v[NU]; bool sel[NU];
#pragma unroll
    for (int i = 0; i < NU; ++i) { v[i] = real[b*NU+i]; sel[i] = false; }
    for (int t = 0; t < NKT; ++t) {
        int best = 0; float bvv = -1e30f;
#pragma unroll
        for (int i = 0; i < NU; ++i)
            if (!sel[i] && v[i] > bvv) { bvv = v[i]; best = i; }
        sel[best] = true;
    }
#pragma unroll
    for (int i = 0; i < NU; ++i) mask[b*NU+i] = sel[i] ? 1.f : 0.f;
}

// ---------------- LSTM gates (pre = pre_i + pre_h + blstm) ----------------
__global__ __launch_bounds__(256)
void k_gates(const float* __restrict__ pre_i, const float* __restrict__ pre_h,
             const float* __restrict__ blstm, const float* __restrict__ cx,
             float* __restrict__ cn, float* __restrict__ hn)
{
    int idx = blockIdx.x*256 + threadIdx.x;
    if (idx >= NB*NU*NH) return;
    int h = idx & 127; int bu = idx >> 7;
    int u = bu & 7;
    const float* pi = pre_i + (long)bu*512;
    const float* ph = pre_h + (long)bu*512;
    const float* bl = blstm + (long)u*512;
    float ig = pi[h]     + ph[h]     + bl[h];
    float fg = pi[128+h] + ph[128+h] + bl[128+h];
    float gg = pi[256+h] + ph[256+h] + bl[256+h];
    float og = pi[384+h] + ph[384+h] + bl[384+h];
    float si = 1.f/(1.f+expf(-ig));
    float sf = 1.f/(1.f+expf(-fg));
    float so = 1.f/(1.f+expf(-og));
    float c = sf*cx[idx] + si*tanhf(gg);
    cn[idx] = c;
    hn[idx] = so*tanhf(c);
}

// ---------------- qc,kc ----------------
__global__ __launch_bounds__(256)
void k_qckc(const float* __restrict__ hn, const float* __restrict__ Wqc,
            const float* __restrict__ Wkc, float* __restrict__ qc,
            float* __restrict__ kc)
{
    int idx = blockIdx.x*256 + threadIdx.x;
    if (idx >= NB*NU*64) return;
    int j = idx & 63; int t = idx >> 6;
    int u = t & 7; int b = t >> 3;
    int k = j & 31;
    const float* W = (j < 32 ? Wqc : Wkc) + ((long)u*NH)*NDKC + k;
    const float* h = hn + (long)(b*NU+u)*NH;
    float s = 0.f;
    for (int hh = 0; hh < NH; ++hh) s += h[hh]*W[(long)hh*NDKC];
    (j < 32 ? qc : kc)[(b*NU+u)*NDKC + k] = s;
}

// ---------------- comm probs ----------------
__global__ __launch_bounds__(64)
void k_cp(const float* __restrict__ qc, const float* __restrict__ kc,
          const float* __restrict__ mask, float* __restrict__ cp)
{
    int b = blockIdx.x;
    int lane = threadIdx.x;
    int u = lane >> 3, n = lane & 7;
    const float* qr = qc + (long)(b*NU+u)*NDKC;
    const float* kr = kc + (long)(b*NU+n)*NDKC;
    float d = 0.f;
    for (int k = 0; k < NDKC; ++k) d += qr[k]*kr[k];
    d *= 0.17677669529663687f;
    float mx = d;
    for (int off = 4; off; off >>= 1) mx = fmaxf(mx, __shfl_xor(mx, off, 8));
    float e = expf(d-mx);
    float sm = e;
    for (int off = 4; off; off >>= 1) sm += __shfl_xor(sm, off, 8);
    cp[b*64 + lane] = (e/sm) * mask[b*NU+u];
}

// ---------------- ctx (bf16 in/out) ----------------
__global__ __launch_bounds__(256)
void k_ctx(const unsigned short* __restrict__ vc, const float* __restrict__ cp,
           unsigned short* __restrict__ ctx)
{
    int b = blockIdx.y;
    int v = blockIdx.x*256 + threadIdx.x;
    __shared__ float cps[64];
    if (threadIdx.x < 64) cps[threadIdx.x] = cp[b*64 + threadIdx.x];
    __syncthreads();
    if (v >= NCV) return;
    float vv[NU];
#pragma unroll
    for (int n = 0; n < NU; ++n) vv[n] = bf2f(vc[((long)(b*NU+n))*NCV + v]);
#pragma unroll
    for (int u = 0; u < NU; ++u) {
        float s = 0.f;
#pragma unroll
        for (int n = 0; n < NU; ++n) s += cps[u*8+n]*vv[n];
        ctx[((long)(b*NU+u))*NCV + v] = f2bf(s);
    }
}

// ---------------- fused tail: blend + hy-sum + logits-softmax ----------------
__global__ __launch_bounds__(128)
void k_tail(const float* __restrict__ hn, const float* __restrict__ cn,
            const float* __restrict__ hcw, const float* __restrict__ hx,
            const float* __restrict__ cx, const float* __restrict__ mask,
            const float* __restrict__ piw, const float* __restrict__ pib,
            float* __restrict__ hy, float* __restrict__ cy,
            float* __restrict__ out)
{
    const int b = blockIdx.x;
    const int h = threadIdx.x;
    __shared__ float hs[128];
    __shared__ float lg[28];
    float s = 0.f;
#pragma unroll
    for (int u = 0; u < NU; ++u) {
        int idx = (b*NU+u)*NH + h;
        float m = mask[b*NU+u];
        float hyv = m*(hn[idx]+hcw[idx]) + (1.f-m)*hx[idx];
        float cyv = m*cn[idx] + (1.f-m)*cx[idx];
        hy[idx] = hyv; cy[idx] = cyv;
        s += hyv;
    }
    hs[h] = s;
    __syncthreads();
    if (h < 28) {
        int o = h / 7, a = h - o*7;
        float acc = pib[o*NA+a];
        for (int k = 0; k < NH; ++k) acc += hs[k] * piw[((long)o*NH+k)*NA + a];
        lg[h] = acc;
    }
    __syncthreads();
    if (h < NO) {
        float mx = lg[h*NA];
#pragma unroll
        for (int a = 1; a < NA; ++a) mx = fmaxf(mx, lg[h*NA+a]);
        float e[NA]; float sm = 0.f;
#pragma unroll
        for (int a = 0; a < NA; ++a) { e[a] = expf(lg[h*NA+a]-mx); sm += e[a]; }
        float inv = 1.f/sm;
#pragma unroll
        for (int a = 0; a < NA; ++a) out[(long)b*NO*NA + h*NA + a] = e[a]*inv;
    }
}

extern "C" void kernel_launch(void* const* d_in, const int* in_sizes, int n_in,
                              void* d_out, int out_size, void* d_ws, size_t ws_size,
                              hipStream_t stream) {
    const float* x    = (const float*)d_in[0];
    const float* hx   = (const float*)d_in[1];
    const float* cx   = (const float*)d_in[2];
    const float* opt  = (const float*)d_in[3];
    const float* c1w  = (const float*)d_in[4];
    const float* c1b  = (const float*)d_in[5];
    const float* c2w  = (const float*)d_in[6];
    const float* c2b  = (const float*)d_in[7];
    const float* c3w  = (const float*)d_in[8];
    const float* c3b  = (const float*)d_in[9];
    const float* Wk   = (const float*)d_in[10];
    const float* bk   = (const float*)d_in[11];
    const float* Wv   = (const float*)d_in[12];
    const float* bv   = (const float*)d_in[13];
    const float* Wq   = (const float*)d_in[14];
    const float* Wi   = (const float*)d_in[15];
    const float* Wh   = (const float*)d_in[16];
    const float* blstm= (const float*)d_in[17];
    const float* Wqc  = (const float*)d_in[18];
    const float* Wkc  = (const float*)d_in[19];
    const float* Wvc  = (const float*)d_in[20];
    const float* Wout = (const float*)d_in[21];
    const float* piw  = (const float*)d_in[22];
    const float* pib  = (const float*)d_in[23];

    float* out = (float*)d_out;
    float* hy  = out + (long)NB*NO*NA;
    float* cy  = hy + (long)NB*NU*NH;

    float* ws = (float*)d_ws;
    long o = 0;
    float* b_k0  = ws + o; o += 16384;
    float* b_v0  = ws + o; o += 102400;
    float* b_q   = ws + o; o += 131072;
    float* b_at  = ws + o; o += 819200;
    float* b_re  = ws + o; o += 2048;
    float* b_mk  = ws + o; o += 2048;
    float* b_pre = ws + o; o += 1048576;
    float* b_cn  = ws + o; o += 262144;
    float* b_hn  = ws + o; o += 262144;
    float* b_qc  = ws + o; o += 65536;
    float* b_kc  = ws + o; o += 65536;
    float* b_cp  = ws + o; o += 16384;
    float* b_hc  = ws + o; o += 262144;
    float* b_hs  = ws + o; o += 32768;
    // o == 3088384
    // Region spans (floats), all < NEED = 33,419,264 (proven):
    //  P1OFF  3,088,384: S1 p1 [-> 7,024,640]
    //                    S2 k0 partials S=561 [-> 12,279,808]  (p1/c2 dead)
    //                    S3-S5 WvT [-> 13,853,184]
    //                    S8+ WvcT/WoutT/partW [-> 14,172,160]
    //  C2OFF  7,024,640: S1 c2 [-> 14,397,440]
    //  EMBOFF 14,397,440: S1-S2 emb32 [-> 28,176,384]
    //                     S5 v0 partials S=121 [12,390,400 -> 26,787,840]
    //                     S9+ vc16/ctx16 [-> 28,176,384]
    //  TOFF   28,176,384: S1-S5 emb16 [3,444,736 -> 31,621,120]  (conv3 dual-write)
    //                     S7 WiT/WhT/pre_h [-> 30,306,304]
    constexpr long P1OFF  = 3088384;
    constexpr long C2OFF  = 7024640;
    constexpr long EMBOFF = 14397440;
    constexpr long TOFF   = 28176384;
    constexpr long NEED   = TOFF + 5242880;   // 33,419,264 floats (proven)
    if (ws_size < (size_t)NEED * sizeof(float)) return;

    float* p1    = ws + P1OFF;
    float* c2    = ws + C2OFF;
    float* emb   = ws + EMBOFF;
    float* partK = ws + P1OFF;                                   // S2 (p1/c2 dead)
    float* partV = ws + EMBOFF;                                  // S5 (emb32 dead)
    unsigned short* emb16 = (unsigned short*)(ws + TOFF);        // S1-S5 (conv3 dual-write)
    unsigned short* WvT   = (unsigned short*)(ws + P1OFF);       // S3-S5 (after k0 reduce)
    unsigned short* WiT   = (unsigned short*)(ws + TOFF);        // S7 (emb16 dead)
    unsigned short* WhT   = (unsigned short*)(ws + TOFF + 819200);
    float* pre_h          = ws + TOFF + 819200 + 262144;
    unsigned short* WvcT  = (unsigned short*)(ws + P1OFF);       // S8 (WvT dead)
    unsigned short* WoutT = (unsigned short*)(ws + P1OFF + 3444736);
    float* partW          = ws + P1OFF + 2*3444736;
    unsigned short* vc16  = (unsigned short*)(ws + EMBOFF);      // S9 (v0 partials dead)
    unsigned short* ctx16 = (unsigned short*)(ws + EMBOFF + 6889472);

    // S1) conv stack (conv3 hi/lo MFMA, per-chunk staging, dual-writes emb32+emb16)
    k_conv1<<<(NB*16*H1*W1 + 255)/256, 256, 0, stream>>>(x, c1w, c1b, p1);
    conv2x2_gemm<32,16,H1,W1,H2,W2><<<NB*((H2*W2+127)/128), 256, 0, stream>>>(p1, c2w, c2b, c2);
    conv3_mfma<<<dim3((H3*W3+127)/128, NB), 256, 0, stream>>>(c2, c3w, c3b, emb, emb16);

    // S2) k0 = emb@Wk + bk  (fp32; S=561; partials in dead p1/c2)
    k0_gemm<<<561, 256, 0, stream>>>(emb, Wk, partK, NE, 96);
    k_reduce_splitk<<<(NB*NDK + 255)/256, 256, 0, stream>>>(
        partK, b_k0, NDK, 0, bk, 0, 1, NB, NDK, 561);

    // S3) Wv -> bf16 transposed [400][53824]  (k0 partials dead)
    k_f2bt<<<dim3(13, 1682, 1), 256, 0, stream>>>(Wv, WvT, NE, NV, 0);

    // S5) v0 = emb16@Wv + bv  (bf16 MFMA, 128x128, S=121; partials at EMBOFF)
    bgemm_splitk<128,128,false><<<dim3(4,2,121), 256, 0, stream>>>(
        emb16, NE, 0, WvT, NE, 0, partV, NB, NV, NE, 121, 448);
    k_reduce_splitk<<<(NB*NV + 255)/256, 256, 0, stream>>>(
        partV, b_v0, NV, 0, bv, 0, 1, NB, NV, 121);

    // S6) q / attention / top-k
    k_q<<<(NB*NU*NDK + 255)/256, 256, 0, stream>>>(opt, hx, Wq, b_q);
    k_attn<<<NB*NU, 64, 0, stream>>>(b_q, b_k0, bk, b_v0, bv, b_at, b_re);
    k_topk<<<1, 256, 0, stream>>>(b_re, b_mk);

    // S7) LSTM pre in bf16 MFMA (fp32 accum/out)
    k_f2bt<<<dim3(16, 13, 8), 256, 0, stream>>>(Wi, WiT, NV, 512, (long)NV*512);
    k_f2bt<<<dim3(16, 4, 8), 256, 0, stream>>>(Wh, WhT, NH, 512, (long)NH*512);
    bgemm_f32<true><<<dim3(8, 4, NU), 256, 0, stream>>>(
        b_at, (long)NU*NV, NV, WiT, NV, (long)512*NV,
        b_pre, (long)NU*512, 512, NB, 512, NV);
    bgemm_f32<true><<<dim3(8, 4, NU), 256, 0, stream>>>(
        hx, (long)NU*NH, NH, WhT, NH, (long)512*NH,
        pre_h, (long)NU*512, 512, NB, 512, NH);
    k_gates<<<(NB*NU*NH + 255)/256, 256, 0, stream>>>(b_pre, pre_h, blstm, cx, b_cn, b_hn);

    // S8) convert Wvc/Wout (WvT dead after v0)
    k_f2bt<<<dim3(211, 4, 8), 256, 0, stream>>>(Wvc, WvcT, NH, NCV, (long)NH*NCV);
    k_f2bt<<<dim3(4, 211, 8), 256, 0, stream>>>(Wout, WoutT, NCV, NH, (long)NCV*NH);

    // S9) vc = h_new@Wvc (bf16 MFMA direct, bf16 out)  (v0 partials dead)
    bgemm_direct<true><<<dim3((NCV+127)/128, 2, NU), 256, 0, stream>>>(
        b_hn, (long)NU*NH, NH, WvcT, NH, (long)NCV*NH,
        vc16, (long)NU*NCV, NCV, NB, NCV, NH);

    // S10) comm probs + ctx
    k_qckc<<<(NB*NU*64 + 255)/256, 256, 0, stream>>>(b_hn, Wqc, Wkc, b_qc, b_kc);
    k_cp<<<NB, 64, 0, stream>>>(b_qc, b_kc, b_mk, b_cp);
    k_ctx<<<dim3((NCV+255)/256, NB), 256, 0, stream>>>(vc16, b_cp, ctx16);

    // S11) hcomm_w = ctx@Wout (bf16 MFMA split-K 16)
    bgemm_splitk<64,64,false><<<dim3(2,4,NU*16), 256, 0, stream>>>(
        ctx16, (long)NU*NCV, NCV, WoutT, NCV, (long)NCV*NH,
        partW, NB, NH, NCV, 16, 448);
    k_reduce_splitk<<<(NU*NB*NH + 255)/256, 256, 0, stream>>>(
        partW, b_hc, (long)NU*NH, NH, nullptr, 0, NU, NB, NH, 16);

    // S12) fused blend + hy-sum + logits
    k_tail<<<NB, 128, 0, stream>>>(b_hn, b_cn, b_hc, hx, cx, b_mk, piw, pib, hy, cy, out);
}